// Round 1
// baseline (525.903 us; speedup 1.0000x reference)
//
#include <hip/hip_runtime.h>
#include <hip/hip_bf16.h>

// PCGTConvLayer round 10: k_cross rewritten as zero-barrier, direct-global-
// operand flash attention. Q fragments live in registers for the whole
// kernel; QK^T B-operand streams from rpk (L2-resident, 128KB/head) and PV
// B-operand from rvT (already [d][rep] so 8 consecutive reps are 16B
// contiguous). Only LDS left is per-wave Ps scratch -> no __syncthreads at
// all; waves are independent. All other kernels verbatim from round 9.
// N=32768 IN=256 D=128 H=4 M=4 KP=128 S=256, SCALE=sqrt(128).

#define INV_SCALE 0.08838834764831845f

typedef __attribute__((ext_vector_type(8))) short bf16x8;
typedef __attribute__((ext_vector_type(4))) float floatx4;
typedef unsigned short ushort_t;
typedef unsigned int uint32;

// ---- ws layout (bytes) ----
#define OFF_Q    0ull            // bf16 [32768][512]
#define OFF_K    33554432ull     // bf16 [32768][512]
#define OFF_V    67108864ull     // bf16 [32768][512]
#define OFF_LOC  100663296ull    // bf16 [32768][128]
#define OFF_RPK  109051904ull    // bf16 [512][4][128]
#define OFF_XC   110100480ull    // bf16 [32768][256]
#define OFF_WC   126877696ull    // bf16: WqT,WkT,WvT ([512][256] each), biases, seeds
#define OFF_SCAL 127671296ull    // f32 [2]
#define OFF_FLAG 127671304ull    // u32 [2]
#define OFF_RVT  127672320ull    // bf16 [4][128][512]
#define OFF_GLB  128196608ull    // bf16 [32768][512]

#define WC_WQ 0
#define WC_WK 131072
#define WC_WV 262144
#define WC_BQ 393216
#define WC_BK 393728
#define WC_BV 394240
#define WC_SEED 394752
#define WC_TOT 396800

static __device__ __forceinline__ float bflo(uint32 u) {
  return __uint_as_float(u << 16);
}
static __device__ __forceinline__ float bfhi(uint32 u) {
  return __uint_as_float(u & 0xffff0000u);
}
static __device__ __forceinline__ float bf2f(ushort_t u) {
  return __uint_as_float(((uint32)u) << 16);
}
static __device__ __forceinline__ ushort_t f2bf(float f) {
  uint32 x = __float_as_uint(f);
  uint32 r = x + 0x7fffu + ((x >> 16) & 1u);
  return (ushort_t)(r >> 16);
}
static __device__ __forceinline__ uint32 pack2bf(float a, float b) {
  return (uint32)f2bf(a) | ((uint32)f2bf(b) << 16);
}

// ---------------------------------------------------------------------------
__global__ __launch_bounds__(64) void k_detect(const uint32* __restrict__ xw,
                                               const ushort_t* __restrict__ betaRaw,
                                               uint32* __restrict__ flags) {
  const int lane = threadIdx.x;
  const uint32 w = xw[lane * 137 + 3];
  const int e = (w >> 7) & 0xff;
  const unsigned long long b = __ballot(e >= 100 && e <= 140);
  if (lane == 0) {
    flags[0] = (__popcll(b) >= 48) ? 1u : 0u;
    flags[1] = (betaRaw[0] != 0) ? 1u : 0u;
  }
}

// ---------------------------------------------------------------------------
// K1: canonicalize. x -> xc (identity layout). W matrices -> TRANSPOSED
// bf16 [512][256] at same wc offsets. biases/seeds identity.
// ---------------------------------------------------------------------------
static __device__ __forceinline__ void conv8(const void* src, long j, int isB,
                                             ushort_t* dst) {
  if (isB) {
    *reinterpret_cast<uint4*>(dst) =
        *reinterpret_cast<const uint4*>(reinterpret_cast<const ushort_t*>(src) + j);
  } else {
    const float* f = reinterpret_cast<const float*>(src) + j;
    const float4 a = *reinterpret_cast<const float4*>(f);
    const float4 b = *reinterpret_cast<const float4*>(f + 4);
    uint4 o;
    o.x = pack2bf(a.x, a.y); o.y = pack2bf(a.z, a.w);
    o.z = pack2bf(b.x, b.y); o.w = pack2bf(b.z, b.w);
    *reinterpret_cast<uint4*>(dst) = o;
  }
}

__global__ __launch_bounds__(256) void k_convert(
    const void* __restrict__ x,
    const void* __restrict__ Wq, const void* __restrict__ bq,
    const void* __restrict__ Wk, const void* __restrict__ bk,
    const void* __restrict__ Wv, const void* __restrict__ bv,
    const void* __restrict__ seeds, const void* __restrict__ alpha,
    const void* __restrict__ beta,
    ushort_t* __restrict__ xc, ushort_t* __restrict__ wc,
    float* __restrict__ scal, const uint32* __restrict__ flags)
{
  const int isB = (int)flags[0];
  const long i8 = ((long)blockIdx.x * 256 + threadIdx.x) * 8;
  if (blockIdx.y == 0) {
    conv8(x, i8, isB, xc + i8);
  } else {
    if (i8 < WC_BQ) {
      // W region: transpose. i8 = sel*131072 + k*512 + n (8 consecutive n).
      const int sel = (int)(i8 >> 17);
      const long local = i8 & 131071;
      const int kk = (int)(local >> 9);
      const int nn = (int)(local & 511);
      const void* src = sel == 0 ? Wq : (sel == 1 ? Wk : Wv);
      ushort_t* dstW = wc + sel * 131072;
#pragma unroll
      for (int j = 0; j < 8; ++j) {
        ushort_t v;
        if (isB) v = reinterpret_cast<const ushort_t*>(src)[local + j];
        else     v = f2bf(reinterpret_cast<const float*>(src)[local + j]);
        dstW[(size_t)(nn + j) * 256 + kk] = v;
      }
    } else if (i8 < WC_TOT) {
      const void* src; long j;
      if (i8 < WC_BK)        { src = bq;    j = i8 - WC_BQ; }
      else if (i8 < WC_BV)   { src = bk;    j = i8 - WC_BK; }
      else if (i8 < WC_SEED) { src = bv;    j = i8 - WC_BV; }
      else                   { src = seeds; j = i8 - WC_SEED; }
      conv8(src, j, isB, wc + i8);
    }
    if (blockIdx.x == 0 && threadIdx.x == 0) {
      const int isBS = (int)flags[1];
      scal[0] = isBS ? bf2f(reinterpret_cast<const ushort_t*>(alpha)[0])
                     : reinterpret_cast<const float*>(alpha)[0];
      scal[1] = isBS ? bf2f(reinterpret_cast<const ushort_t*>(beta)[0])
                     : reinterpret_cast<const float*>(beta)[0];
    }
  }
}

// ---------------------------------------------------------------------------
// K2: fused QKV GEMM. One block = 64 rows of x; loops sel(3) x 8 col-chunks.
// Xs staged ONCE (XOR-swizzled: chunk c of row at ((c^(row&7))<<3)); Ws from
// W^T with identical swizzle via coalesced uint4. MFMA 16x16x32, wave =
// 16 rows x 64 cols per chunk. LDS exactly 64 KiB.
// ---------------------------------------------------------------------------
__global__ __launch_bounds__(256) void k_qkv(
    const ushort_t* __restrict__ xc, const ushort_t* __restrict__ wc,
    ushort_t* __restrict__ Qb, ushort_t* __restrict__ Kb, ushort_t* __restrict__ Vb)
{
  const int m0 = blockIdx.x * 64;
  const int tid = threadIdx.x, lane = tid & 63, wv = tid >> 6;
  const int l16 = lane & 15, quad = lane >> 4;

  __shared__ __align__(16) ushort_t Xs[64 * 256];   // 32 KiB
  __shared__ __align__(16) ushort_t Ws[64 * 256];   // 32 KiB

#pragma unroll
  for (int i = 0; i < 8; ++i) {
    const int id = tid + 256 * i;          // 2048 chunks of 8
    const int row = id >> 5, c = id & 31;
    uint4 v = *reinterpret_cast<const uint4*>(xc + (size_t)(m0 + row) * 256 + c * 8);
    *reinterpret_cast<uint4*>(&Xs[row * 256 + ((c ^ (row & 7)) << 3)]) = v;
  }

  for (int sel = 0; sel < 3; ++sel) {
    const ushort_t* WT   = wc + sel * 131072;
    const ushort_t* bias = wc + WC_BQ + sel * 512;
    ushort_t* out        = sel == 0 ? Qb : (sel == 1 ? Kb : Vb);
    for (int nc = 0; nc < 8; ++nc) {
      const int n0 = nc * 64;
      __syncthreads();   // prev chunk's Ws readers done (also orders Xs staging)
#pragma unroll
      for (int i = 0; i < 8; ++i) {
        const int id = tid + 256 * i;
        const int row = id >> 5, c = id & 31;
        uint4 v = *reinterpret_cast<const uint4*>(WT + (size_t)(n0 + row) * 256 + c * 8);
        *reinterpret_cast<uint4*>(&Ws[row * 256 + ((c ^ (row & 7)) << 3)]) = v;
      }
      __syncthreads();

      floatx4 acc[4] = {};
      const int arow = wv * 16 + l16;
#pragma unroll
      for (int ks = 0; ks < 8; ++ks) {
        const int ac = ks * 4 + quad;
        bf16x8 a = *reinterpret_cast<const bf16x8*>(&Xs[arow * 256 + ((ac ^ (arow & 7)) << 3)]);
#pragma unroll
        for (int nt = 0; nt < 4; ++nt) {
          const int brow = nt * 16 + l16;
          bf16x8 b = *reinterpret_cast<const bf16x8*>(&Ws[brow * 256 + ((ac ^ (brow & 7)) << 3)]);
          acc[nt] = __builtin_amdgcn_mfma_f32_16x16x32_bf16(a, b, acc[nt], 0, 0, 0);
        }
      }

#pragma unroll
      for (int nt = 0; nt < 4; ++nt) {
        const int col = n0 + nt * 16 + l16;
        const float bf = bf2f(bias[col]);
#pragma unroll
        for (int r = 0; r < 4; ++r) {
          const int row = m0 + wv * 16 + quad * 4 + r;
          out[(size_t)row * 512 + col] = f2bf(acc[nt][r] + bf);
        }
      }
    }
  }
}

// ---------------------------------------------------------------------------
// K3: pooling (seeds -> rpk, rvT). Verified (CHK3).
// ---------------------------------------------------------------------------
__global__ __launch_bounds__(256) void k_pool(
    const ushort_t* __restrict__ Kb, const ushort_t* __restrict__ Vb,
    const int* __restrict__ pidx_all, const ushort_t* __restrict__ wc,
    ushort_t* __restrict__ rpk, ushort_t* __restrict__ rvT)
{
  const int k = blockIdx.x, h = blockIdx.y;
  const int tid = threadIdx.x, lane = tid & 63, wv = tid >> 6;
  const int* pidx = pidx_all + k * 256;

  __shared__ __align__(16) ushort_t SB[128 * 256];
  const uint32* SBU = reinterpret_cast<const uint32*>(SB);

#pragma unroll
  for (int i = 0; i < 16; ++i) {
    const int e8 = tid + 256 * i;
    const int q = e8 >> 4, dc = (e8 & 15) * 8;
    uint4 kv = *reinterpret_cast<const uint4*>(Kb + (size_t)pidx[q] * 512 + h * 128 + dc);
    const ushort_t* ku = reinterpret_cast<const ushort_t*>(&kv);
    const int qp = q >> 1, qb = q & 1;
#pragma unroll
    for (int j = 0; j < 8; ++j) {
      const int d = dc + j;
      SB[d * 256 + (((qp ^ (d & 31)) << 1) | qb)] = ku[j];
    }
  }
  __syncthreads();

  float q00, q01, q10, q11;
  {
    const uint32* ssrc = reinterpret_cast<const uint32*>(wc + WC_SEED + (size_t)(wv * 4 + h) * 128);
    float s00 = 0.f, s01 = 0.f, s10 = 0.f, s11 = 0.f;
#pragma unroll 8
    for (int dc = 0; dc < 64; ++dc) {
      const uint32 qv = ssrc[dc];
      const float a0 = bflo(qv), a1 = bfhi(qv);
      const int d0 = dc * 2, d1 = d0 + 1;
      const int c0 = lane ^ (d0 & 31);
      const int c1 = lane ^ (d1 & 31);
      const uint32 u00 = SBU[d0 * 128 + c0];
      const uint32 u01 = SBU[d0 * 128 + c0 + 64];
      const uint32 u10 = SBU[d1 * 128 + c1];
      const uint32 u11 = SBU[d1 * 128 + c1 + 64];
      s00 += a0 * bflo(u00) + a1 * bflo(u10);
      s01 += a0 * bfhi(u00) + a1 * bfhi(u10);
      s10 += a0 * bflo(u01) + a1 * bflo(u11);
      s11 += a0 * bfhi(u01) + a1 * bfhi(u11);
    }
    s00 *= INV_SCALE; s01 *= INV_SCALE; s10 *= INV_SCALE; s11 *= INV_SCALE;
    float mx = fmaxf(fmaxf(s00, s01), fmaxf(s10, s11));
#pragma unroll
    for (int off = 32; off >= 1; off >>= 1) mx = fmaxf(mx, __shfl_xor(mx, off));
    const float e00 = __expf(s00 - mx), e01 = __expf(s01 - mx);
    const float e10 = __expf(s10 - mx), e11 = __expf(s11 - mx);
    float sm = e00 + e01 + e10 + e11;
#pragma unroll
    for (int off = 32; off >= 1; off >>= 1) sm += __shfl_xor(sm, off);
    const float inv = 1.0f / sm;
    q00 = e00 * inv; q01 = e01 * inv; q10 = e10 * inv; q11 = e11 * inv;
  }

  {
    float rk0 = 0.f, rk1 = 0.f;
    const int d0 = 2 * lane, d1 = 2 * lane + 1;
#pragma unroll 4
    for (int qp = 0; qp < 64; ++qp) {
      const float pa = __shfl(q00, qp), pb = __shfl(q01, qp);
      const float pc = __shfl(q10, qp), pd = __shfl(q11, qp);
      const int c0 = qp ^ (d0 & 31);
      const int c1 = qp ^ (d1 & 31);
      const uint32 u0  = SBU[d0 * 128 + c0];
      const uint32 u0b = SBU[d0 * 128 + c0 + 64];
      const uint32 u1  = SBU[d1 * 128 + c1];
      const uint32 u1b = SBU[d1 * 128 + c1 + 64];
      rk0 += pa * bflo(u0) + pb * bfhi(u0) + pc * bflo(u0b) + pd * bfhi(u0b);
      rk1 += pa * bflo(u1) + pb * bfhi(u1) + pc * bflo(u1b) + pd * bfhi(u1b);
    }
    reinterpret_cast<uint32*>(rpk + ((size_t)((k * 4 + wv) * 4 + h)) * 128)[lane] = pack2bf(rk0, rk1);
  }
  __syncthreads();

#pragma unroll
  for (int i = 0; i < 16; ++i) {
    const int e8 = tid + 256 * i;
    const int q = e8 >> 4, dc = (e8 & 15) * 8;
    uint4 vv = *reinterpret_cast<const uint4*>(Vb + (size_t)pidx[q] * 512 + h * 128 + dc);
    *reinterpret_cast<uint4*>(&SB[q * 128 + dc]) = vv;
  }
  __syncthreads();

  {
    float rv0 = 0.f, rv1 = 0.f;
#pragma unroll 4
    for (int qp = 0; qp < 64; ++qp) {
      const float pa = __shfl(q00, qp), pb = __shfl(q01, qp);
      const float pc = __shfl(q10, qp), pd = __shfl(q11, qp);
      const uint32 v00 = SBU[(2 * qp) * 64 + lane];
      const uint32 v01 = SBU[(2 * qp + 1) * 64 + lane];
      const uint32 v10 = SBU[(128 + 2 * qp) * 64 + lane];
      const uint32 v11 = SBU[(129 + 2 * qp) * 64 + lane];
      rv0 += pa * bflo(v00) + pb * bflo(v01) + pc * bflo(v10) + pd * bflo(v11);
      rv1 += pa * bfhi(v00) + pb * bfhi(v01) + pc * bfhi(v10) + pd * bfhi(v11);
    }
    const int rrep = k * 4 + wv;
    rvT[(size_t)(h * 128 + 2 * lane) * 512 + rrep]     = f2bf(rv0);
    rvT[(size_t)(h * 128 + 2 * lane + 1) * 512 + rrep] = f2bf(rv1);
  }
}

// ---------------------------------------------------------------------------
// K4: MFMA fine attention (verified round 8).
// ---------------------------------------------------------------------------
__global__ __launch_bounds__(256) void k_fine(
    const ushort_t* __restrict__ Qb, const ushort_t* __restrict__ Kb,
    const ushort_t* __restrict__ Vb, const int* __restrict__ pidx_all,
    ushort_t* __restrict__ locS)
{
  const int k = blockIdx.x, qg = blockIdx.y;
  const int tid = threadIdx.x, lane = tid & 63, wv = tid >> 6;
  const int l16 = lane & 15, quad = lane >> 4;
  const int* pidx = pidx_all + k * 256;

  __shared__ __align__(16) ushort_t Qs[64 * 136];
  __shared__ __align__(16) ushort_t SB2[64 * 136];
  __shared__ __align__(16) ushort_t Ps[4][16 * 72];

  float accS[8][4];
#pragma unroll
  for (int nt = 0; nt < 8; ++nt)
#pragma unroll
    for (int r = 0; r < 4; ++r) accS[nt][r] = 0.f;

  for (int h = 0; h < 4; ++h) {
    __syncthreads();
#pragma unroll
    for (int i = 0; i < 4; ++i) {
      const int e = tid + 256 * i;
      const int r = e >> 4, c8 = (e & 15) * 8;
      uint4 v = *reinterpret_cast<const uint4*>(Qb + (size_t)pidx[qg * 64 + r] * 512 + h * 128 + c8);
      *reinterpret_cast<uint4*>(&Qs[r * 136 + c8]) = v;
    }

    floatx4 O[8] = {};
    float m_i[4], l_i[4];
#pragma unroll
    for (int r = 0; r < 4; ++r) { m_i[r] = -3e38f; l_i[r] = 0.f; }

    for (int c = 0; c < 4; ++c) {
      __syncthreads();
#pragma unroll
      for (int i = 0; i < 4; ++i) {
        const int e = tid + 256 * i;
        const int r = e >> 4, c8 = (e & 15) * 8;
        uint4 v = *reinterpret_cast<const uint4*>(Kb + (size_t)pidx[c * 64 + r] * 512 + h * 128 + c8);
        *reinterpret_cast<uint4*>(&SB2[r * 136 + c8]) = v;
      }
      __syncthreads();

      floatx4 S[4] = {};
#pragma unroll
      for (int ks = 0; ks < 4; ++ks) {
        bf16x8 a = *reinterpret_cast<const bf16x8*>(&Qs[(wv * 16 + l16) * 136 + ks * 32 + quad * 8]);
#pragma unroll
        for (int nt = 0; nt < 4; ++nt) {
          bf16x8 b = *reinterpret_cast<const bf16x8*>(&SB2[(nt * 16 + l16) * 136 + ks * 32 + quad * 8]);
          S[nt] = __builtin_amdgcn_mfma_f32_16x16x32_bf16(a, b, S[nt], 0, 0, 0);
        }
      }
#pragma unroll
      for (int nt = 0; nt < 4; ++nt)
#pragma unroll
        for (int r = 0; r < 4; ++r) S[nt][r] *= INV_SCALE;

#pragma unroll
      for (int r = 0; r < 4; ++r) {
        float cm = fmaxf(fmaxf(S[0][r], S[1][r]), fmaxf(S[2][r], S[3][r]));
#pragma unroll
        for (int off = 1; off <= 8; off <<= 1) cm = fmaxf(cm, __shfl_xor(cm, off));
        const float mn = fmaxf(m_i[r], cm);
        const float sc = __expf(m_i[r] - mn);
        m_i[r] = mn;
        l_i[r] *= sc;
#pragma unroll
        for (int nt = 0; nt < 8; ++nt) O[nt][r] *= sc;
        float ps = 0.f;
#pragma unroll
        for (int nt = 0; nt < 4; ++nt) {
          const float p = __expf(S[nt][r] - mn);
          ps += p;
          Ps[wv][(quad * 4 + r) * 72 + nt * 16 + l16] = f2bf(p);
        }
#pragma unroll
        for (int off = 1; off <= 8; off <<= 1) ps += __shfl_xor(ps, off);
        l_i[r] += ps;
      }
      __syncthreads();

#pragma unroll
      for (int i = 0; i < 4; ++i) {
        const int e = tid + 256 * i;
        const int key = e & 63, dc8 = (e >> 6) * 8;
        uint4 vv = *reinterpret_cast<const uint4*>(Vb + (size_t)pidx[c * 64 + key] * 512 + h * 128 + dc8);
        const ushort_t* u = reinterpret_cast<const ushort_t*>(&vv);
#pragma unroll
        for (int j = 0; j < 8; ++j) {
          const int d = dc8 + j;
          SB2[d * 64 + (((key >> 3) ^ j) << 3) + (key & 7)] = u[j];
        }
      }
      __syncthreads();

#pragma unroll
      for (int ks = 0; ks < 2; ++ks) {
        bf16x8 a = *reinterpret_cast<const bf16x8*>(&Ps[wv][l16 * 72 + ks * 32 + quad * 8]);
#pragma unroll
        for (int nt = 0; nt < 8; ++nt) {
          const int d = nt * 16 + l16;
          const int q8 = ks * 4 + quad;
          bf16x8 b = *reinterpret_cast<const bf16x8*>(&SB2[d * 64 + ((q8 ^ (d & 7)) << 3)]);
          O[nt] = __builtin_amdgcn_mfma_f32_16x16x32_bf16(a, b, O[nt], 0, 0, 0);
        }
      }
    }

#pragma unroll
    for (int r = 0; r < 4; ++r) {
      const float inv = 1.0f / l_i[r];
#pragma unroll
      for (int nt = 0; nt < 8; ++nt) accS[nt][r] += O[nt][r] * inv;
    }
  }

#pragma unroll
  for (int r = 0; r < 4; ++r) {
    const int n = pidx[qg * 64 + wv * 16 + quad * 4 + r];
#pragma unroll
    for (int nt = 0; nt < 8; ++nt)
      locS[(size_t)n * 128 + nt * 16 + l16] = f2bf(accS[nt][r] * 0.25f);
  }
}

// ---------------------------------------------------------------------------
// K5: MFMA cross-attention, round 10: zero-barrier, direct-global operands.
// Block = 64 Q rows x one head; 4 independent waves of 16 rows each.
// Q frags held in registers for the whole kernel. QK^T B-frags load straight
// from rpk (rep-major: lane l16 -> rep row, 16B contiguous k-slice). PV
// B-frags load straight from rvT ([d][rep]: 8 consecutive reps = 16B).
// Only LDS: per-wave Ps (P-transpose scratch for the PV A-operand). No
// __syncthreads anywhere -> waves free-run; occupancy LDS-unconstrained.
// ---------------------------------------------------------------------------
__global__ __launch_bounds__(256, 4) void k_cross(
    const ushort_t* __restrict__ Qb, const ushort_t* __restrict__ rpk,
    const ushort_t* __restrict__ rvT, ushort_t* __restrict__ glb)
{
  const int h = blockIdx.y;
  const int n0 = blockIdx.x * 64;
  const int tid = threadIdx.x, lane = tid & 63, wv = tid >> 6;
  const int l16 = lane & 15, quad = lane >> 4;

  __shared__ __align__(16) ushort_t Ps[4][16 * 72];   // 9 KiB, wave-exclusive

  // Q fragments: row = n0 + wv*16 + l16, k-chunk = ks*32 + quad*8. 16 VGPRs.
  bf16x8 qf[4];
  {
    const ushort_t* qrow =
        Qb + (size_t)(n0 + wv * 16 + l16) * 512 + h * 128 + quad * 8;
#pragma unroll
    for (int ks = 0; ks < 4; ++ks)
      qf[ks] = *reinterpret_cast<const bf16x8*>(qrow + ks * 32);
  }

  // Per-lane invariant operand base pointers.
  // QK B: rep = c*64 + nt*16 + l16; addr = rpk + rep*512 + h*128 + ks*32 + quad*8
  const ushort_t* rpkB = rpk + (size_t)l16 * 512 + h * 128 + quad * 8;
  // PV B: d-row = nt*16 + l16; addr = rvT + (h*128 + d)*512 + c*64 + ks*32 + quad*8
  const ushort_t* rvtB = rvT + ((size_t)(h * 128 + l16)) * 512 + quad * 8;

  floatx4 O[8] = {};
  float m_i[4], l_i[4];
#pragma unroll
  for (int r = 0; r < 4; ++r) { m_i[r] = -3e38f; l_i[r] = 0.f; }

  for (int c = 0; c < 8; ++c) {
    // ---- QK^T: S[nt] = Q(16x128) . rpk_chunk(64x128)^T ----
    floatx4 S[4] = {};
#pragma unroll
    for (int ks = 0; ks < 4; ++ks) {
#pragma unroll
      for (int nt = 0; nt < 4; ++nt) {
        bf16x8 b = *reinterpret_cast<const bf16x8*>(
            rpkB + ((size_t)(c * 64 + nt * 16)) * 512 + ks * 32);
        S[nt] = __builtin_amdgcn_mfma_f32_16x16x32_bf16(qf[ks], b, S[nt], 0, 0, 0);
      }
    }
#pragma unroll
    for (int nt = 0; nt < 4; ++nt)
#pragma unroll
      for (int r = 0; r < 4; ++r) S[nt][r] *= INV_SCALE;

    // ---- online softmax (identical math to round 9) ----
#pragma unroll
    for (int r = 0; r < 4; ++r) {
      float cm = fmaxf(fmaxf(S[0][r], S[1][r]), fmaxf(S[2][r], S[3][r]));
#pragma unroll
      for (int off = 1; off <= 8; off <<= 1) cm = fmaxf(cm, __shfl_xor(cm, off));
      const float mn = fmaxf(m_i[r], cm);
      const float sc = __expf(m_i[r] - mn);
      m_i[r] = mn;
      l_i[r] *= sc;
#pragma unroll
      for (int nt = 0; nt < 8; ++nt) O[nt][r] *= sc;
      float ps = 0.f;
#pragma unroll
      for (int nt = 0; nt < 4; ++nt) {
        const float p = __expf(S[nt][r] - mn);
        ps += p;
        Ps[wv][(quad * 4 + r) * 72 + nt * 16 + l16] = f2bf(p);
      }
#pragma unroll
      for (int off = 1; off <= 8; off <<= 1) ps += __shfl_xor(ps, off);
      l_i[r] += ps;
    }
    // Ps write->read is within-wave; compiler orders via lgkmcnt (no barrier).

    // ---- PV: O += P(16x64) . rv_chunk(64x128) ----
#pragma unroll
    for (int ks = 0; ks < 2; ++ks) {
      bf16x8 a = *reinterpret_cast<const bf16x8*>(&Ps[wv][l16 * 72 + ks * 32 + quad * 8]);
#pragma unroll
      for (int nt = 0; nt < 8; ++nt) {
        bf16x8 b = *reinterpret_cast<const bf16x8*>(
            rvtB + ((size_t)(nt * 16)) * 512 + c * 64 + ks * 32);
        O[nt] = __builtin_amdgcn_mfma_f32_16x16x32_bf16(a, b, O[nt], 0, 0, 0);
      }
    }
  }

#pragma unroll
  for (int r = 0; r < 4; ++r) {
    const float inv = 1.0f / l_i[r];
    const int n = n0 + wv * 16 + quad * 4 + r;
#pragma unroll
    for (int nt = 0; nt < 8; ++nt)
      glb[(size_t)n * 512 + h * 128 + nt * 16 + l16] = f2bf(O[nt][r] * inv);
  }
}

// ---------------------------------------------------------------------------
// K6: combine -> f32 output.
// ---------------------------------------------------------------------------
__global__ __launch_bounds__(256) void k_combine(
    const ushort_t* __restrict__ locS, const ushort_t* __restrict__ glb,
    const ushort_t* __restrict__ Vb, const float* __restrict__ scal,
    float* __restrict__ out)
{
  const int t = blockIdx.x * 256 + threadIdx.x;
  const int n = t >> 6, dp = t & 63;
  const float alpha = 1.0f / (1.0f + __expf(-scal[0]));
  const float beta = scal[1];
  const uint32 lv = reinterpret_cast<const uint32*>(locS)[(size_t)n * 64 + dp];
  float g0 = 0.f, g1 = 0.f, v0 = 0.f, v1 = 0.f;
#pragma unroll
  for (int hh = 0; hh < 4; ++hh) {
    const uint32 gv = *reinterpret_cast<const uint32*>(glb + (size_t)n * 512 + hh * 128 + 2 * dp);
    const uint32 vv = *reinterpret_cast<const uint32*>(Vb + (size_t)n * 512 + hh * 128 + 2 * dp);
    g0 += bflo(gv); g1 += bfhi(gv);
    v0 += bflo(vv); v1 += bfhi(vv);
  }
  const float r0 = alpha * bflo(lv) + (1.0f - alpha) * g0 * 0.25f + beta * v0 * 0.25f;
  const float r1 = alpha * bfhi(lv) + (1.0f - alpha) * g1 * 0.25f + beta * v1 * 0.25f;
  reinterpret_cast<float2*>(out)[(size_t)n * 64 + dp] = make_float2(r0, r1);
}

extern "C" void kernel_launch(void* const* d_in, const int* in_sizes, int n_in,
                              void* d_out, int out_size, void* d_ws, size_t ws_size,
                              hipStream_t stream) {
  const void* x     = d_in[0];
  const int*  pidx  = (const int*)d_in[1];
  const void* Wq    = d_in[2];
  const void* bq    = d_in[3];
  const void* Wk    = d_in[4];
  const void* bk    = d_in[5];
  const void* Wv    = d_in[6];
  const void* bv    = d_in[7];
  const void* seeds = d_in[8];
  const void* al    = d_in[9];
  const void* be    = d_in[10];

  char* ws = (char*)d_ws;
  ushort_t* Qb   = (ushort_t*)(ws + OFF_Q);
  ushort_t* Kb   = (ushort_t*)(ws + OFF_K);
  ushort_t* Vb   = (ushort_t*)(ws + OFF_V);
  ushort_t* locS = (ushort_t*)(ws + OFF_LOC);
  ushort_t* rpk  = (ushort_t*)(ws + OFF_RPK);
  ushort_t* xc   = (ushort_t*)(ws + OFF_XC);
  ushort_t* wc   = (ushort_t*)(ws + OFF_WC);
  float*    scal = (float*)   (ws + OFF_SCAL);
  uint32*   flags= (uint32*)  (ws + OFF_FLAG);
  ushort_t* rvT  = (ushort_t*)(ws + OFF_RVT);
  ushort_t* glb  = (ushort_t*)(ws + OFF_GLB);

  k_detect<<<1, 64, 0, stream>>>((const uint32*)x, (const ushort_t*)be, flags);
  k_convert<<<dim3(4096, 2), 256, 0, stream>>>(x, Wq, bq, Wk, bk, Wv, bv, seeds, al, be,
                                               xc, wc, scal, flags);
  k_qkv<<<512, 256, 0, stream>>>(xc, wc, Qb, Kb, Vb);
  k_pool<<<dim3(128, 4), 256, 0, stream>>>(Kb, Vb, pidx, wc, rpk, rvT);
  k_fine<<<dim3(128, 4), 256, 0, stream>>>(Qb, Kb, Vb, pidx, locS);
  k_cross<<<dim3(512, 4), 256, 0, stream>>>(Qb, rpk, rvT, glb);
  k_combine<<<8192, 256, 0, stream>>>(locS, glb, Vb, scal, (float*)d_out);
}

// Round 3
// 462.232 us; speedup vs baseline: 1.1377x; 1.1377x over previous
//
#include <hip/hip_runtime.h>
#include <hip/hip_bf16.h>

// PCGTConvLayer round 12: identical to round 11 (k_cross = round-9 LDS-staged
// structure + reg-resident Q + split BsK/BsV + T14 reg prefetch + T13
// defer-max + exp2-domain softmax) with __exp2f -> exp2f hardening (standard
// HIP spelling; lowers to native v_exp_f32 on gfx950). Round-11 bench was an
// infra container failure, not a kernel verdict. All other kernels verbatim.
// N=32768 IN=256 D=128 H=4 M=4 KP=128 S=256, SCALE=sqrt(128).

#define INV_SCALE 0.08838834764831845f
// INV_SCALE * log2(e)
#define C2EXP 0.12751744f
// 8 / INV_SCALE  (defer-max threshold in unscaled-score domain)
#define DEFER_THR 90.50966799f

typedef __attribute__((ext_vector_type(8))) short bf16x8;
typedef __attribute__((ext_vector_type(4))) float floatx4;
typedef unsigned short ushort_t;
typedef unsigned int uint32;

// ---- ws layout (bytes) ----
#define OFF_Q    0ull            // bf16 [32768][512]
#define OFF_K    33554432ull     // bf16 [32768][512]
#define OFF_V    67108864ull     // bf16 [32768][512]
#define OFF_LOC  100663296ull    // bf16 [32768][128]
#define OFF_RPK  109051904ull    // bf16 [512][4][128]
#define OFF_XC   110100480ull    // bf16 [32768][256]
#define OFF_WC   126877696ull    // bf16: WqT,WkT,WvT ([512][256] each), biases, seeds
#define OFF_SCAL 127671296ull    // f32 [2]
#define OFF_FLAG 127671304ull    // u32 [2]
#define OFF_RVT  127672320ull    // bf16 [4][128][512]
#define OFF_GLB  128196608ull    // bf16 [32768][512]

#define WC_WQ 0
#define WC_WK 131072
#define WC_WV 262144
#define WC_BQ 393216
#define WC_BK 393728
#define WC_BV 394240
#define WC_SEED 394752
#define WC_TOT 396800

static __device__ __forceinline__ float bflo(uint32 u) {
  return __uint_as_float(u << 16);
}
static __device__ __forceinline__ float bfhi(uint32 u) {
  return __uint_as_float(u & 0xffff0000u);
}
static __device__ __forceinline__ float bf2f(ushort_t u) {
  return __uint_as_float(((uint32)u) << 16);
}
static __device__ __forceinline__ ushort_t f2bf(float f) {
  uint32 x = __float_as_uint(f);
  uint32 r = x + 0x7fffu + ((x >> 16) & 1u);
  return (ushort_t)(r >> 16);
}
static __device__ __forceinline__ uint32 pack2bf(float a, float b) {
  return (uint32)f2bf(a) | ((uint32)f2bf(b) << 16);
}

// ---------------------------------------------------------------------------
__global__ __launch_bounds__(64) void k_detect(const uint32* __restrict__ xw,
                                               const ushort_t* __restrict__ betaRaw,
                                               uint32* __restrict__ flags) {
  const int lane = threadIdx.x;
  const uint32 w = xw[lane * 137 + 3];
  const int e = (w >> 7) & 0xff;
  const unsigned long long b = __ballot(e >= 100 && e <= 140);
  if (lane == 0) {
    flags[0] = (__popcll(b) >= 48) ? 1u : 0u;
    flags[1] = (betaRaw[0] != 0) ? 1u : 0u;
  }
}

// ---------------------------------------------------------------------------
// K1: canonicalize. x -> xc (identity layout). W matrices -> TRANSPOSED
// bf16 [512][256] at same wc offsets. biases/seeds identity.
// ---------------------------------------------------------------------------
static __device__ __forceinline__ void conv8(const void* src, long j, int isB,
                                             ushort_t* dst) {
  if (isB) {
    *reinterpret_cast<uint4*>(dst) =
        *reinterpret_cast<const uint4*>(reinterpret_cast<const ushort_t*>(src) + j);
  } else {
    const float* f = reinterpret_cast<const float*>(src) + j;
    const float4 a = *reinterpret_cast<const float4*>(f);
    const float4 b = *reinterpret_cast<const float4*>(f + 4);
    uint4 o;
    o.x = pack2bf(a.x, a.y); o.y = pack2bf(a.z, a.w);
    o.z = pack2bf(b.x, b.y); o.w = pack2bf(b.z, b.w);
    *reinterpret_cast<uint4*>(dst) = o;
  }
}

__global__ __launch_bounds__(256) void k_convert(
    const void* __restrict__ x,
    const void* __restrict__ Wq, const void* __restrict__ bq,
    const void* __restrict__ Wk, const void* __restrict__ bk,
    const void* __restrict__ Wv, const void* __restrict__ bv,
    const void* __restrict__ seeds, const void* __restrict__ alpha,
    const void* __restrict__ beta,
    ushort_t* __restrict__ xc, ushort_t* __restrict__ wc,
    float* __restrict__ scal, const uint32* __restrict__ flags)
{
  const int isB = (int)flags[0];
  const long i8 = ((long)blockIdx.x * 256 + threadIdx.x) * 8;
  if (blockIdx.y == 0) {
    conv8(x, i8, isB, xc + i8);
  } else {
    if (i8 < WC_BQ) {
      // W region: transpose. i8 = sel*131072 + k*512 + n (8 consecutive n).
      const int sel = (int)(i8 >> 17);
      const long local = i8 & 131071;
      const int kk = (int)(local >> 9);
      const int nn = (int)(local & 511);
      const void* src = sel == 0 ? Wq : (sel == 1 ? Wk : Wv);
      ushort_t* dstW = wc + sel * 131072;
#pragma unroll
      for (int j = 0; j < 8; ++j) {
        ushort_t v;
        if (isB) v = reinterpret_cast<const ushort_t*>(src)[local + j];
        else     v = f2bf(reinterpret_cast<const float*>(src)[local + j]);
        dstW[(size_t)(nn + j) * 256 + kk] = v;
      }
    } else if (i8 < WC_TOT) {
      const void* src; long j;
      if (i8 < WC_BK)        { src = bq;    j = i8 - WC_BQ; }
      else if (i8 < WC_BV)   { src = bk;    j = i8 - WC_BK; }
      else if (i8 < WC_SEED) { src = bv;    j = i8 - WC_BV; }
      else                   { src = seeds; j = i8 - WC_SEED; }
      conv8(src, j, isB, wc + i8);
    }
    if (blockIdx.x == 0 && threadIdx.x == 0) {
      const int isBS = (int)flags[1];
      scal[0] = isBS ? bf2f(reinterpret_cast<const ushort_t*>(alpha)[0])
                     : reinterpret_cast<const float*>(alpha)[0];
      scal[1] = isBS ? bf2f(reinterpret_cast<const ushort_t*>(beta)[0])
                     : reinterpret_cast<const float*>(beta)[0];
    }
  }
}

// ---------------------------------------------------------------------------
// K2: fused QKV GEMM. One block = 64 rows of x; loops sel(3) x 8 col-chunks.
// Xs staged ONCE (XOR-swizzled: chunk c of row at ((c^(row&7))<<3)); Ws from
// W^T with identical swizzle via coalesced uint4. MFMA 16x16x32, wave =
// 16 rows x 64 cols per chunk. LDS exactly 64 KiB.
// ---------------------------------------------------------------------------
__global__ __launch_bounds__(256) void k_qkv(
    const ushort_t* __restrict__ xc, const ushort_t* __restrict__ wc,
    ushort_t* __restrict__ Qb, ushort_t* __restrict__ Kb, ushort_t* __restrict__ Vb)
{
  const int m0 = blockIdx.x * 64;
  const int tid = threadIdx.x, lane = tid & 63, wv = tid >> 6;
  const int l16 = lane & 15, quad = lane >> 4;

  __shared__ __align__(16) ushort_t Xs[64 * 256];   // 32 KiB
  __shared__ __align__(16) ushort_t Ws[64 * 256];   // 32 KiB

#pragma unroll
  for (int i = 0; i < 8; ++i) {
    const int id = tid + 256 * i;          // 2048 chunks of 8
    const int row = id >> 5, c = id & 31;
    uint4 v = *reinterpret_cast<const uint4*>(xc + (size_t)(m0 + row) * 256 + c * 8);
    *reinterpret_cast<uint4*>(&Xs[row * 256 + ((c ^ (row & 7)) << 3)]) = v;
  }

  for (int sel = 0; sel < 3; ++sel) {
    const ushort_t* WT   = wc + sel * 131072;
    const ushort_t* bias = wc + WC_BQ + sel * 512;
    ushort_t* out        = sel == 0 ? Qb : (sel == 1 ? Kb : Vb);
    for (int nc = 0; nc < 8; ++nc) {
      const int n0 = nc * 64;
      __syncthreads();   // prev chunk's Ws readers done (also orders Xs staging)
#pragma unroll
      for (int i = 0; i < 8; ++i) {
        const int id = tid + 256 * i;
        const int row = id >> 5, c = id & 31;
        uint4 v = *reinterpret_cast<const uint4*>(WT + (size_t)(n0 + row) * 256 + c * 8);
        *reinterpret_cast<uint4*>(&Ws[row * 256 + ((c ^ (row & 7)) << 3)]) = v;
      }
      __syncthreads();

      floatx4 acc[4] = {};
      const int arow = wv * 16 + l16;
#pragma unroll
      for (int ks = 0; ks < 8; ++ks) {
        const int ac = ks * 4 + quad;
        bf16x8 a = *reinterpret_cast<const bf16x8*>(&Xs[arow * 256 + ((ac ^ (arow & 7)) << 3)]);
#pragma unroll
        for (int nt = 0; nt < 4; ++nt) {
          const int brow = nt * 16 + l16;
          bf16x8 b = *reinterpret_cast<const bf16x8*>(&Ws[brow * 256 + ((ac ^ (brow & 7)) << 3)]);
          acc[nt] = __builtin_amdgcn_mfma_f32_16x16x32_bf16(a, b, acc[nt], 0, 0, 0);
        }
      }

#pragma unroll
      for (int nt = 0; nt < 4; ++nt) {
        const int col = n0 + nt * 16 + l16;
        const float bf = bf2f(bias[col]);
#pragma unroll
        for (int r = 0; r < 4; ++r) {
          const int row = m0 + wv * 16 + quad * 4 + r;
          out[(size_t)row * 512 + col] = f2bf(acc[nt][r] + bf);
        }
      }
    }
  }
}

// ---------------------------------------------------------------------------
// K3: pooling (seeds -> rpk, rvT). Verified (CHK3).
// ---------------------------------------------------------------------------
__global__ __launch_bounds__(256) void k_pool(
    const ushort_t* __restrict__ Kb, const ushort_t* __restrict__ Vb,
    const int* __restrict__ pidx_all, const ushort_t* __restrict__ wc,
    ushort_t* __restrict__ rpk, ushort_t* __restrict__ rvT)
{
  const int k = blockIdx.x, h = blockIdx.y;
  const int tid = threadIdx.x, lane = tid & 63, wv = tid >> 6;
  const int* pidx = pidx_all + k * 256;

  __shared__ __align__(16) ushort_t SB[128 * 256];
  const uint32* SBU = reinterpret_cast<const uint32*>(SB);

#pragma unroll
  for (int i = 0; i < 16; ++i) {
    const int e8 = tid + 256 * i;
    const int q = e8 >> 4, dc = (e8 & 15) * 8;
    uint4 kv = *reinterpret_cast<const uint4*>(Kb + (size_t)pidx[q] * 512 + h * 128 + dc);
    const ushort_t* ku = reinterpret_cast<const ushort_t*>(&kv);
    const int qp = q >> 1, qb = q & 1;
#pragma unroll
    for (int j = 0; j < 8; ++j) {
      const int d = dc + j;
      SB[d * 256 + (((qp ^ (d & 31)) << 1) | qb)] = ku[j];
    }
  }
  __syncthreads();

  float q00, q01, q10, q11;
  {
    const uint32* ssrc = reinterpret_cast<const uint32*>(wc + WC_SEED + (size_t)(wv * 4 + h) * 128);
    float s00 = 0.f, s01 = 0.f, s10 = 0.f, s11 = 0.f;
#pragma unroll 8
    for (int dc = 0; dc < 64; ++dc) {
      const uint32 qv = ssrc[dc];
      const float a0 = bflo(qv), a1 = bfhi(qv);
      const int d0 = dc * 2, d1 = d0 + 1;
      const int c0 = lane ^ (d0 & 31);
      const int c1 = lane ^ (d1 & 31);
      const uint32 u00 = SBU[d0 * 128 + c0];
      const uint32 u01 = SBU[d0 * 128 + c0 + 64];
      const uint32 u10 = SBU[d1 * 128 + c1];
      const uint32 u11 = SBU[d1 * 128 + c1 + 64];
      s00 += a0 * bflo(u00) + a1 * bflo(u10);
      s01 += a0 * bfhi(u00) + a1 * bfhi(u10);
      s10 += a0 * bflo(u01) + a1 * bflo(u11);
      s11 += a0 * bfhi(u01) + a1 * bfhi(u11);
    }
    s00 *= INV_SCALE; s01 *= INV_SCALE; s10 *= INV_SCALE; s11 *= INV_SCALE;
    float mx = fmaxf(fmaxf(s00, s01), fmaxf(s10, s11));
#pragma unroll
    for (int off = 32; off >= 1; off >>= 1) mx = fmaxf(mx, __shfl_xor(mx, off));
    const float e00 = __expf(s00 - mx), e01 = __expf(s01 - mx);
    const float e10 = __expf(s10 - mx), e11 = __expf(s11 - mx);
    float sm = e00 + e01 + e10 + e11;
#pragma unroll
    for (int off = 32; off >= 1; off >>= 1) sm += __shfl_xor(sm, off);
    const float inv = 1.0f / sm;
    q00 = e00 * inv; q01 = e01 * inv; q10 = e10 * inv; q11 = e11 * inv;
  }

  {
    float rk0 = 0.f, rk1 = 0.f;
    const int d0 = 2 * lane, d1 = 2 * lane + 1;
#pragma unroll 4
    for (int qp = 0; qp < 64; ++qp) {
      const float pa = __shfl(q00, qp), pb = __shfl(q01, qp);
      const float pc = __shfl(q10, qp), pd = __shfl(q11, qp);
      const int c0 = qp ^ (d0 & 31);
      const int c1 = qp ^ (d1 & 31);
      const uint32 u0  = SBU[d0 * 128 + c0];
      const uint32 u0b = SBU[d0 * 128 + c0 + 64];
      const uint32 u1  = SBU[d1 * 128 + c1];
      const uint32 u1b = SBU[d1 * 128 + c1 + 64];
      rk0 += pa * bflo(u0) + pb * bfhi(u0) + pc * bflo(u0b) + pd * bfhi(u0b);
      rk1 += pa * bflo(u1) + pb * bfhi(u1) + pc * bflo(u1b) + pd * bfhi(u1b);
    }
    reinterpret_cast<uint32*>(rpk + ((size_t)((k * 4 + wv) * 4 + h)) * 128)[lane] = pack2bf(rk0, rk1);
  }
  __syncthreads();

#pragma unroll
  for (int i = 0; i < 16; ++i) {
    const int e8 = tid + 256 * i;
    const int q = e8 >> 4, dc = (e8 & 15) * 8;
    uint4 vv = *reinterpret_cast<const uint4*>(Vb + (size_t)pidx[q] * 512 + h * 128 + dc);
    *reinterpret_cast<uint4*>(&SB[q * 128 + dc]) = vv;
  }
  __syncthreads();

  {
    float rv0 = 0.f, rv1 = 0.f;
#pragma unroll 4
    for (int qp = 0; qp < 64; ++qp) {
      const float pa = __shfl(q00, qp), pb = __shfl(q01, qp);
      const float pc = __shfl(q10, qp), pd = __shfl(q11, qp);
      const uint32 v00 = SBU[(2 * qp) * 64 + lane];
      const uint32 v01 = SBU[(2 * qp + 1) * 64 + lane];
      const uint32 v10 = SBU[(128 + 2 * qp) * 64 + lane];
      const uint32 v11 = SBU[(129 + 2 * qp) * 64 + lane];
      rv0 += pa * bflo(v00) + pb * bflo(v01) + pc * bflo(v10) + pd * bflo(v11);
      rv1 += pa * bfhi(v00) + pb * bfhi(v01) + pc * bfhi(v10) + pd * bfhi(v11);
    }
    const int rrep = k * 4 + wv;
    rvT[(size_t)(h * 128 + 2 * lane) * 512 + rrep]     = f2bf(rv0);
    rvT[(size_t)(h * 128 + 2 * lane + 1) * 512 + rrep] = f2bf(rv1);
  }
}

// ---------------------------------------------------------------------------
// K4: MFMA fine attention (verified round 8).
// ---------------------------------------------------------------------------
__global__ __launch_bounds__(256) void k_fine(
    const ushort_t* __restrict__ Qb, const ushort_t* __restrict__ Kb,
    const ushort_t* __restrict__ Vb, const int* __restrict__ pidx_all,
    ushort_t* __restrict__ locS)
{
  const int k = blockIdx.x, qg = blockIdx.y;
  const int tid = threadIdx.x, lane = tid & 63, wv = tid >> 6;
  const int l16 = lane & 15, quad = lane >> 4;
  const int* pidx = pidx_all + k * 256;

  __shared__ __align__(16) ushort_t Qs[64 * 136];
  __shared__ __align__(16) ushort_t SB2[64 * 136];
  __shared__ __align__(16) ushort_t Ps[4][16 * 72];

  float accS[8][4];
#pragma unroll
  for (int nt = 0; nt < 8; ++nt)
#pragma unroll
    for (int r = 0; r < 4; ++r) accS[nt][r] = 0.f;

  for (int h = 0; h < 4; ++h) {
    __syncthreads();
#pragma unroll
    for (int i = 0; i < 4; ++i) {
      const int e = tid + 256 * i;
      const int r = e >> 4, c8 = (e & 15) * 8;
      uint4 v = *reinterpret_cast<const uint4*>(Qb + (size_t)pidx[qg * 64 + r] * 512 + h * 128 + c8);
      *reinterpret_cast<uint4*>(&Qs[r * 136 + c8]) = v;
    }

    floatx4 O[8] = {};
    float m_i[4], l_i[4];
#pragma unroll
    for (int r = 0; r < 4; ++r) { m_i[r] = -3e38f; l_i[r] = 0.f; }

    for (int c = 0; c < 4; ++c) {
      __syncthreads();
#pragma unroll
      for (int i = 0; i < 4; ++i) {
        const int e = tid + 256 * i;
        const int r = e >> 4, c8 = (e & 15) * 8;
        uint4 v = *reinterpret_cast<const uint4*>(Kb + (size_t)pidx[c * 64 + r] * 512 + h * 128 + c8);
        *reinterpret_cast<uint4*>(&SB2[r * 136 + c8]) = v;
      }
      __syncthreads();

      floatx4 S[4] = {};
#pragma unroll
      for (int ks = 0; ks < 4; ++ks) {
        bf16x8 a = *reinterpret_cast<const bf16x8*>(&Qs[(wv * 16 + l16) * 136 + ks * 32 + quad * 8]);
#pragma unroll
        for (int nt = 0; nt < 4; ++nt) {
          bf16x8 b = *reinterpret_cast<const bf16x8*>(&SB2[(nt * 16 + l16) * 136 + ks * 32 + quad * 8]);
          S[nt] = __builtin_amdgcn_mfma_f32_16x16x32_bf16(a, b, S[nt], 0, 0, 0);
        }
      }
#pragma unroll
      for (int nt = 0; nt < 4; ++nt)
#pragma unroll
        for (int r = 0; r < 4; ++r) S[nt][r] *= INV_SCALE;

#pragma unroll
      for (int r = 0; r < 4; ++r) {
        float cm = fmaxf(fmaxf(S[0][r], S[1][r]), fmaxf(S[2][r], S[3][r]));
#pragma unroll
        for (int off = 1; off <= 8; off <<= 1) cm = fmaxf(cm, __shfl_xor(cm, off));
        const float mn = fmaxf(m_i[r], cm);
        const float sc = __expf(m_i[r] - mn);
        m_i[r] = mn;
        l_i[r] *= sc;
#pragma unroll
        for (int nt = 0; nt < 8; ++nt) O[nt][r] *= sc;
        float ps = 0.f;
#pragma unroll
        for (int nt = 0; nt < 4; ++nt) {
          const float p = __expf(S[nt][r] - mn);
          ps += p;
          Ps[wv][(quad * 4 + r) * 72 + nt * 16 + l16] = f2bf(p);
        }
#pragma unroll
        for (int off = 1; off <= 8; off <<= 1) ps += __shfl_xor(ps, off);
        l_i[r] += ps;
      }
      __syncthreads();

#pragma unroll
      for (int i = 0; i < 4; ++i) {
        const int e = tid + 256 * i;
        const int key = e & 63, dc8 = (e >> 6) * 8;
        uint4 vv = *reinterpret_cast<const uint4*>(Vb + (size_t)pidx[c * 64 + key] * 512 + h * 128 + dc8);
        const ushort_t* u = reinterpret_cast<const ushort_t*>(&vv);
#pragma unroll
        for (int j = 0; j < 8; ++j) {
          const int d = dc8 + j;
          SB2[d * 64 + (((key >> 3) ^ j) << 3) + (key & 7)] = u[j];
        }
      }
      __syncthreads();

#pragma unroll
      for (int ks = 0; ks < 2; ++ks) {
        bf16x8 a = *reinterpret_cast<const bf16x8*>(&Ps[wv][l16 * 72 + ks * 32 + quad * 8]);
#pragma unroll
        for (int nt = 0; nt < 8; ++nt) {
          const int d = nt * 16 + l16;
          const int q8 = ks * 4 + quad;
          bf16x8 b = *reinterpret_cast<const bf16x8*>(&SB2[d * 64 + ((q8 ^ (d & 7)) << 3)]);
          O[nt] = __builtin_amdgcn_mfma_f32_16x16x32_bf16(a, b, O[nt], 0, 0, 0);
        }
      }
    }

#pragma unroll
    for (int r = 0; r < 4; ++r) {
      const float inv = 1.0f / l_i[r];
#pragma unroll
      for (int nt = 0; nt < 8; ++nt) accS[nt][r] += O[nt][r] * inv;
    }
  }

#pragma unroll
  for (int r = 0; r < 4; ++r) {
    const int n = pidx[qg * 64 + wv * 16 + quad * 4 + r];
#pragma unroll
    for (int nt = 0; nt < 8; ++nt)
      locS[(size_t)n * 128 + nt * 16 + l16] = f2bf(accS[nt][r] * 0.25f);
  }
}

// ---------------------------------------------------------------------------
// K5: MFMA cross-attention, round 12 (= round 11 + exp2f hardening).
// Round-9 structure (LDS-staged B operands, verified) with:
//  - Q fragments in registers (no Qs buffer)
//  - split BsK/BsV -> 2 barriers/iter (was 4)
//  - T14: next chunk's globals loaded into regs right after the stage
//    barrier; they drain under QK+softmax+PV of the current chunk
//  - T13 defer-max (skip O-rescale when wave-wide max growth <= 8*SCALE)
//  - INV_SCALE folded into exp2 constant (scores stay unscaled)
// LDS 44 KiB -> 3 blocks/CU (same as round 9).
// ---------------------------------------------------------------------------
__global__ __launch_bounds__(256, 3) void k_cross(
    const ushort_t* __restrict__ Qb, const ushort_t* __restrict__ rpk,
    const ushort_t* __restrict__ rvT, ushort_t* __restrict__ glb)
{
  const int h = blockIdx.y;
  const int n0 = blockIdx.x * 64;
  const int tid = threadIdx.x, lane = tid & 63, wv = tid >> 6;
  const int l16 = lane & 15, quad = lane >> 4;

  __shared__ __align__(16) ushort_t BsK[64 * 136];   // 17 KiB rpk chunk
  __shared__ __align__(16) ushort_t BsV[128 * 72];   // 18 KiB rvT chunk
  __shared__ __align__(16) ushort_t Ps[4][16 * 72];  //  9 KiB wave-private

  // Q fragments (row = n0+wv*16+l16, k-chunk ks*32+quad*8). 16 VGPRs.
  bf16x8 qf[4];
  {
    const ushort_t* qrow =
        Qb + (size_t)(n0 + wv * 16 + l16) * 512 + h * 128 + quad * 8;
#pragma unroll
    for (int ks = 0; ks < 4; ++ks)
      qf[ks] = *reinterpret_cast<const bf16x8*>(qrow + ks * 32);
  }

  // Per-thread staging coordinates (identical tiling to round 9).
  const int kR = tid >> 4, kC = (tid & 15) * 8;   // K: rows kR+16i, col kC
  const int vD = tid >> 3, vC = (tid & 7) * 8;    // V: rows vD+32i, col vC

  // Prefetch chunk 0 into registers.
  uint4 vk[4], vv[4];
#pragma unroll
  for (int i = 0; i < 4; ++i) {
    vk[i] = *reinterpret_cast<const uint4*>(
        rpk + (size_t)(kR + 16 * i) * 512 + h * 128 + kC);
    vv[i] = *reinterpret_cast<const uint4*>(
        rvT + (size_t)(h * 128 + vD + 32 * i) * 512 + vC);
  }

  floatx4 O[8] = {};
  float m_i[4], l_i[4];
#pragma unroll
  for (int r = 0; r < 4; ++r) { m_i[r] = -3e38f; l_i[r] = 0.f; }

  for (int c = 0; c < 8; ++c) {
    __syncthreads();   // all waves done reading previous chunk's BsK/BsV
#pragma unroll
    for (int i = 0; i < 4; ++i) {
      *reinterpret_cast<uint4*>(&BsK[(kR + 16 * i) * 136 + kC]) = vk[i];
      *reinterpret_cast<uint4*>(&BsV[(vD + 32 * i) * 72 + vC]) = vv[i];
    }
    __syncthreads();   // staged data visible

    // T14: issue next chunk's loads now; they complete under compute.
    {
      const int cn = (c + 1) & 7;
#pragma unroll
      for (int i = 0; i < 4; ++i) {
        vk[i] = *reinterpret_cast<const uint4*>(
            rpk + (size_t)(cn * 64 + kR + 16 * i) * 512 + h * 128 + kC);
        vv[i] = *reinterpret_cast<const uint4*>(
            rvT + (size_t)(h * 128 + vD + 32 * i) * 512 + cn * 64 + vC);
      }
    }

    // ---- QK^T (unscaled scores) ----
    floatx4 S[4] = {};
#pragma unroll
    for (int ks = 0; ks < 4; ++ks) {
#pragma unroll
      for (int nt = 0; nt < 4; ++nt) {
        bf16x8 b = *reinterpret_cast<const bf16x8*>(
            &BsK[(nt * 16 + l16) * 136 + ks * 32 + quad * 8]);
        S[nt] = __builtin_amdgcn_mfma_f32_16x16x32_bf16(qf[ks], b, S[nt], 0, 0, 0);
      }
    }

    // ---- online softmax, exp2 domain, defer-max ----
#pragma unroll
    for (int r = 0; r < 4; ++r) {
      float cm = fmaxf(fmaxf(S[0][r], S[1][r]), fmaxf(S[2][r], S[3][r]));
#pragma unroll
      for (int off = 1; off <= 8; off <<= 1) cm = fmaxf(cm, __shfl_xor(cm, off));
      if (!__all(cm <= m_i[r] + DEFER_THR)) {
        const float mn = fmaxf(m_i[r], cm);
        const float sc = exp2f((m_i[r] - mn) * C2EXP);
        m_i[r] = mn;
        l_i[r] *= sc;
#pragma unroll
        for (int nt = 0; nt < 8; ++nt) O[nt][r] *= sc;
      }
      float ps = 0.f;
#pragma unroll
      for (int nt = 0; nt < 4; ++nt) {
        const float p = exp2f((S[nt][r] - m_i[r]) * C2EXP);
        ps += p;
        Ps[wv][(quad * 4 + r) * 72 + nt * 16 + l16] = f2bf(p);
      }
#pragma unroll
      for (int off = 1; off <= 8; off <<= 1) ps += __shfl_xor(ps, off);
      l_i[r] += ps;
    }
    // Ps write->read is within-wave (lgkmcnt-ordered, no barrier needed).

    // ---- PV ----
#pragma unroll
    for (int ks = 0; ks < 2; ++ks) {
      bf16x8 a = *reinterpret_cast<const bf16x8*>(&Ps[wv][l16 * 72 + ks * 32 + quad * 8]);
#pragma unroll
      for (int nt = 0; nt < 8; ++nt) {
        bf16x8 b = *reinterpret_cast<const bf16x8*>(
            &BsV[(nt * 16 + l16) * 72 + ks * 32 + quad * 8]);
        O[nt] = __builtin_amdgcn_mfma_f32_16x16x32_bf16(a, b, O[nt], 0, 0, 0);
      }
    }
  }

#pragma unroll
  for (int r = 0; r < 4; ++r) {
    const float inv = 1.0f / l_i[r];
    const int n = n0 + wv * 16 + quad * 4 + r;
#pragma unroll
    for (int nt = 0; nt < 8; ++nt)
      glb[(size_t)n * 512 + h * 128 + nt * 16 + l16] = f2bf(O[nt][r] * inv);
  }
}

// ---------------------------------------------------------------------------
// K6: combine -> f32 output.
// ---------------------------------------------------------------------------
__global__ __launch_bounds__(256) void k_combine(
    const ushort_t* __restrict__ locS, const ushort_t* __restrict__ glb,
    const ushort_t* __restrict__ Vb, const float* __restrict__ scal,
    float* __restrict__ out)
{
  const int t = blockIdx.x * 256 + threadIdx.x;
  const int n = t >> 6, dp = t & 63;
  const float alpha = 1.0f / (1.0f + __expf(-scal[0]));
  const float beta = scal[1];
  const uint32 lv = reinterpret_cast<const uint32*>(locS)[(size_t)n * 64 + dp];
  float g0 = 0.f, g1 = 0.f, v0 = 0.f, v1 = 0.f;
#pragma unroll
  for (int hh = 0; hh < 4; ++hh) {
    const uint32 gv = *reinterpret_cast<const uint32*>(glb + (size_t)n * 512 + hh * 128 + 2 * dp);
    const uint32 vv = *reinterpret_cast<const uint32*>(Vb + (size_t)n * 512 + hh * 128 + 2 * dp);
    g0 += bflo(gv); g1 += bfhi(gv);
    v0 += bflo(vv); v1 += bfhi(vv);
  }
  const float r0 = alpha * bflo(lv) + (1.0f - alpha) * g0 * 0.25f + beta * v0 * 0.25f;
  const float r1 = alpha * bfhi(lv) + (1.0f - alpha) * g1 * 0.25f + beta * v1 * 0.25f;
  reinterpret_cast<float2*>(out)[(size_t)n * 64 + dp] = make_float2(r0, r1);
}

extern "C" void kernel_launch(void* const* d_in, const int* in_sizes, int n_in,
                              void* d_out, int out_size, void* d_ws, size_t ws_size,
                              hipStream_t stream) {
  const void* x     = d_in[0];
  const int*  pidx  = (const int*)d_in[1];
  const void* Wq    = d_in[2];
  const void* bq    = d_in[3];
  const void* Wk    = d_in[4];
  const void* bk    = d_in[5];
  const void* Wv    = d_in[6];
  const void* bv    = d_in[7];
  const void* seeds = d_in[8];
  const void* al    = d_in[9];
  const void* be    = d_in[10];

  char* ws = (char*)d_ws;
  ushort_t* Qb   = (ushort_t*)(ws + OFF_Q);
  ushort_t* Kb   = (ushort_t*)(ws + OFF_K);
  ushort_t* Vb   = (ushort_t*)(ws + OFF_V);
  ushort_t* locS = (ushort_t*)(ws + OFF_LOC);
  ushort_t* rpk  = (ushort_t*)(ws + OFF_RPK);
  ushort_t* xc   = (ushort_t*)(ws + OFF_XC);
  ushort_t* wc   = (ushort_t*)(ws + OFF_WC);
  float*    scal = (float*)   (ws + OFF_SCAL);
  uint32*   flags= (uint32*)  (ws + OFF_FLAG);
  ushort_t* rvT  = (ushort_t*)(ws + OFF_RVT);
  ushort_t* glb  = (ushort_t*)(ws + OFF_GLB);

  k_detect<<<1, 64, 0, stream>>>((const uint32*)x, (const ushort_t*)be, flags);
  k_convert<<<dim3(4096, 2), 256, 0, stream>>>(x, Wq, bq, Wk, bk, Wv, bv, seeds, al, be,
                                               xc, wc, scal, flags);
  k_qkv<<<512, 256, 0, stream>>>(xc, wc, Qb, Kb, Vb);
  k_pool<<<dim3(128, 4), 256, 0, stream>>>(Kb, Vb, pidx, wc, rpk, rvT);
  k_fine<<<dim3(128, 4), 256, 0, stream>>>(Qb, Kb, Vb, pidx, locS);
  k_cross<<<dim3(512, 4), 256, 0, stream>>>(Qb, rpk, rvT, glb);
  k_combine<<<8192, 256, 0, stream>>>(locS, glb, Vb, scal, (float*)d_out);
}

// Round 4
// 392.226 us; speedup vs baseline: 1.3408x; 1.1785x over previous
//
#include <hip/hip_runtime.h>
#include <hip/hip_bf16.h>

// PCGTConvLayer round 13: k_cross staging rebuilt around
// __builtin_amdgcn_global_load_lds (width 16) + double-buffered unpadded
// BsK/BsV with XOR swizzle (pre-swizzled global source + swizzled ds_read,
// rule #21 / k_qkv's verified pattern). Round 12's VGPR-array prefetch
// spilled to scratch (+474 MB WRITE_SIZE, VGPR stuck at 80) -> replaced by
// LDS-direct async loads that use zero data VGPRs. One barrier per chunk.
// Keeps reg-resident Q, defer-max, exp2-domain softmax (harness-verified).
// All other kernels verbatim. N=32768 IN=256 D=128 H=4 M=4 KP=128 S=256.

#define INV_SCALE 0.08838834764831845f
// INV_SCALE * log2(e)
#define C2EXP 0.12751744f
// 8 / INV_SCALE  (defer-max threshold in unscaled-score domain)
#define DEFER_THR 90.50966799f

typedef __attribute__((ext_vector_type(8))) short bf16x8;
typedef __attribute__((ext_vector_type(4))) float floatx4;
typedef unsigned short ushort_t;
typedef unsigned int uint32;

// ---- ws layout (bytes) ----
#define OFF_Q    0ull            // bf16 [32768][512]
#define OFF_K    33554432ull     // bf16 [32768][512]
#define OFF_V    67108864ull     // bf16 [32768][512]
#define OFF_LOC  100663296ull    // bf16 [32768][128]
#define OFF_RPK  109051904ull    // bf16 [512][4][128]
#define OFF_XC   110100480ull    // bf16 [32768][256]
#define OFF_WC   126877696ull    // bf16: WqT,WkT,WvT ([512][256] each), biases, seeds
#define OFF_SCAL 127671296ull    // f32 [2]
#define OFF_FLAG 127671304ull    // u32 [2]
#define OFF_RVT  127672320ull    // bf16 [4][128][512]
#define OFF_GLB  128196608ull    // bf16 [32768][512]

#define WC_WQ 0
#define WC_WK 131072
#define WC_WV 262144
#define WC_BQ 393216
#define WC_BK 393728
#define WC_BV 394240
#define WC_SEED 394752
#define WC_TOT 396800

static __device__ __forceinline__ float bflo(uint32 u) {
  return __uint_as_float(u << 16);
}
static __device__ __forceinline__ float bfhi(uint32 u) {
  return __uint_as_float(u & 0xffff0000u);
}
static __device__ __forceinline__ float bf2f(ushort_t u) {
  return __uint_as_float(((uint32)u) << 16);
}
static __device__ __forceinline__ ushort_t f2bf(float f) {
  uint32 x = __float_as_uint(f);
  uint32 r = x + 0x7fffu + ((x >> 16) & 1u);
  return (ushort_t)(r >> 16);
}
static __device__ __forceinline__ uint32 pack2bf(float a, float b) {
  return (uint32)f2bf(a) | ((uint32)f2bf(b) << 16);
}

// async global -> LDS, 16 bytes per lane. LDS dest must be wave-uniform base;
// lane i lands at base + i*16 B. Global source is per-lane.
static __device__ __forceinline__ void gl2lds16(const ushort_t* g, ushort_t* l) {
  __builtin_amdgcn_global_load_lds(
      (const __attribute__((address_space(1))) void*)g,
      (__attribute__((address_space(3))) void*)l, 16, 0, 0);
}

// ---------------------------------------------------------------------------
__global__ __launch_bounds__(64) void k_detect(const uint32* __restrict__ xw,
                                               const ushort_t* __restrict__ betaRaw,
                                               uint32* __restrict__ flags) {
  const int lane = threadIdx.x;
  const uint32 w = xw[lane * 137 + 3];
  const int e = (w >> 7) & 0xff;
  const unsigned long long b = __ballot(e >= 100 && e <= 140);
  if (lane == 0) {
    flags[0] = (__popcll(b) >= 48) ? 1u : 0u;
    flags[1] = (betaRaw[0] != 0) ? 1u : 0u;
  }
}

// ---------------------------------------------------------------------------
// K1: canonicalize. x -> xc (identity layout). W matrices -> TRANSPOSED
// bf16 [512][256] at same wc offsets. biases/seeds identity.
// ---------------------------------------------------------------------------
static __device__ __forceinline__ void conv8(const void* src, long j, int isB,
                                             ushort_t* dst) {
  if (isB) {
    *reinterpret_cast<uint4*>(dst) =
        *reinterpret_cast<const uint4*>(reinterpret_cast<const ushort_t*>(src) + j);
  } else {
    const float* f = reinterpret_cast<const float*>(src) + j;
    const float4 a = *reinterpret_cast<const float4*>(f);
    const float4 b = *reinterpret_cast<const float4*>(f + 4);
    uint4 o;
    o.x = pack2bf(a.x, a.y); o.y = pack2bf(a.z, a.w);
    o.z = pack2bf(b.x, b.y); o.w = pack2bf(b.z, b.w);
    *reinterpret_cast<uint4*>(dst) = o;
  }
}

__global__ __launch_bounds__(256) void k_convert(
    const void* __restrict__ x,
    const void* __restrict__ Wq, const void* __restrict__ bq,
    const void* __restrict__ Wk, const void* __restrict__ bk,
    const void* __restrict__ Wv, const void* __restrict__ bv,
    const void* __restrict__ seeds, const void* __restrict__ alpha,
    const void* __restrict__ beta,
    ushort_t* __restrict__ xc, ushort_t* __restrict__ wc,
    float* __restrict__ scal, const uint32* __restrict__ flags)
{
  const int isB = (int)flags[0];
  const long i8 = ((long)blockIdx.x * 256 + threadIdx.x) * 8;
  if (blockIdx.y == 0) {
    conv8(x, i8, isB, xc + i8);
  } else {
    if (i8 < WC_BQ) {
      // W region: transpose. i8 = sel*131072 + k*512 + n (8 consecutive n).
      const int sel = (int)(i8 >> 17);
      const long local = i8 & 131071;
      const int kk = (int)(local >> 9);
      const int nn = (int)(local & 511);
      const void* src = sel == 0 ? Wq : (sel == 1 ? Wk : Wv);
      ushort_t* dstW = wc + sel * 131072;
#pragma unroll
      for (int j = 0; j < 8; ++j) {
        ushort_t v;
        if (isB) v = reinterpret_cast<const ushort_t*>(src)[local + j];
        else     v = f2bf(reinterpret_cast<const float*>(src)[local + j]);
        dstW[(size_t)(nn + j) * 256 + kk] = v;
      }
    } else if (i8 < WC_TOT) {
      const void* src; long j;
      if (i8 < WC_BK)        { src = bq;    j = i8 - WC_BQ; }
      else if (i8 < WC_BV)   { src = bk;    j = i8 - WC_BK; }
      else if (i8 < WC_SEED) { src = bv;    j = i8 - WC_BV; }
      else                   { src = seeds; j = i8 - WC_SEED; }
      conv8(src, j, isB, wc + i8);
    }
    if (blockIdx.x == 0 && threadIdx.x == 0) {
      const int isBS = (int)flags[1];
      scal[0] = isBS ? bf2f(reinterpret_cast<const ushort_t*>(alpha)[0])
                     : reinterpret_cast<const float*>(alpha)[0];
      scal[1] = isBS ? bf2f(reinterpret_cast<const ushort_t*>(beta)[0])
                     : reinterpret_cast<const float*>(beta)[0];
    }
  }
}

// ---------------------------------------------------------------------------
// K2: fused QKV GEMM. One block = 64 rows of x; loops sel(3) x 8 col-chunks.
// Xs staged ONCE (XOR-swizzled: chunk c of row at ((c^(row&7))<<3)); Ws from
// W^T with identical swizzle via coalesced uint4. MFMA 16x16x32, wave =
// 16 rows x 64 cols per chunk. LDS exactly 64 KiB.
// ---------------------------------------------------------------------------
__global__ __launch_bounds__(256) void k_qkv(
    const ushort_t* __restrict__ xc, const ushort_t* __restrict__ wc,
    ushort_t* __restrict__ Qb, ushort_t* __restrict__ Kb, ushort_t* __restrict__ Vb)
{
  const int m0 = blockIdx.x * 64;
  const int tid = threadIdx.x, lane = tid & 63, wv = tid >> 6;
  const int l16 = lane & 15, quad = lane >> 4;

  __shared__ __align__(16) ushort_t Xs[64 * 256];   // 32 KiB
  __shared__ __align__(16) ushort_t Ws[64 * 256];   // 32 KiB

#pragma unroll
  for (int i = 0; i < 8; ++i) {
    const int id = tid + 256 * i;          // 2048 chunks of 8
    const int row = id >> 5, c = id & 31;
    uint4 v = *reinterpret_cast<const uint4*>(xc + (size_t)(m0 + row) * 256 + c * 8);
    *reinterpret_cast<uint4*>(&Xs[row * 256 + ((c ^ (row & 7)) << 3)]) = v;
  }

  for (int sel = 0; sel < 3; ++sel) {
    const ushort_t* WT   = wc + sel * 131072;
    const ushort_t* bias = wc + WC_BQ + sel * 512;
    ushort_t* out        = sel == 0 ? Qb : (sel == 1 ? Kb : Vb);
    for (int nc = 0; nc < 8; ++nc) {
      const int n0 = nc * 64;
      __syncthreads();   // prev chunk's Ws readers done (also orders Xs staging)
#pragma unroll
      for (int i = 0; i < 8; ++i) {
        const int id = tid + 256 * i;
        const int row = id >> 5, c = id & 31;
        uint4 v = *reinterpret_cast<const uint4*>(WT + (size_t)(n0 + row) * 256 + c * 8);
        *reinterpret_cast<uint4*>(&Ws[row * 256 + ((c ^ (row & 7)) << 3)]) = v;
      }
      __syncthreads();

      floatx4 acc[4] = {};
      const int arow = wv * 16 + l16;
#pragma unroll
      for (int ks = 0; ks < 8; ++ks) {
        const int ac = ks * 4 + quad;
        bf16x8 a = *reinterpret_cast<const bf16x8*>(&Xs[arow * 256 + ((ac ^ (arow & 7)) << 3)]);
#pragma unroll
        for (int nt = 0; nt < 4; ++nt) {
          const int brow = nt * 16 + l16;
          bf16x8 b = *reinterpret_cast<const bf16x8*>(&Ws[brow * 256 + ((ac ^ (brow & 7)) << 3)]);
          acc[nt] = __builtin_amdgcn_mfma_f32_16x16x32_bf16(a, b, acc[nt], 0, 0, 0);
        }
      }

#pragma unroll
      for (int nt = 0; nt < 4; ++nt) {
        const int col = n0 + nt * 16 + l16;
        const float bf = bf2f(bias[col]);
#pragma unroll
        for (int r = 0; r < 4; ++r) {
          const int row = m0 + wv * 16 + quad * 4 + r;
          out[(size_t)row * 512 + col] = f2bf(acc[nt][r] + bf);
        }
      }
    }
  }
}

// ---------------------------------------------------------------------------
// K3: pooling (seeds -> rpk, rvT). Verified (CHK3).
// ---------------------------------------------------------------------------
__global__ __launch_bounds__(256) void k_pool(
    const ushort_t* __restrict__ Kb, const ushort_t* __restrict__ Vb,
    const int* __restrict__ pidx_all, const ushort_t* __restrict__ wc,
    ushort_t* __restrict__ rpk, ushort_t* __restrict__ rvT)
{
  const int k = blockIdx.x, h = blockIdx.y;
  const int tid = threadIdx.x, lane = tid & 63, wv = tid >> 6;
  const int* pidx = pidx_all + k * 256;

  __shared__ __align__(16) ushort_t SB[128 * 256];
  const uint32* SBU = reinterpret_cast<const uint32*>(SB);

#pragma unroll
  for (int i = 0; i < 16; ++i) {
    const int e8 = tid + 256 * i;
    const int q = e8 >> 4, dc = (e8 & 15) * 8;
    uint4 kv = *reinterpret_cast<const uint4*>(Kb + (size_t)pidx[q] * 512 + h * 128 + dc);
    const ushort_t* ku = reinterpret_cast<const ushort_t*>(&kv);
    const int qp = q >> 1, qb = q & 1;
#pragma unroll
    for (int j = 0; j < 8; ++j) {
      const int d = dc + j;
      SB[d * 256 + (((qp ^ (d & 31)) << 1) | qb)] = ku[j];
    }
  }
  __syncthreads();

  float q00, q01, q10, q11;
  {
    const uint32* ssrc = reinterpret_cast<const uint32*>(wc + WC_SEED + (size_t)(wv * 4 + h) * 128);
    float s00 = 0.f, s01 = 0.f, s10 = 0.f, s11 = 0.f;
#pragma unroll 8
    for (int dc = 0; dc < 64; ++dc) {
      const uint32 qv = ssrc[dc];
      const float a0 = bflo(qv), a1 = bfhi(qv);
      const int d0 = dc * 2, d1 = d0 + 1;
      const int c0 = lane ^ (d0 & 31);
      const int c1 = lane ^ (d1 & 31);
      const uint32 u00 = SBU[d0 * 128 + c0];
      const uint32 u01 = SBU[d0 * 128 + c0 + 64];
      const uint32 u10 = SBU[d1 * 128 + c1];
      const uint32 u11 = SBU[d1 * 128 + c1 + 64];
      s00 += a0 * bflo(u00) + a1 * bflo(u10);
      s01 += a0 * bfhi(u00) + a1 * bfhi(u10);
      s10 += a0 * bflo(u01) + a1 * bflo(u11);
      s11 += a0 * bfhi(u01) + a1 * bfhi(u11);
    }
    s00 *= INV_SCALE; s01 *= INV_SCALE; s10 *= INV_SCALE; s11 *= INV_SCALE;
    float mx = fmaxf(fmaxf(s00, s01), fmaxf(s10, s11));
#pragma unroll
    for (int off = 32; off >= 1; off >>= 1) mx = fmaxf(mx, __shfl_xor(mx, off));
    const float e00 = __expf(s00 - mx), e01 = __expf(s01 - mx);
    const float e10 = __expf(s10 - mx), e11 = __expf(s11 - mx);
    float sm = e00 + e01 + e10 + e11;
#pragma unroll
    for (int off = 32; off >= 1; off >>= 1) sm += __shfl_xor(sm, off);
    const float inv = 1.0f / sm;
    q00 = e00 * inv; q01 = e01 * inv; q10 = e10 * inv; q11 = e11 * inv;
  }

  {
    float rk0 = 0.f, rk1 = 0.f;
    const int d0 = 2 * lane, d1 = 2 * lane + 1;
#pragma unroll 4
    for (int qp = 0; qp < 64; ++qp) {
      const float pa = __shfl(q00, qp), pb = __shfl(q01, qp);
      const float pc = __shfl(q10, qp), pd = __shfl(q11, qp);
      const int c0 = qp ^ (d0 & 31);
      const int c1 = qp ^ (d1 & 31);
      const uint32 u0  = SBU[d0 * 128 + c0];
      const uint32 u0b = SBU[d0 * 128 + c0 + 64];
      const uint32 u1  = SBU[d1 * 128 + c1];
      const uint32 u1b = SBU[d1 * 128 + c1 + 64];
      rk0 += pa * bflo(u0) + pb * bfhi(u0) + pc * bflo(u0b) + pd * bfhi(u0b);
      rk1 += pa * bflo(u1) + pb * bfhi(u1) + pc * bflo(u1b) + pd * bfhi(u1b);
    }
    reinterpret_cast<uint32*>(rpk + ((size_t)((k * 4 + wv) * 4 + h)) * 128)[lane] = pack2bf(rk0, rk1);
  }
  __syncthreads();

#pragma unroll
  for (int i = 0; i < 16; ++i) {
    const int e8 = tid + 256 * i;
    const int q = e8 >> 4, dc = (e8 & 15) * 8;
    uint4 vv = *reinterpret_cast<const uint4*>(Vb + (size_t)pidx[q] * 512 + h * 128 + dc);
    *reinterpret_cast<uint4*>(&SB[q * 128 + dc]) = vv;
  }
  __syncthreads();

  {
    float rv0 = 0.f, rv1 = 0.f;
#pragma unroll 4
    for (int qp = 0; qp < 64; ++qp) {
      const float pa = __shfl(q00, qp), pb = __shfl(q01, qp);
      const float pc = __shfl(q10, qp), pd = __shfl(q11, qp);
      const uint32 v00 = SBU[(2 * qp) * 64 + lane];
      const uint32 v01 = SBU[(2 * qp + 1) * 64 + lane];
      const uint32 v10 = SBU[(128 + 2 * qp) * 64 + lane];
      const uint32 v11 = SBU[(129 + 2 * qp) * 64 + lane];
      rv0 += pa * bflo(v00) + pb * bflo(v01) + pc * bflo(v10) + pd * bflo(v11);
      rv1 += pa * bfhi(v00) + pb * bfhi(v01) + pc * bfhi(v10) + pd * bfhi(v11);
    }
    const int rrep = k * 4 + wv;
    rvT[(size_t)(h * 128 + 2 * lane) * 512 + rrep]     = f2bf(rv0);
    rvT[(size_t)(h * 128 + 2 * lane + 1) * 512 + rrep] = f2bf(rv1);
  }
}

// ---------------------------------------------------------------------------
// K4: MFMA fine attention (verified round 8).
// ---------------------------------------------------------------------------
__global__ __launch_bounds__(256) void k_fine(
    const ushort_t* __restrict__ Qb, const ushort_t* __restrict__ Kb,
    const ushort_t* __restrict__ Vb, const int* __restrict__ pidx_all,
    ushort_t* __restrict__ locS)
{
  const int k = blockIdx.x, qg = blockIdx.y;
  const int tid = threadIdx.x, lane = tid & 63, wv = tid >> 6;
  const int l16 = lane & 15, quad = lane >> 4;
  const int* pidx = pidx_all + k * 256;

  __shared__ __align__(16) ushort_t Qs[64 * 136];
  __shared__ __align__(16) ushort_t SB2[64 * 136];
  __shared__ __align__(16) ushort_t Ps[4][16 * 72];

  float accS[8][4];
#pragma unroll
  for (int nt = 0; nt < 8; ++nt)
#pragma unroll
    for (int r = 0; r < 4; ++r) accS[nt][r] = 0.f;

  for (int h = 0; h < 4; ++h) {
    __syncthreads();
#pragma unroll
    for (int i = 0; i < 4; ++i) {
      const int e = tid + 256 * i;
      const int r = e >> 4, c8 = (e & 15) * 8;
      uint4 v = *reinterpret_cast<const uint4*>(Qb + (size_t)pidx[qg * 64 + r] * 512 + h * 128 + c8);
      *reinterpret_cast<uint4*>(&Qs[r * 136 + c8]) = v;
    }

    floatx4 O[8] = {};
    float m_i[4], l_i[4];
#pragma unroll
    for (int r = 0; r < 4; ++r) { m_i[r] = -3e38f; l_i[r] = 0.f; }

    for (int c = 0; c < 4; ++c) {
      __syncthreads();
#pragma unroll
      for (int i = 0; i < 4; ++i) {
        const int e = tid + 256 * i;
        const int r = e >> 4, c8 = (e & 15) * 8;
        uint4 v = *reinterpret_cast<const uint4*>(Kb + (size_t)pidx[c * 64 + r] * 512 + h * 128 + c8);
        *reinterpret_cast<uint4*>(&SB2[r * 136 + c8]) = v;
      }
      __syncthreads();

      floatx4 S[4] = {};
#pragma unroll
      for (int ks = 0; ks < 4; ++ks) {
        bf16x8 a = *reinterpret_cast<const bf16x8*>(&Qs[(wv * 16 + l16) * 136 + ks * 32 + quad * 8]);
#pragma unroll
        for (int nt = 0; nt < 4; ++nt) {
          bf16x8 b = *reinterpret_cast<const bf16x8*>(&SB2[(nt * 16 + l16) * 136 + ks * 32 + quad * 8]);
          S[nt] = __builtin_amdgcn_mfma_f32_16x16x32_bf16(a, b, S[nt], 0, 0, 0);
        }
      }
#pragma unroll
      for (int nt = 0; nt < 4; ++nt)
#pragma unroll
        for (int r = 0; r < 4; ++r) S[nt][r] *= INV_SCALE;

#pragma unroll
      for (int r = 0; r < 4; ++r) {
        float cm = fmaxf(fmaxf(S[0][r], S[1][r]), fmaxf(S[2][r], S[3][r]));
#pragma unroll
        for (int off = 1; off <= 8; off <<= 1) cm = fmaxf(cm, __shfl_xor(cm, off));
        const float mn = fmaxf(m_i[r], cm);
        const float sc = __expf(m_i[r] - mn);
        m_i[r] = mn;
        l_i[r] *= sc;
#pragma unroll
        for (int nt = 0; nt < 8; ++nt) O[nt][r] *= sc;
        float ps = 0.f;
#pragma unroll
        for (int nt = 0; nt < 4; ++nt) {
          const float p = __expf(S[nt][r] - mn);
          ps += p;
          Ps[wv][(quad * 4 + r) * 72 + nt * 16 + l16] = f2bf(p);
        }
#pragma unroll
        for (int off = 1; off <= 8; off <<= 1) ps += __shfl_xor(ps, off);
        l_i[r] += ps;
      }
      __syncthreads();

#pragma unroll
      for (int i = 0; i < 4; ++i) {
        const int e = tid + 256 * i;
        const int key = e & 63, dc8 = (e >> 6) * 8;
        uint4 vv = *reinterpret_cast<const uint4*>(Vb + (size_t)pidx[c * 64 + key] * 512 + h * 128 + dc8);
        const ushort_t* u = reinterpret_cast<const ushort_t*>(&vv);
#pragma unroll
        for (int j = 0; j < 8; ++j) {
          const int d = dc8 + j;
          SB2[d * 64 + (((key >> 3) ^ j) << 3) + (key & 7)] = u[j];
        }
      }
      __syncthreads();

#pragma unroll
      for (int ks = 0; ks < 2; ++ks) {
        bf16x8 a = *reinterpret_cast<const bf16x8*>(&Ps[wv][l16 * 72 + ks * 32 + quad * 8]);
#pragma unroll
        for (int nt = 0; nt < 8; ++nt) {
          const int d = nt * 16 + l16;
          const int q8 = ks * 4 + quad;
          bf16x8 b = *reinterpret_cast<const bf16x8*>(&SB2[d * 64 + ((q8 ^ (d & 7)) << 3)]);
          O[nt] = __builtin_amdgcn_mfma_f32_16x16x32_bf16(a, b, O[nt], 0, 0, 0);
        }
      }
    }

#pragma unroll
    for (int r = 0; r < 4; ++r) {
      const float inv = 1.0f / l_i[r];
#pragma unroll
      for (int nt = 0; nt < 8; ++nt) accS[nt][r] += O[nt][r] * inv;
    }
  }

#pragma unroll
  for (int r = 0; r < 4; ++r) {
    const int n = pidx[qg * 64 + wv * 16 + quad * 4 + r];
#pragma unroll
    for (int nt = 0; nt < 8; ++nt)
      locS[(size_t)n * 128 + nt * 16 + l16] = f2bf(accS[nt][r] * 0.25f);
  }
}

// ---------------------------------------------------------------------------
// K5: MFMA cross-attention, round 13.
// Double-buffered BsK/BsV staged via global_load_lds (width 16, zero data
// VGPRs). Unpadded tiles with XOR swizzle: LDS chunk c' of row r holds
// global chunk (c'^(r&7)); ds_read uses chunk (ac^(r&7)) -> conflict-free
// (2-way max). One __syncthreads per chunk (compiler's implicit vmcnt(0)
// drain doubles as the load fence). Reg-resident Q, defer-max, exp2 softmax.
// LDS: 2*16K (BsK) + 2*16K (BsV) + 9K (Ps) = 73 KiB -> 2 blocks/CU.
// ---------------------------------------------------------------------------
__global__ __launch_bounds__(256, 2) void k_cross(
    const ushort_t* __restrict__ Qb, const ushort_t* __restrict__ rpk,
    const ushort_t* __restrict__ rvT, ushort_t* __restrict__ glb)
{
  const int h = blockIdx.y;
  const int n0 = blockIdx.x * 64;
  const int tid = threadIdx.x, lane = tid & 63, wv = tid >> 6;
  const int l16 = lane & 15, quad = lane >> 4;

  __shared__ __align__(16) ushort_t BsK[2][64 * 128];   // 2 x 16 KiB
  __shared__ __align__(16) ushort_t BsV[2][128 * 64];   // 2 x 16 KiB
  __shared__ __align__(16) ushort_t Ps[4][16 * 72];     // 9 KiB wave-private

  // Q fragments (row = n0+wv*16+l16, k-chunk ks*32+quad*8). 16 VGPRs.
  bf16x8 qf[4];
  {
    const ushort_t* qrow =
        Qb + (size_t)(n0 + wv * 16 + l16) * 512 + h * 128 + quad * 8;
#pragma unroll
    for (int ks = 0; ks < 4; ++ks)
      qf[ks] = *reinterpret_cast<const bf16x8*>(qrow + ks * 32);
  }

  // Per-lane staging source coordinates.
  const int kRL = lane >> 4;        // row-in-group 0..3 (K)
  const int kCH = lane & 15;        // 16B chunk 0..15  (K)
  const int vDL = lane >> 3;        // row-in-group 0..7 (V)
  const int vCH = lane & 7;         // 16B chunk 0..7   (V)

  floatx4 O[8] = {};
  float m_i[4], l_i[4];
#pragma unroll
  for (int r = 0; r < 4; ++r) { m_i[r] = -3e38f; l_i[r] = 0.f; }

  // Prologue: stage chunk 0 into buffer 0.
  {
#pragma unroll
    for (int j = 0; j < 4; ++j) {
      const int row = wv * 16 + j * 4 + kRL;     // 0..63
      gl2lds16(rpk + (size_t)row * 512 + h * 128 + ((kCH ^ (row & 7)) << 3),
               &BsK[0][(wv * 16 + j * 4) * 128]);
      const int d = wv * 32 + j * 8 + vDL;       // 0..127
      gl2lds16(rvT + (size_t)(h * 128 + d) * 512 + ((vCH ^ (d & 7)) << 3),
               &BsV[0][(wv * 32 + j * 8) * 64]);
    }
  }
  __syncthreads();   // implicit vmcnt(0): chunk 0 landed

  const int kswz = l16 & 7;   // row&7 for all fragment rows this lane reads

  for (int c = 0; c < 8; ++c) {
    const int cur = c & 1;

    // Stage next chunk into the other buffer; loads fly under this chunk's
    // compute and are drained by the barrier at the end of the iteration.
    if (c < 7) {
      const int nb = cur ^ 1;
      const int cn = c + 1;
#pragma unroll
      for (int j = 0; j < 4; ++j) {
        const int row = wv * 16 + j * 4 + kRL;
        gl2lds16(rpk + (size_t)(cn * 64 + row) * 512 + h * 128 +
                     ((kCH ^ (row & 7)) << 3),
                 &BsK[nb][(wv * 16 + j * 4) * 128]);
        const int d = wv * 32 + j * 8 + vDL;
        gl2lds16(rvT + (size_t)(h * 128 + d) * 512 + cn * 64 +
                     ((vCH ^ (d & 7)) << 3),
                 &BsV[nb][(wv * 32 + j * 8) * 64]);
      }
    }

    // ---- QK^T (unscaled scores) ----
    floatx4 S[4] = {};
#pragma unroll
    for (int ks = 0; ks < 4; ++ks) {
      const int ac = ks * 4 + quad;
#pragma unroll
      for (int nt = 0; nt < 4; ++nt) {
        bf16x8 b = *reinterpret_cast<const bf16x8*>(
            &BsK[cur][(nt * 16 + l16) * 128 + ((ac ^ kswz) << 3)]);
        S[nt] = __builtin_amdgcn_mfma_f32_16x16x32_bf16(qf[ks], b, S[nt], 0, 0, 0);
      }
    }

    // ---- online softmax, exp2 domain, defer-max ----
#pragma unroll
    for (int r = 0; r < 4; ++r) {
      float cm = fmaxf(fmaxf(S[0][r], S[1][r]), fmaxf(S[2][r], S[3][r]));
#pragma unroll
      for (int off = 1; off <= 8; off <<= 1) cm = fmaxf(cm, __shfl_xor(cm, off));
      if (!__all(cm <= m_i[r] + DEFER_THR)) {
        const float mn = fmaxf(m_i[r], cm);
        const float sc = exp2f((m_i[r] - mn) * C2EXP);
        m_i[r] = mn;
        l_i[r] *= sc;
#pragma unroll
        for (int nt = 0; nt < 8; ++nt) O[nt][r] *= sc;
      }
      float ps = 0.f;
#pragma unroll
      for (int nt = 0; nt < 4; ++nt) {
        const float p = exp2f((S[nt][r] - m_i[r]) * C2EXP);
        ps += p;
        Ps[wv][(quad * 4 + r) * 72 + nt * 16 + l16] = f2bf(p);
      }
#pragma unroll
      for (int off = 1; off <= 8; off <<= 1) ps += __shfl_xor(ps, off);
      l_i[r] += ps;
    }
    // Ps write->read is within-wave (lgkmcnt-ordered, no barrier needed).

    // ---- PV ----
#pragma unroll
    for (int ks = 0; ks < 2; ++ks) {
      bf16x8 a = *reinterpret_cast<const bf16x8*>(&Ps[wv][l16 * 72 + ks * 32 + quad * 8]);
#pragma unroll
      for (int nt = 0; nt < 8; ++nt) {
        const int q8 = ks * 4 + quad;
        bf16x8 b = *reinterpret_cast<const bf16x8*>(
            &BsV[cur][(nt * 16 + l16) * 64 + ((q8 ^ kswz) << 3)]);
        O[nt] = __builtin_amdgcn_mfma_f32_16x16x32_bf16(a, b, O[nt], 0, 0, 0);
      }
    }

    __syncthreads();   // drains next-chunk loads; all waves done with 'cur'
  }

#pragma unroll
  for (int r = 0; r < 4; ++r) {
    const float inv = 1.0f / l_i[r];
    const int n = n0 + wv * 16 + quad * 4 + r;
#pragma unroll
    for (int nt = 0; nt < 8; ++nt)
      glb[(size_t)n * 512 + h * 128 + nt * 16 + l16] = f2bf(O[nt][r] * inv);
  }
}

// ---------------------------------------------------------------------------
// K6: combine -> f32 output.
// ---------------------------------------------------------------------------
__global__ __launch_bounds__(256) void k_combine(
    const ushort_t* __restrict__ locS, const ushort_t* __restrict__ glb,
    const ushort_t* __restrict__ Vb, const float* __restrict__ scal,
    float* __restrict__ out)
{
  const int t = blockIdx.x * 256 + threadIdx.x;
  const int n = t >> 6, dp = t & 63;
  const float alpha = 1.0f / (1.0f + __expf(-scal[0]));
  const float beta = scal[1];
  const uint32 lv = reinterpret_cast<const uint32*>(locS)[(size_t)n * 64 + dp];
  float g0 = 0.f, g1 = 0.f, v0 = 0.f, v1 = 0.f;
#pragma unroll
  for (int hh = 0; hh < 4; ++hh) {
    const uint32 gv = *reinterpret_cast<const uint32*>(glb + (size_t)n * 512 + hh * 128 + 2 * dp);
    const uint32 vv = *reinterpret_cast<const uint32*>(Vb + (size_t)n * 512 + hh * 128 + 2 * dp);
    g0 += bflo(gv); g1 += bfhi(gv);
    v0 += bflo(vv); v1 += bfhi(vv);
  }
  const float r0 = alpha * bflo(lv) + (1.0f - alpha) * g0 * 0.25f + beta * v0 * 0.25f;
  const float r1 = alpha * bfhi(lv) + (1.0f - alpha) * g1 * 0.25f + beta * v1 * 0.25f;
  reinterpret_cast<float2*>(out)[(size_t)n * 64 + dp] = make_float2(r0, r1);
}

extern "C" void kernel_launch(void* const* d_in, const int* in_sizes, int n_in,
                              void* d_out, int out_size, void* d_ws, size_t ws_size,
                              hipStream_t stream) {
  const void* x     = d_in[0];
  const int*  pidx  = (const int*)d_in[1];
  const void* Wq    = d_in[2];
  const void* bq    = d_in[3];
  const void* Wk    = d_in[4];
  const void* bk    = d_in[5];
  const void* Wv    = d_in[6];
  const void* bv    = d_in[7];
  const void* seeds = d_in[8];
  const void* al    = d_in[9];
  const void* be    = d_in[10];

  char* ws = (char*)d_ws;
  ushort_t* Qb   = (ushort_t*)(ws + OFF_Q);
  ushort_t* Kb   = (ushort_t*)(ws + OFF_K);
  ushort_t* Vb   = (ushort_t*)(ws + OFF_V);
  ushort_t* locS = (ushort_t*)(ws + OFF_LOC);
  ushort_t* rpk  = (ushort_t*)(ws + OFF_RPK);
  ushort_t* xc   = (ushort_t*)(ws + OFF_XC);
  ushort_t* wc   = (ushort_t*)(ws + OFF_WC);
  float*    scal = (float*)   (ws + OFF_SCAL);
  uint32*   flags= (uint32*)  (ws + OFF_FLAG);
  ushort_t* rvT  = (ushort_t*)(ws + OFF_RVT);
  ushort_t* glb  = (ushort_t*)(ws + OFF_GLB);

  k_detect<<<1, 64, 0, stream>>>((const uint32*)x, (const ushort_t*)be, flags);
  k_convert<<<dim3(4096, 2), 256, 0, stream>>>(x, Wq, bq, Wk, bk, Wv, bv, seeds, al, be,
                                               xc, wc, scal, flags);
  k_qkv<<<512, 256, 0, stream>>>(xc, wc, Qb, Kb, Vb);
  k_pool<<<dim3(128, 4), 256, 0, stream>>>(Kb, Vb, pidx, wc, rpk, rvT);
  k_fine<<<dim3(128, 4), 256, 0, stream>>>(Qb, Kb, Vb, pidx, locS);
  k_cross<<<dim3(512, 4), 256, 0, stream>>>(Qb, rpk, rvT, glb);
  k_combine<<<8192, 256, 0, stream>>>(locS, glb, Vb, scal, (float*)d_out);
}

// Round 5
// 366.516 us; speedup vs baseline: 1.4349x; 1.0701x over previous
//
#include <hip/hip_runtime.h>
#include <hip/hip_bf16.h>

// PCGTConvLayer round 14: k_cross softmax rewritten in SWAPPED-QK^T domain.
// mfma(K_frag, Q_frag) gives S^T (lane holds 16 scores of ONE q-row, reps
// lane-local) at zero operand cost (A/B frag lane maps identical on gfx950).
// Row reduce: 15 local fmax/add + 2 shfl_xor (was 4x4 shfl chains) -> cuts
// the 44% VALUBusy serial-shuffle critical path. m/l are scalars; Ps writes
// become 4 aligned b64 stores; PV and round-13 async staging unchanged.
// All other kernels verbatim. N=32768 IN=256 D=128 H=4 M=4 KP=128 S=256.

#define INV_SCALE 0.08838834764831845f
// INV_SCALE * log2(e)
#define C2EXP 0.12751744f
// 8 / INV_SCALE  (defer-max threshold in unscaled-score domain)
#define DEFER_THR 90.50966799f

typedef __attribute__((ext_vector_type(8))) short bf16x8;
typedef __attribute__((ext_vector_type(4))) float floatx4;
typedef unsigned short ushort_t;
typedef unsigned int uint32;

// ---- ws layout (bytes) ----
#define OFF_Q    0ull            // bf16 [32768][512]
#define OFF_K    33554432ull     // bf16 [32768][512]
#define OFF_V    67108864ull     // bf16 [32768][512]
#define OFF_LOC  100663296ull    // bf16 [32768][128]
#define OFF_RPK  109051904ull    // bf16 [512][4][128]
#define OFF_XC   110100480ull    // bf16 [32768][256]
#define OFF_WC   126877696ull    // bf16: WqT,WkT,WvT ([512][256] each), biases, seeds
#define OFF_SCAL 127671296ull    // f32 [2]
#define OFF_FLAG 127671304ull    // u32 [2]
#define OFF_RVT  127672320ull    // bf16 [4][128][512]
#define OFF_GLB  128196608ull    // bf16 [32768][512]

#define WC_WQ 0
#define WC_WK 131072
#define WC_WV 262144
#define WC_BQ 393216
#define WC_BK 393728
#define WC_BV 394240
#define WC_SEED 394752
#define WC_TOT 396800

static __device__ __forceinline__ float bflo(uint32 u) {
  return __uint_as_float(u << 16);
}
static __device__ __forceinline__ float bfhi(uint32 u) {
  return __uint_as_float(u & 0xffff0000u);
}
static __device__ __forceinline__ float bf2f(ushort_t u) {
  return __uint_as_float(((uint32)u) << 16);
}
static __device__ __forceinline__ ushort_t f2bf(float f) {
  uint32 x = __float_as_uint(f);
  uint32 r = x + 0x7fffu + ((x >> 16) & 1u);
  return (ushort_t)(r >> 16);
}
static __device__ __forceinline__ uint32 pack2bf(float a, float b) {
  return (uint32)f2bf(a) | ((uint32)f2bf(b) << 16);
}

// async global -> LDS, 16 bytes per lane. LDS dest must be wave-uniform base;
// lane i lands at base + i*16 B. Global source is per-lane.
static __device__ __forceinline__ void gl2lds16(const ushort_t* g, ushort_t* l) {
  __builtin_amdgcn_global_load_lds(
      (const __attribute__((address_space(1))) void*)g,
      (__attribute__((address_space(3))) void*)l, 16, 0, 0);
}

// ---------------------------------------------------------------------------
__global__ __launch_bounds__(64) void k_detect(const uint32* __restrict__ xw,
                                               const ushort_t* __restrict__ betaRaw,
                                               uint32* __restrict__ flags) {
  const int lane = threadIdx.x;
  const uint32 w = xw[lane * 137 + 3];
  const int e = (w >> 7) & 0xff;
  const unsigned long long b = __ballot(e >= 100 && e <= 140);
  if (lane == 0) {
    flags[0] = (__popcll(b) >= 48) ? 1u : 0u;
    flags[1] = (betaRaw[0] != 0) ? 1u : 0u;
  }
}

// ---------------------------------------------------------------------------
// K1: canonicalize. x -> xc (identity layout). W matrices -> TRANSPOSED
// bf16 [512][256] at same wc offsets. biases/seeds identity.
// ---------------------------------------------------------------------------
static __device__ __forceinline__ void conv8(const void* src, long j, int isB,
                                             ushort_t* dst) {
  if (isB) {
    *reinterpret_cast<uint4*>(dst) =
        *reinterpret_cast<const uint4*>(reinterpret_cast<const ushort_t*>(src) + j);
  } else {
    const float* f = reinterpret_cast<const float*>(src) + j;
    const float4 a = *reinterpret_cast<const float4*>(f);
    const float4 b = *reinterpret_cast<const float4*>(f + 4);
    uint4 o;
    o.x = pack2bf(a.x, a.y); o.y = pack2bf(a.z, a.w);
    o.z = pack2bf(b.x, b.y); o.w = pack2bf(b.z, b.w);
    *reinterpret_cast<uint4*>(dst) = o;
  }
}

__global__ __launch_bounds__(256) void k_convert(
    const void* __restrict__ x,
    const void* __restrict__ Wq, const void* __restrict__ bq,
    const void* __restrict__ Wk, const void* __restrict__ bk,
    const void* __restrict__ Wv, const void* __restrict__ bv,
    const void* __restrict__ seeds, const void* __restrict__ alpha,
    const void* __restrict__ beta,
    ushort_t* __restrict__ xc, ushort_t* __restrict__ wc,
    float* __restrict__ scal, const uint32* __restrict__ flags)
{
  const int isB = (int)flags[0];
  const long i8 = ((long)blockIdx.x * 256 + threadIdx.x) * 8;
  if (blockIdx.y == 0) {
    conv8(x, i8, isB, xc + i8);
  } else {
    if (i8 < WC_BQ) {
      // W region: transpose. i8 = sel*131072 + k*512 + n (8 consecutive n).
      const int sel = (int)(i8 >> 17);
      const long local = i8 & 131071;
      const int kk = (int)(local >> 9);
      const int nn = (int)(local & 511);
      const void* src = sel == 0 ? Wq : (sel == 1 ? Wk : Wv);
      ushort_t* dstW = wc + sel * 131072;
#pragma unroll
      for (int j = 0; j < 8; ++j) {
        ushort_t v;
        if (isB) v = reinterpret_cast<const ushort_t*>(src)[local + j];
        else     v = f2bf(reinterpret_cast<const float*>(src)[local + j]);
        dstW[(size_t)(nn + j) * 256 + kk] = v;
      }
    } else if (i8 < WC_TOT) {
      const void* src; long j;
      if (i8 < WC_BK)        { src = bq;    j = i8 - WC_BQ; }
      else if (i8 < WC_BV)   { src = bk;    j = i8 - WC_BK; }
      else if (i8 < WC_SEED) { src = bv;    j = i8 - WC_BV; }
      else                   { src = seeds; j = i8 - WC_SEED; }
      conv8(src, j, isB, wc + i8);
    }
    if (blockIdx.x == 0 && threadIdx.x == 0) {
      const int isBS = (int)flags[1];
      scal[0] = isBS ? bf2f(reinterpret_cast<const ushort_t*>(alpha)[0])
                     : reinterpret_cast<const float*>(alpha)[0];
      scal[1] = isBS ? bf2f(reinterpret_cast<const ushort_t*>(beta)[0])
                     : reinterpret_cast<const float*>(beta)[0];
    }
  }
}

// ---------------------------------------------------------------------------
// K2: fused QKV GEMM. One block = 64 rows of x; loops sel(3) x 8 col-chunks.
// Xs staged ONCE (XOR-swizzled: chunk c of row at ((c^(row&7))<<3)); Ws from
// W^T with identical swizzle via coalesced uint4. MFMA 16x16x32, wave =
// 16 rows x 64 cols per chunk. LDS exactly 64 KiB.
// ---------------------------------------------------------------------------
__global__ __launch_bounds__(256) void k_qkv(
    const ushort_t* __restrict__ xc, const ushort_t* __restrict__ wc,
    ushort_t* __restrict__ Qb, ushort_t* __restrict__ Kb, ushort_t* __restrict__ Vb)
{
  const int m0 = blockIdx.x * 64;
  const int tid = threadIdx.x, lane = tid & 63, wv = tid >> 6;
  const int l16 = lane & 15, quad = lane >> 4;

  __shared__ __align__(16) ushort_t Xs[64 * 256];   // 32 KiB
  __shared__ __align__(16) ushort_t Ws[64 * 256];   // 32 KiB

#pragma unroll
  for (int i = 0; i < 8; ++i) {
    const int id = tid + 256 * i;          // 2048 chunks of 8
    const int row = id >> 5, c = id & 31;
    uint4 v = *reinterpret_cast<const uint4*>(xc + (size_t)(m0 + row) * 256 + c * 8);
    *reinterpret_cast<uint4*>(&Xs[row * 256 + ((c ^ (row & 7)) << 3)]) = v;
  }

  for (int sel = 0; sel < 3; ++sel) {
    const ushort_t* WT   = wc + sel * 131072;
    const ushort_t* bias = wc + WC_BQ + sel * 512;
    ushort_t* out        = sel == 0 ? Qb : (sel == 1 ? Kb : Vb);
    for (int nc = 0; nc < 8; ++nc) {
      const int n0 = nc * 64;
      __syncthreads();   // prev chunk's Ws readers done (also orders Xs staging)
#pragma unroll
      for (int i = 0; i < 8; ++i) {
        const int id = tid + 256 * i;
        const int row = id >> 5, c = id & 31;
        uint4 v = *reinterpret_cast<const uint4*>(WT + (size_t)(n0 + row) * 256 + c * 8);
        *reinterpret_cast<uint4*>(&Ws[row * 256 + ((c ^ (row & 7)) << 3)]) = v;
      }
      __syncthreads();

      floatx4 acc[4] = {};
      const int arow = wv * 16 + l16;
#pragma unroll
      for (int ks = 0; ks < 8; ++ks) {
        const int ac = ks * 4 + quad;
        bf16x8 a = *reinterpret_cast<const bf16x8*>(&Xs[arow * 256 + ((ac ^ (arow & 7)) << 3)]);
#pragma unroll
        for (int nt = 0; nt < 4; ++nt) {
          const int brow = nt * 16 + l16;
          bf16x8 b = *reinterpret_cast<const bf16x8*>(&Ws[brow * 256 + ((ac ^ (brow & 7)) << 3)]);
          acc[nt] = __builtin_amdgcn_mfma_f32_16x16x32_bf16(a, b, acc[nt], 0, 0, 0);
        }
      }

#pragma unroll
      for (int nt = 0; nt < 4; ++nt) {
        const int col = n0 + nt * 16 + l16;
        const float bf = bf2f(bias[col]);
#pragma unroll
        for (int r = 0; r < 4; ++r) {
          const int row = m0 + wv * 16 + quad * 4 + r;
          out[(size_t)row * 512 + col] = f2bf(acc[nt][r] + bf);
        }
      }
    }
  }
}

// ---------------------------------------------------------------------------
// K3: pooling (seeds -> rpk, rvT). Verified (CHK3).
// ---------------------------------------------------------------------------
__global__ __launch_bounds__(256) void k_pool(
    const ushort_t* __restrict__ Kb, const ushort_t* __restrict__ Vb,
    const int* __restrict__ pidx_all, const ushort_t* __restrict__ wc,
    ushort_t* __restrict__ rpk, ushort_t* __restrict__ rvT)
{
  const int k = blockIdx.x, h = blockIdx.y;
  const int tid = threadIdx.x, lane = tid & 63, wv = tid >> 6;
  const int* pidx = pidx_all + k * 256;

  __shared__ __align__(16) ushort_t SB[128 * 256];
  const uint32* SBU = reinterpret_cast<const uint32*>(SB);

#pragma unroll
  for (int i = 0; i < 16; ++i) {
    const int e8 = tid + 256 * i;
    const int q = e8 >> 4, dc = (e8 & 15) * 8;
    uint4 kv = *reinterpret_cast<const uint4*>(Kb + (size_t)pidx[q] * 512 + h * 128 + dc);
    const ushort_t* ku = reinterpret_cast<const ushort_t*>(&kv);
    const int qp = q >> 1, qb = q & 1;
#pragma unroll
    for (int j = 0; j < 8; ++j) {
      const int d = dc + j;
      SB[d * 256 + (((qp ^ (d & 31)) << 1) | qb)] = ku[j];
    }
  }
  __syncthreads();

  float q00, q01, q10, q11;
  {
    const uint32* ssrc = reinterpret_cast<const uint32*>(wc + WC_SEED + (size_t)(wv * 4 + h) * 128);
    float s00 = 0.f, s01 = 0.f, s10 = 0.f, s11 = 0.f;
#pragma unroll 8
    for (int dc = 0; dc < 64; ++dc) {
      const uint32 qv = ssrc[dc];
      const float a0 = bflo(qv), a1 = bfhi(qv);
      const int d0 = dc * 2, d1 = d0 + 1;
      const int c0 = lane ^ (d0 & 31);
      const int c1 = lane ^ (d1 & 31);
      const uint32 u00 = SBU[d0 * 128 + c0];
      const uint32 u01 = SBU[d0 * 128 + c0 + 64];
      const uint32 u10 = SBU[d1 * 128 + c1];
      const uint32 u11 = SBU[d1 * 128 + c1 + 64];
      s00 += a0 * bflo(u00) + a1 * bflo(u10);
      s01 += a0 * bfhi(u00) + a1 * bfhi(u10);
      s10 += a0 * bflo(u01) + a1 * bflo(u11);
      s11 += a0 * bfhi(u01) + a1 * bfhi(u11);
    }
    s00 *= INV_SCALE; s01 *= INV_SCALE; s10 *= INV_SCALE; s11 *= INV_SCALE;
    float mx = fmaxf(fmaxf(s00, s01), fmaxf(s10, s11));
#pragma unroll
    for (int off = 32; off >= 1; off >>= 1) mx = fmaxf(mx, __shfl_xor(mx, off));
    const float e00 = __expf(s00 - mx), e01 = __expf(s01 - mx);
    const float e10 = __expf(s10 - mx), e11 = __expf(s11 - mx);
    float sm = e00 + e01 + e10 + e11;
#pragma unroll
    for (int off = 32; off >= 1; off >>= 1) sm += __shfl_xor(sm, off);
    const float inv = 1.0f / sm;
    q00 = e00 * inv; q01 = e01 * inv; q10 = e10 * inv; q11 = e11 * inv;
  }

  {
    float rk0 = 0.f, rk1 = 0.f;
    const int d0 = 2 * lane, d1 = 2 * lane + 1;
#pragma unroll 4
    for (int qp = 0; qp < 64; ++qp) {
      const float pa = __shfl(q00, qp), pb = __shfl(q01, qp);
      const float pc = __shfl(q10, qp), pd = __shfl(q11, qp);
      const int c0 = qp ^ (d0 & 31);
      const int c1 = qp ^ (d1 & 31);
      const uint32 u0  = SBU[d0 * 128 + c0];
      const uint32 u0b = SBU[d0 * 128 + c0 + 64];
      const uint32 u1  = SBU[d1 * 128 + c1];
      const uint32 u1b = SBU[d1 * 128 + c1 + 64];
      rk0 += pa * bflo(u0) + pb * bfhi(u0) + pc * bflo(u0b) + pd * bfhi(u0b);
      rk1 += pa * bflo(u1) + pb * bfhi(u1) + pc * bflo(u1b) + pd * bfhi(u1b);
    }
    reinterpret_cast<uint32*>(rpk + ((size_t)((k * 4 + wv) * 4 + h)) * 128)[lane] = pack2bf(rk0, rk1);
  }
  __syncthreads();

#pragma unroll
  for (int i = 0; i < 16; ++i) {
    const int e8 = tid + 256 * i;
    const int q = e8 >> 4, dc = (e8 & 15) * 8;
    uint4 vv = *reinterpret_cast<const uint4*>(Vb + (size_t)pidx[q] * 512 + h * 128 + dc);
    *reinterpret_cast<uint4*>(&SB[q * 128 + dc]) = vv;
  }
  __syncthreads();

  {
    float rv0 = 0.f, rv1 = 0.f;
#pragma unroll 4
    for (int qp = 0; qp < 64; ++qp) {
      const float pa = __shfl(q00, qp), pb = __shfl(q01, qp);
      const float pc = __shfl(q10, qp), pd = __shfl(q11, qp);
      const uint32 v00 = SBU[(2 * qp) * 64 + lane];
      const uint32 v01 = SBU[(2 * qp + 1) * 64 + lane];
      const uint32 v10 = SBU[(128 + 2 * qp) * 64 + lane];
      const uint32 v11 = SBU[(129 + 2 * qp) * 64 + lane];
      rv0 += pa * bflo(v00) + pb * bflo(v01) + pc * bflo(v10) + pd * bflo(v11);
      rv1 += pa * bfhi(v00) + pb * bfhi(v01) + pc * bfhi(v10) + pd * bfhi(v11);
    }
    const int rrep = k * 4 + wv;
    rvT[(size_t)(h * 128 + 2 * lane) * 512 + rrep]     = f2bf(rv0);
    rvT[(size_t)(h * 128 + 2 * lane + 1) * 512 + rrep] = f2bf(rv1);
  }
}

// ---------------------------------------------------------------------------
// K4: MFMA fine attention (verified round 8).
// ---------------------------------------------------------------------------
__global__ __launch_bounds__(256) void k_fine(
    const ushort_t* __restrict__ Qb, const ushort_t* __restrict__ Kb,
    const ushort_t* __restrict__ Vb, const int* __restrict__ pidx_all,
    ushort_t* __restrict__ locS)
{
  const int k = blockIdx.x, qg = blockIdx.y;
  const int tid = threadIdx.x, lane = tid & 63, wv = tid >> 6;
  const int l16 = lane & 15, quad = lane >> 4;
  const int* pidx = pidx_all + k * 256;

  __shared__ __align__(16) ushort_t Qs[64 * 136];
  __shared__ __align__(16) ushort_t SB2[64 * 136];
  __shared__ __align__(16) ushort_t Ps[4][16 * 72];

  float accS[8][4];
#pragma unroll
  for (int nt = 0; nt < 8; ++nt)
#pragma unroll
    for (int r = 0; r < 4; ++r) accS[nt][r] = 0.f;

  for (int h = 0; h < 4; ++h) {
    __syncthreads();
#pragma unroll
    for (int i = 0; i < 4; ++i) {
      const int e = tid + 256 * i;
      const int r = e >> 4, c8 = (e & 15) * 8;
      uint4 v = *reinterpret_cast<const uint4*>(Qb + (size_t)pidx[qg * 64 + r] * 512 + h * 128 + c8);
      *reinterpret_cast<uint4*>(&Qs[r * 136 + c8]) = v;
    }

    floatx4 O[8] = {};
    float m_i[4], l_i[4];
#pragma unroll
    for (int r = 0; r < 4; ++r) { m_i[r] = -3e38f; l_i[r] = 0.f; }

    for (int c = 0; c < 4; ++c) {
      __syncthreads();
#pragma unroll
      for (int i = 0; i < 4; ++i) {
        const int e = tid + 256 * i;
        const int r = e >> 4, c8 = (e & 15) * 8;
        uint4 v = *reinterpret_cast<const uint4*>(Kb + (size_t)pidx[c * 64 + r] * 512 + h * 128 + c8);
        *reinterpret_cast<uint4*>(&SB2[r * 136 + c8]) = v;
      }
      __syncthreads();

      floatx4 S[4] = {};
#pragma unroll
      for (int ks = 0; ks < 4; ++ks) {
        bf16x8 a = *reinterpret_cast<const bf16x8*>(&Qs[(wv * 16 + l16) * 136 + ks * 32 + quad * 8]);
#pragma unroll
        for (int nt = 0; nt < 4; ++nt) {
          bf16x8 b = *reinterpret_cast<const bf16x8*>(&SB2[(nt * 16 + l16) * 136 + ks * 32 + quad * 8]);
          S[nt] = __builtin_amdgcn_mfma_f32_16x16x32_bf16(a, b, S[nt], 0, 0, 0);
        }
      }
#pragma unroll
      for (int nt = 0; nt < 4; ++nt)
#pragma unroll
        for (int r = 0; r < 4; ++r) S[nt][r] *= INV_SCALE;

#pragma unroll
      for (int r = 0; r < 4; ++r) {
        float cm = fmaxf(fmaxf(S[0][r], S[1][r]), fmaxf(S[2][r], S[3][r]));
#pragma unroll
        for (int off = 1; off <= 8; off <<= 1) cm = fmaxf(cm, __shfl_xor(cm, off));
        const float mn = fmaxf(m_i[r], cm);
        const float sc = __expf(m_i[r] - mn);
        m_i[r] = mn;
        l_i[r] *= sc;
#pragma unroll
        for (int nt = 0; nt < 8; ++nt) O[nt][r] *= sc;
        float ps = 0.f;
#pragma unroll
        for (int nt = 0; nt < 4; ++nt) {
          const float p = __expf(S[nt][r] - mn);
          ps += p;
          Ps[wv][(quad * 4 + r) * 72 + nt * 16 + l16] = f2bf(p);
        }
#pragma unroll
        for (int off = 1; off <= 8; off <<= 1) ps += __shfl_xor(ps, off);
        l_i[r] += ps;
      }
      __syncthreads();

#pragma unroll
      for (int i = 0; i < 4; ++i) {
        const int e = tid + 256 * i;
        const int key = e & 63, dc8 = (e >> 6) * 8;
        uint4 vv = *reinterpret_cast<const uint4*>(Vb + (size_t)pidx[c * 64 + key] * 512 + h * 128 + dc8);
        const ushort_t* u = reinterpret_cast<const ushort_t*>(&vv);
#pragma unroll
        for (int j = 0; j < 8; ++j) {
          const int d = dc8 + j;
          SB2[d * 64 + (((key >> 3) ^ j) << 3) + (key & 7)] = u[j];
        }
      }
      __syncthreads();

#pragma unroll
      for (int ks = 0; ks < 2; ++ks) {
        bf16x8 a = *reinterpret_cast<const bf16x8*>(&Ps[wv][l16 * 72 + ks * 32 + quad * 8]);
#pragma unroll
        for (int nt = 0; nt < 8; ++nt) {
          const int d = nt * 16 + l16;
          const int q8 = ks * 4 + quad;
          bf16x8 b = *reinterpret_cast<const bf16x8*>(&SB2[d * 64 + ((q8 ^ (d & 7)) << 3)]);
          O[nt] = __builtin_amdgcn_mfma_f32_16x16x32_bf16(a, b, O[nt], 0, 0, 0);
        }
      }
    }

#pragma unroll
    for (int r = 0; r < 4; ++r) {
      const float inv = 1.0f / l_i[r];
#pragma unroll
      for (int nt = 0; nt < 8; ++nt) accS[nt][r] += O[nt][r] * inv;
    }
  }

#pragma unroll
  for (int r = 0; r < 4; ++r) {
    const int n = pidx[qg * 64 + wv * 16 + quad * 4 + r];
#pragma unroll
    for (int nt = 0; nt < 8; ++nt)
      locS[(size_t)n * 128 + nt * 16 + l16] = f2bf(accS[nt][r] * 0.25f);
  }
}

// ---------------------------------------------------------------------------
// K5: MFMA cross-attention, round 14.
// Round-13 chassis (gl2lds double-buffer staging, verified) with SWAPPED
// QK^T: S^T[nt] = mfma(K_frag, Q_frag) puts all 16 scores of q-row l16 in
// the lane's registers (reps lane-local). Row max/sum = 15 local ops +
// 2 shfl_xor (vs 32 shfl chains). m_i/l_i scalar per lane (qrow = l16,
// replicated over quads). Ps writes: 4 aligned b64 stores. PV unchanged
// (Ps read layout [qrow][rep] identical to before). Defer-max + exp2 domain.
// ---------------------------------------------------------------------------
__global__ __launch_bounds__(256, 2) void k_cross(
    const ushort_t* __restrict__ Qb, const ushort_t* __restrict__ rpk,
    const ushort_t* __restrict__ rvT, ushort_t* __restrict__ glb)
{
  const int h = blockIdx.y;
  const int n0 = blockIdx.x * 64;
  const int tid = threadIdx.x, lane = tid & 63, wv = tid >> 6;
  const int l16 = lane & 15, quad = lane >> 4;

  __shared__ __align__(16) ushort_t BsK[2][64 * 128];   // 2 x 16 KiB
  __shared__ __align__(16) ushort_t BsV[2][128 * 64];   // 2 x 16 KiB
  __shared__ __align__(16) ushort_t Ps[4][16 * 72];     // 9 KiB wave-private

  // Q fragments (row = n0+wv*16+l16, k-chunk ks*32+quad*8). 16 VGPRs.
  // Used as the B operand of the swapped MFMA (same lane map as A).
  bf16x8 qf[4];
  {
    const ushort_t* qrow =
        Qb + (size_t)(n0 + wv * 16 + l16) * 512 + h * 128 + quad * 8;
#pragma unroll
    for (int ks = 0; ks < 4; ++ks)
      qf[ks] = *reinterpret_cast<const bf16x8*>(qrow + ks * 32);
  }

  // Per-lane staging source coordinates.
  const int kRL = lane >> 4;        // row-in-group 0..3 (K)
  const int kCH = lane & 15;        // 16B chunk 0..15  (K)
  const int vDL = lane >> 3;        // row-in-group 0..7 (V)
  const int vCH = lane & 7;         // 16B chunk 0..7   (V)

  floatx4 O[8] = {};
  float m_i = -3e38f, l_i = 0.f;    // for qrow = l16 (replicated over quads)

  // Prologue: stage chunk 0 into buffer 0.
  {
#pragma unroll
    for (int j = 0; j < 4; ++j) {
      const int row = wv * 16 + j * 4 + kRL;     // 0..63
      gl2lds16(rpk + (size_t)row * 512 + h * 128 + ((kCH ^ (row & 7)) << 3),
               &BsK[0][(wv * 16 + j * 4) * 128]);
      const int d = wv * 32 + j * 8 + vDL;       // 0..127
      gl2lds16(rvT + (size_t)(h * 128 + d) * 512 + ((vCH ^ (d & 7)) << 3),
               &BsV[0][(wv * 32 + j * 8) * 64]);
    }
  }
  __syncthreads();   // implicit vmcnt(0): chunk 0 landed

  const int kswz = l16 & 7;   // row&7 for all fragment rows this lane reads

  for (int c = 0; c < 8; ++c) {
    const int cur = c & 1;

    // Stage next chunk into the other buffer; loads fly under this chunk's
    // compute and are drained by the barrier at the end of the iteration.
    if (c < 7) {
      const int nb = cur ^ 1;
      const int cn = c + 1;
#pragma unroll
      for (int j = 0; j < 4; ++j) {
        const int row = wv * 16 + j * 4 + kRL;
        gl2lds16(rpk + (size_t)(cn * 64 + row) * 512 + h * 128 +
                     ((kCH ^ (row & 7)) << 3),
                 &BsK[nb][(wv * 16 + j * 4) * 128]);
        const int d = wv * 32 + j * 8 + vDL;
        gl2lds16(rvT + (size_t)(h * 128 + d) * 512 + cn * 64 +
                     ((vCH ^ (d & 7)) << 3),
                 &BsV[nb][(wv * 32 + j * 8) * 64]);
      }
    }

    // ---- swapped QK^T: S[nt][r] = score[rep=nt*16+quad*4+r][qrow=l16] ----
    floatx4 S[4] = {};
#pragma unroll
    for (int ks = 0; ks < 4; ++ks) {
      const int ac = ks * 4 + quad;
#pragma unroll
      for (int nt = 0; nt < 4; ++nt) {
        bf16x8 b = *reinterpret_cast<const bf16x8*>(
            &BsK[cur][(nt * 16 + l16) * 128 + ((ac ^ kswz) << 3)]);
        S[nt] = __builtin_amdgcn_mfma_f32_16x16x32_bf16(b, qf[ks], S[nt], 0, 0, 0);
      }
    }

    // ---- softmax over lane-local reps (exp2 domain, defer-max) ----
    float cm;
    {
      const float m0 = fmaxf(fmaxf(S[0][0], S[0][1]), fmaxf(S[0][2], S[0][3]));
      const float m1 = fmaxf(fmaxf(S[1][0], S[1][1]), fmaxf(S[1][2], S[1][3]));
      const float m2 = fmaxf(fmaxf(S[2][0], S[2][1]), fmaxf(S[2][2], S[2][3]));
      const float m3 = fmaxf(fmaxf(S[3][0], S[3][1]), fmaxf(S[3][2], S[3][3]));
      cm = fmaxf(fmaxf(m0, m1), fmaxf(m2, m3));
      cm = fmaxf(cm, __shfl_xor(cm, 16));
      cm = fmaxf(cm, __shfl_xor(cm, 32));   // chunk max for qrow l16
    }
    if (!__all(cm <= m_i + DEFER_THR)) {
      const float mn = fmaxf(m_i, cm);
      const float sc = exp2f((m_i - mn) * C2EXP);
      m_i = mn;
      l_i *= sc;
      float scR[4];
#pragma unroll
      for (int r = 0; r < 4; ++r) scR[r] = __shfl(sc, quad * 4 + r);
#pragma unroll
      for (int nt = 0; nt < 8; ++nt)
#pragma unroll
        for (int r = 0; r < 4; ++r) O[nt][r] *= scR[r];
    }
    {
      const float mC = m_i * C2EXP;
      float ps = 0.f;
#pragma unroll
      for (int nt = 0; nt < 4; ++nt) {
        const float p0 = exp2f(S[nt][0] * C2EXP - mC);
        const float p1 = exp2f(S[nt][1] * C2EXP - mC);
        const float p2 = exp2f(S[nt][2] * C2EXP - mC);
        const float p3 = exp2f(S[nt][3] * C2EXP - mC);
        ps += (p0 + p1) + (p2 + p3);
        // Ps[qrow=l16][rep = nt*16 + quad*4 + 0..3]: one aligned 8B store.
        uint2 pk2 = make_uint2(pack2bf(p0, p1), pack2bf(p2, p3));
        *reinterpret_cast<uint2*>(&Ps[wv][l16 * 72 + nt * 16 + quad * 4]) = pk2;
      }
      ps += __shfl_xor(ps, 16);
      ps += __shfl_xor(ps, 32);             // chunk sum for qrow l16
      l_i += ps;
    }
    // Ps write->read is within-wave (lgkmcnt-ordered, no barrier needed).

    // ---- PV (unchanged; Ps read layout [qrow][rep] same as before) ----
#pragma unroll
    for (int ks = 0; ks < 2; ++ks) {
      bf16x8 a = *reinterpret_cast<const bf16x8*>(&Ps[wv][l16 * 72 + ks * 32 + quad * 8]);
#pragma unroll
      for (int nt = 0; nt < 8; ++nt) {
        const int q8 = ks * 4 + quad;
        bf16x8 b = *reinterpret_cast<const bf16x8*>(
            &BsV[cur][(nt * 16 + l16) * 64 + ((q8 ^ kswz) << 3)]);
        O[nt] = __builtin_amdgcn_mfma_f32_16x16x32_bf16(a, b, O[nt], 0, 0, 0);
      }
    }

    __syncthreads();   // drains next-chunk loads; all waves done with 'cur'
  }

  // l_i holds denom for qrow=l16; O rows are quad*4+r -> broadcast via shfl.
  float invR[4];
#pragma unroll
  for (int r = 0; r < 4; ++r) invR[r] = 1.0f / __shfl(l_i, quad * 4 + r);
#pragma unroll
  for (int r = 0; r < 4; ++r) {
    const int n = n0 + wv * 16 + quad * 4 + r;
#pragma unroll
    for (int nt = 0; nt < 8; ++nt)
      glb[(size_t)n * 512 + h * 128 + nt * 16 + l16] = f2bf(O[nt][r] * invR[r]);
  }
}

// ---------------------------------------------------------------------------
// K6: combine -> f32 output.
// ---------------------------------------------------------------------------
__global__ __launch_bounds__(256) void k_combine(
    const ushort_t* __restrict__ locS, const ushort_t* __restrict__ glb,
    const ushort_t* __restrict__ Vb, const float* __restrict__ scal,
    float* __restrict__ out)
{
  const int t = blockIdx.x * 256 + threadIdx.x;
  const int n = t >> 6, dp = t & 63;
  const float alpha = 1.0f / (1.0f + __expf(-scal[0]));
  const float beta = scal[1];
  const uint32 lv = reinterpret_cast<const uint32*>(locS)[(size_t)n * 64 + dp];
  float g0 = 0.f, g1 = 0.f, v0 = 0.f, v1 = 0.f;
#pragma unroll
  for (int hh = 0; hh < 4; ++hh) {
    const uint32 gv = *reinterpret_cast<const uint32*>(glb + (size_t)n * 512 + hh * 128 + 2 * dp);
    const uint32 vv = *reinterpret_cast<const uint32*>(Vb + (size_t)n * 512 + hh * 128 + 2 * dp);
    g0 += bflo(gv); g1 += bfhi(gv);
    v0 += bflo(vv); v1 += bfhi(vv);
  }
  const float r0 = alpha * bflo(lv) + (1.0f - alpha) * g0 * 0.25f + beta * v0 * 0.25f;
  const float r1 = alpha * bfhi(lv) + (1.0f - alpha) * g1 * 0.25f + beta * v1 * 0.25f;
  reinterpret_cast<float2*>(out)[(size_t)n * 64 + dp] = make_float2(r0, r1);
}

extern "C" void kernel_launch(void* const* d_in, const int* in_sizes, int n_in,
                              void* d_out, int out_size, void* d_ws, size_t ws_size,
                              hipStream_t stream) {
  const void* x     = d_in[0];
  const int*  pidx  = (const int*)d_in[1];
  const void* Wq    = d_in[2];
  const void* bq    = d_in[3];
  const void* Wk    = d_in[4];
  const void* bk    = d_in[5];
  const void* Wv    = d_in[6];
  const void* bv    = d_in[7];
  const void* seeds = d_in[8];
  const void* al    = d_in[9];
  const void* be    = d_in[10];

  char* ws = (char*)d_ws;
  ushort_t* Qb   = (ushort_t*)(ws + OFF_Q);
  ushort_t* Kb   = (ushort_t*)(ws + OFF_K);
  ushort_t* Vb   = (ushort_t*)(ws + OFF_V);
  ushort_t* locS = (ushort_t*)(ws + OFF_LOC);
  ushort_t* rpk  = (ushort_t*)(ws + OFF_RPK);
  ushort_t* xc   = (ushort_t*)(ws + OFF_XC);
  ushort_t* wc   = (ushort_t*)(ws + OFF_WC);
  float*    scal = (float*)   (ws + OFF_SCAL);
  uint32*   flags= (uint32*)  (ws + OFF_FLAG);
  ushort_t* rvT  = (ushort_t*)(ws + OFF_RVT);
  ushort_t* glb  = (ushort_t*)(ws + OFF_GLB);

  k_detect<<<1, 64, 0, stream>>>((const uint32*)x, (const ushort_t*)be, flags);
  k_convert<<<dim3(4096, 2), 256, 0, stream>>>(x, Wq, bq, Wk, bk, Wv, bv, seeds, al, be,
                                               xc, wc, scal, flags);
  k_qkv<<<512, 256, 0, stream>>>(xc, wc, Qb, Kb, Vb);
  k_pool<<<dim3(128, 4), 256, 0, stream>>>(Kb, Vb, pidx, wc, rpk, rvT);
  k_fine<<<dim3(128, 4), 256, 0, stream>>>(Qb, Kb, Vb, pidx, locS);
  k_cross<<<dim3(512, 4), 256, 0, stream>>>(Qb, rpk, rvT, glb);
  k_combine<<<8192, 256, 0, stream>>>(locS, glb, Vb, scal, (float*)d_out);
}

// Round 6
// 332.059 us; speedup vs baseline: 1.5838x; 1.1038x over previous
//
#include <hip/hip_runtime.h>
#include <hip/hip_bf16.h>

// PCGTConvLayer round 15: k_fine rebuilt with the verified k_cross recipe:
// swapped QK^T (lane-local softmax, 2 shfl per reduce), reg-resident Q per
// head, double-buffered K tile via global_load_lds + XOR swizzle (gathered
// rows), 2 barriers per (h,c) unit (was 6). V scalar-scatter transpose kept
// verbatim. k_cross/k_qkv/k_pool/etc verbatim from round 14 (366.5 us).
// N=32768 IN=256 D=128 H=4 M=4 KP=128 S=256, SCALE=sqrt(128).

#define INV_SCALE 0.08838834764831845f
// INV_SCALE * log2(e)
#define C2EXP 0.12751744f
// 8 / INV_SCALE  (defer-max threshold in unscaled-score domain)
#define DEFER_THR 90.50966799f

typedef __attribute__((ext_vector_type(8))) short bf16x8;
typedef __attribute__((ext_vector_type(4))) float floatx4;
typedef unsigned short ushort_t;
typedef unsigned int uint32;

// ---- ws layout (bytes) ----
#define OFF_Q    0ull            // bf16 [32768][512]
#define OFF_K    33554432ull     // bf16 [32768][512]
#define OFF_V    67108864ull     // bf16 [32768][512]
#define OFF_LOC  100663296ull    // bf16 [32768][128]
#define OFF_RPK  109051904ull    // bf16 [512][4][128]
#define OFF_XC   110100480ull    // bf16 [32768][256]
#define OFF_WC   126877696ull    // bf16: WqT,WkT,WvT ([512][256] each), biases, seeds
#define OFF_SCAL 127671296ull    // f32 [2]
#define OFF_FLAG 127671304ull    // u32 [2]
#define OFF_RVT  127672320ull    // bf16 [4][128][512]
#define OFF_GLB  128196608ull    // bf16 [32768][512]

#define WC_WQ 0
#define WC_WK 131072
#define WC_WV 262144
#define WC_BQ 393216
#define WC_BK 393728
#define WC_BV 394240
#define WC_SEED 394752
#define WC_TOT 396800

static __device__ __forceinline__ float bflo(uint32 u) {
  return __uint_as_float(u << 16);
}
static __device__ __forceinline__ float bfhi(uint32 u) {
  return __uint_as_float(u & 0xffff0000u);
}
static __device__ __forceinline__ float bf2f(ushort_t u) {
  return __uint_as_float(((uint32)u) << 16);
}
static __device__ __forceinline__ ushort_t f2bf(float f) {
  uint32 x = __float_as_uint(f);
  uint32 r = x + 0x7fffu + ((x >> 16) & 1u);
  return (ushort_t)(r >> 16);
}
static __device__ __forceinline__ uint32 pack2bf(float a, float b) {
  return (uint32)f2bf(a) | ((uint32)f2bf(b) << 16);
}

// async global -> LDS, 16 bytes per lane. LDS dest must be wave-uniform base;
// lane i lands at base + i*16 B. Global source is per-lane.
static __device__ __forceinline__ void gl2lds16(const ushort_t* g, ushort_t* l) {
  __builtin_amdgcn_global_load_lds(
      (const __attribute__((address_space(1))) void*)g,
      (__attribute__((address_space(3))) void*)l, 16, 0, 0);
}

// ---------------------------------------------------------------------------
__global__ __launch_bounds__(64) void k_detect(const uint32* __restrict__ xw,
                                               const ushort_t* __restrict__ betaRaw,
                                               uint32* __restrict__ flags) {
  const int lane = threadIdx.x;
  const uint32 w = xw[lane * 137 + 3];
  const int e = (w >> 7) & 0xff;
  const unsigned long long b = __ballot(e >= 100 && e <= 140);
  if (lane == 0) {
    flags[0] = (__popcll(b) >= 48) ? 1u : 0u;
    flags[1] = (betaRaw[0] != 0) ? 1u : 0u;
  }
}

// ---------------------------------------------------------------------------
// K1: canonicalize. x -> xc (identity layout). W matrices -> TRANSPOSED
// bf16 [512][256] at same wc offsets. biases/seeds identity.
// ---------------------------------------------------------------------------
static __device__ __forceinline__ void conv8(const void* src, long j, int isB,
                                             ushort_t* dst) {
  if (isB) {
    *reinterpret_cast<uint4*>(dst) =
        *reinterpret_cast<const uint4*>(reinterpret_cast<const ushort_t*>(src) + j);
  } else {
    const float* f = reinterpret_cast<const float*>(src) + j;
    const float4 a = *reinterpret_cast<const float4*>(f);
    const float4 b = *reinterpret_cast<const float4*>(f + 4);
    uint4 o;
    o.x = pack2bf(a.x, a.y); o.y = pack2bf(a.z, a.w);
    o.z = pack2bf(b.x, b.y); o.w = pack2bf(b.z, b.w);
    *reinterpret_cast<uint4*>(dst) = o;
  }
}

__global__ __launch_bounds__(256) void k_convert(
    const void* __restrict__ x,
    const void* __restrict__ Wq, const void* __restrict__ bq,
    const void* __restrict__ Wk, const void* __restrict__ bk,
    const void* __restrict__ Wv, const void* __restrict__ bv,
    const void* __restrict__ seeds, const void* __restrict__ alpha,
    const void* __restrict__ beta,
    ushort_t* __restrict__ xc, ushort_t* __restrict__ wc,
    float* __restrict__ scal, const uint32* __restrict__ flags)
{
  const int isB = (int)flags[0];
  const long i8 = ((long)blockIdx.x * 256 + threadIdx.x) * 8;
  if (blockIdx.y == 0) {
    conv8(x, i8, isB, xc + i8);
  } else {
    if (i8 < WC_BQ) {
      // W region: transpose. i8 = sel*131072 + k*512 + n (8 consecutive n).
      const int sel = (int)(i8 >> 17);
      const long local = i8 & 131071;
      const int kk = (int)(local >> 9);
      const int nn = (int)(local & 511);
      const void* src = sel == 0 ? Wq : (sel == 1 ? Wk : Wv);
      ushort_t* dstW = wc + sel * 131072;
#pragma unroll
      for (int j = 0; j < 8; ++j) {
        ushort_t v;
        if (isB) v = reinterpret_cast<const ushort_t*>(src)[local + j];
        else     v = f2bf(reinterpret_cast<const float*>(src)[local + j]);
        dstW[(size_t)(nn + j) * 256 + kk] = v;
      }
    } else if (i8 < WC_TOT) {
      const void* src; long j;
      if (i8 < WC_BK)        { src = bq;    j = i8 - WC_BQ; }
      else if (i8 < WC_BV)   { src = bk;    j = i8 - WC_BK; }
      else if (i8 < WC_SEED) { src = bv;    j = i8 - WC_BV; }
      else                   { src = seeds; j = i8 - WC_SEED; }
      conv8(src, j, isB, wc + i8);
    }
    if (blockIdx.x == 0 && threadIdx.x == 0) {
      const int isBS = (int)flags[1];
      scal[0] = isBS ? bf2f(reinterpret_cast<const ushort_t*>(alpha)[0])
                     : reinterpret_cast<const float*>(alpha)[0];
      scal[1] = isBS ? bf2f(reinterpret_cast<const ushort_t*>(beta)[0])
                     : reinterpret_cast<const float*>(beta)[0];
    }
  }
}

// ---------------------------------------------------------------------------
// K2: fused QKV GEMM. One block = 64 rows of x; loops sel(3) x 8 col-chunks.
// Xs staged ONCE (XOR-swizzled: chunk c of row at ((c^(row&7))<<3)); Ws from
// W^T with identical swizzle via coalesced uint4. MFMA 16x16x32, wave =
// 16 rows x 64 cols per chunk. LDS exactly 64 KiB.
// ---------------------------------------------------------------------------
__global__ __launch_bounds__(256) void k_qkv(
    const ushort_t* __restrict__ xc, const ushort_t* __restrict__ wc,
    ushort_t* __restrict__ Qb, ushort_t* __restrict__ Kb, ushort_t* __restrict__ Vb)
{
  const int m0 = blockIdx.x * 64;
  const int tid = threadIdx.x, lane = tid & 63, wv = tid >> 6;
  const int l16 = lane & 15, quad = lane >> 4;

  __shared__ __align__(16) ushort_t Xs[64 * 256];   // 32 KiB
  __shared__ __align__(16) ushort_t Ws[64 * 256];   // 32 KiB

#pragma unroll
  for (int i = 0; i < 8; ++i) {
    const int id = tid + 256 * i;          // 2048 chunks of 8
    const int row = id >> 5, c = id & 31;
    uint4 v = *reinterpret_cast<const uint4*>(xc + (size_t)(m0 + row) * 256 + c * 8);
    *reinterpret_cast<uint4*>(&Xs[row * 256 + ((c ^ (row & 7)) << 3)]) = v;
  }

  for (int sel = 0; sel < 3; ++sel) {
    const ushort_t* WT   = wc + sel * 131072;
    const ushort_t* bias = wc + WC_BQ + sel * 512;
    ushort_t* out        = sel == 0 ? Qb : (sel == 1 ? Kb : Vb);
    for (int nc = 0; nc < 8; ++nc) {
      const int n0 = nc * 64;
      __syncthreads();   // prev chunk's Ws readers done (also orders Xs staging)
#pragma unroll
      for (int i = 0; i < 8; ++i) {
        const int id = tid + 256 * i;
        const int row = id >> 5, c = id & 31;
        uint4 v = *reinterpret_cast<const uint4*>(WT + (size_t)(n0 + row) * 256 + c * 8);
        *reinterpret_cast<uint4*>(&Ws[row * 256 + ((c ^ (row & 7)) << 3)]) = v;
      }
      __syncthreads();

      floatx4 acc[4] = {};
      const int arow = wv * 16 + l16;
#pragma unroll
      for (int ks = 0; ks < 8; ++ks) {
        const int ac = ks * 4 + quad;
        bf16x8 a = *reinterpret_cast<const bf16x8*>(&Xs[arow * 256 + ((ac ^ (arow & 7)) << 3)]);
#pragma unroll
        for (int nt = 0; nt < 4; ++nt) {
          const int brow = nt * 16 + l16;
          bf16x8 b = *reinterpret_cast<const bf16x8*>(&Ws[brow * 256 + ((ac ^ (brow & 7)) << 3)]);
          acc[nt] = __builtin_amdgcn_mfma_f32_16x16x32_bf16(a, b, acc[nt], 0, 0, 0);
        }
      }

#pragma unroll
      for (int nt = 0; nt < 4; ++nt) {
        const int col = n0 + nt * 16 + l16;
        const float bf = bf2f(bias[col]);
#pragma unroll
        for (int r = 0; r < 4; ++r) {
          const int row = m0 + wv * 16 + quad * 4 + r;
          out[(size_t)row * 512 + col] = f2bf(acc[nt][r] + bf);
        }
      }
    }
  }
}

// ---------------------------------------------------------------------------
// K3: pooling (seeds -> rpk, rvT). Verified (CHK3).
// ---------------------------------------------------------------------------
__global__ __launch_bounds__(256) void k_pool(
    const ushort_t* __restrict__ Kb, const ushort_t* __restrict__ Vb,
    const int* __restrict__ pidx_all, const ushort_t* __restrict__ wc,
    ushort_t* __restrict__ rpk, ushort_t* __restrict__ rvT)
{
  const int k = blockIdx.x, h = blockIdx.y;
  const int tid = threadIdx.x, lane = tid & 63, wv = tid >> 6;
  const int* pidx = pidx_all + k * 256;

  __shared__ __align__(16) ushort_t SB[128 * 256];
  const uint32* SBU = reinterpret_cast<const uint32*>(SB);

#pragma unroll
  for (int i = 0; i < 16; ++i) {
    const int e8 = tid + 256 * i;
    const int q = e8 >> 4, dc = (e8 & 15) * 8;
    uint4 kv = *reinterpret_cast<const uint4*>(Kb + (size_t)pidx[q] * 512 + h * 128 + dc);
    const ushort_t* ku = reinterpret_cast<const ushort_t*>(&kv);
    const int qp = q >> 1, qb = q & 1;
#pragma unroll
    for (int j = 0; j < 8; ++j) {
      const int d = dc + j;
      SB[d * 256 + (((qp ^ (d & 31)) << 1) | qb)] = ku[j];
    }
  }
  __syncthreads();

  float q00, q01, q10, q11;
  {
    const uint32* ssrc = reinterpret_cast<const uint32*>(wc + WC_SEED + (size_t)(wv * 4 + h) * 128);
    float s00 = 0.f, s01 = 0.f, s10 = 0.f, s11 = 0.f;
#pragma unroll 8
    for (int dc = 0; dc < 64; ++dc) {
      const uint32 qv = ssrc[dc];
      const float a0 = bflo(qv), a1 = bfhi(qv);
      const int d0 = dc * 2, d1 = d0 + 1;
      const int c0 = lane ^ (d0 & 31);
      const int c1 = lane ^ (d1 & 31);
      const uint32 u00 = SBU[d0 * 128 + c0];
      const uint32 u01 = SBU[d0 * 128 + c0 + 64];
      const uint32 u10 = SBU[d1 * 128 + c1];
      const uint32 u11 = SBU[d1 * 128 + c1 + 64];
      s00 += a0 * bflo(u00) + a1 * bflo(u10);
      s01 += a0 * bfhi(u00) + a1 * bfhi(u10);
      s10 += a0 * bflo(u01) + a1 * bflo(u11);
      s11 += a0 * bfhi(u01) + a1 * bfhi(u11);
    }
    s00 *= INV_SCALE; s01 *= INV_SCALE; s10 *= INV_SCALE; s11 *= INV_SCALE;
    float mx = fmaxf(fmaxf(s00, s01), fmaxf(s10, s11));
#pragma unroll
    for (int off = 32; off >= 1; off >>= 1) mx = fmaxf(mx, __shfl_xor(mx, off));
    const float e00 = __expf(s00 - mx), e01 = __expf(s01 - mx);
    const float e10 = __expf(s10 - mx), e11 = __expf(s11 - mx);
    float sm = e00 + e01 + e10 + e11;
#pragma unroll
    for (int off = 32; off >= 1; off >>= 1) sm += __shfl_xor(sm, off);
    const float inv = 1.0f / sm;
    q00 = e00 * inv; q01 = e01 * inv; q10 = e10 * inv; q11 = e11 * inv;
  }

  {
    float rk0 = 0.f, rk1 = 0.f;
    const int d0 = 2 * lane, d1 = 2 * lane + 1;
#pragma unroll 4
    for (int qp = 0; qp < 64; ++qp) {
      const float pa = __shfl(q00, qp), pb = __shfl(q01, qp);
      const float pc = __shfl(q10, qp), pd = __shfl(q11, qp);
      const int c0 = qp ^ (d0 & 31);
      const int c1 = qp ^ (d1 & 31);
      const uint32 u0  = SBU[d0 * 128 + c0];
      const uint32 u0b = SBU[d0 * 128 + c0 + 64];
      const uint32 u1  = SBU[d1 * 128 + c1];
      const uint32 u1b = SBU[d1 * 128 + c1 + 64];
      rk0 += pa * bflo(u0) + pb * bfhi(u0) + pc * bflo(u0b) + pd * bfhi(u0b);
      rk1 += pa * bflo(u1) + pb * bfhi(u1) + pc * bflo(u1b) + pd * bfhi(u1b);
    }
    reinterpret_cast<uint32*>(rpk + ((size_t)((k * 4 + wv) * 4 + h)) * 128)[lane] = pack2bf(rk0, rk1);
  }
  __syncthreads();

#pragma unroll
  for (int i = 0; i < 16; ++i) {
    const int e8 = tid + 256 * i;
    const int q = e8 >> 4, dc = (e8 & 15) * 8;
    uint4 vv = *reinterpret_cast<const uint4*>(Vb + (size_t)pidx[q] * 512 + h * 128 + dc);
    *reinterpret_cast<uint4*>(&SB[q * 128 + dc]) = vv;
  }
  __syncthreads();

  {
    float rv0 = 0.f, rv1 = 0.f;
#pragma unroll 4
    for (int qp = 0; qp < 64; ++qp) {
      const float pa = __shfl(q00, qp), pb = __shfl(q01, qp);
      const float pc = __shfl(q10, qp), pd = __shfl(q11, qp);
      const uint32 v00 = SBU[(2 * qp) * 64 + lane];
      const uint32 v01 = SBU[(2 * qp + 1) * 64 + lane];
      const uint32 v10 = SBU[(128 + 2 * qp) * 64 + lane];
      const uint32 v11 = SBU[(129 + 2 * qp) * 64 + lane];
      rv0 += pa * bflo(v00) + pb * bflo(v01) + pc * bflo(v10) + pd * bflo(v11);
      rv1 += pa * bfhi(v00) + pb * bfhi(v01) + pc * bfhi(v10) + pd * bfhi(v11);
    }
    const int rrep = k * 4 + wv;
    rvT[(size_t)(h * 128 + 2 * lane) * 512 + rrep]     = f2bf(rv0);
    rvT[(size_t)(h * 128 + 2 * lane + 1) * 512 + rrep] = f2bf(rv1);
  }
}

// ---------------------------------------------------------------------------
// K4: MFMA fine attention, round 15.
// Swapped QK^T (lane-local softmax), Q frags in regs per head, K tile
// double-buffered via gl2lds + XOR swizzle (gathered rows), 2 barriers per
// (h,c) unit. V scalar-scatter transpose kept verbatim from round 8.
// LDS: BsK 2x16K + SBV 16K + Ps 9K = 57 KiB (grid-pinned 2 blocks/CU).
// ---------------------------------------------------------------------------
__global__ __launch_bounds__(256) void k_fine(
    const ushort_t* __restrict__ Qb, const ushort_t* __restrict__ Kb,
    const ushort_t* __restrict__ Vb, const int* __restrict__ pidx_all,
    ushort_t* __restrict__ locS)
{
  const int k = blockIdx.x, qg = blockIdx.y;
  const int tid = threadIdx.x, lane = tid & 63, wv = tid >> 6;
  const int l16 = lane & 15, quad = lane >> 4;
  const int* pidx = pidx_all + k * 256;

  __shared__ __align__(16) ushort_t BsK[2][64 * 128];  // 2 x 16 KiB
  __shared__ __align__(16) ushort_t SBV[128 * 64];     // 16 KiB (V^T scatter)
  __shared__ __align__(16) ushort_t Ps[4][16 * 72];    // 9 KiB wave-private

  // This lane's q-row global index (q-row = l16 within the wave's 16 rows).
  const int qidx = pidx[qg * 64 + wv * 16 + l16];

  // K staging lane coordinates (round-13 pattern).
  const int kRL = lane >> 4;        // row-in-group 0..3
  const int kCH = lane & 15;        // 16B chunk 0..15
  const int kswz = l16 & 7;

  float accS[8][4];
#pragma unroll
  for (int nt = 0; nt < 8; ++nt)
#pragma unroll
    for (int r = 0; r < 4; ++r) accS[nt][r] = 0.f;

  // Prologue: stage K tile (h=0,c=0) into BsK[0].
#pragma unroll
  for (int j = 0; j < 4; ++j) {
    const int row = wv * 16 + j * 4 + kRL;   // 0..63
    gl2lds16(Kb + (size_t)pidx[row] * 512 + ((kCH ^ (row & 7)) << 3),
             &BsK[0][(wv * 16 + j * 4) * 128]);
  }
  __syncthreads();   // implicit vmcnt(0): tile 0 landed

  bf16x8 qf[4];
  floatx4 O[8];
  float m_i = -3e38f, l_i = 0.f;

  for (int idx = 0; idx < 16; ++idx) {
    const int h = idx >> 2, c = idx & 3;
    const int cur = idx & 1;

    if (c == 0) {
      // New head: load Q fragments, reset online-softmax state.
      const ushort_t* qrow = Qb + (size_t)qidx * 512 + h * 128 + quad * 8;
#pragma unroll
      for (int ks = 0; ks < 4; ++ks)
        qf[ks] = *reinterpret_cast<const bf16x8*>(qrow + ks * 32);
#pragma unroll
      for (int nt = 0; nt < 8; ++nt) O[nt] = (floatx4){0.f, 0.f, 0.f, 0.f};
      m_i = -3e38f;
      l_i = 0.f;
    }

    // Prefetch next (h,c) K tile into the other buffer (drained by the
    // end-of-iteration barrier's implicit vmcnt(0)).
    if (idx < 15) {
      const int hn = (idx + 1) >> 2, cn = (idx + 1) & 3;
      const int nb = cur ^ 1;
#pragma unroll
      for (int j = 0; j < 4; ++j) {
        const int row = wv * 16 + j * 4 + kRL;
        gl2lds16(Kb + (size_t)pidx[cn * 64 + row] * 512 + hn * 128 +
                     ((kCH ^ (row & 7)) << 3),
                 &BsK[nb][(wv * 16 + j * 4) * 128]);
      }
    }

    // ---- swapped QK^T: S[nt][r] = score[key = nt*16+quad*4+r][qrow = l16] ----
    floatx4 S[4] = {};
#pragma unroll
    for (int ks = 0; ks < 4; ++ks) {
      const int ac = ks * 4 + quad;
#pragma unroll
      for (int nt = 0; nt < 4; ++nt) {
        bf16x8 b = *reinterpret_cast<const bf16x8*>(
            &BsK[cur][(nt * 16 + l16) * 128 + ((ac ^ kswz) << 3)]);
        S[nt] = __builtin_amdgcn_mfma_f32_16x16x32_bf16(b, qf[ks], S[nt], 0, 0, 0);
      }
    }

    // ---- lane-local softmax (exp2 domain, defer-max) ----
    float cm;
    {
      const float m0 = fmaxf(fmaxf(S[0][0], S[0][1]), fmaxf(S[0][2], S[0][3]));
      const float m1 = fmaxf(fmaxf(S[1][0], S[1][1]), fmaxf(S[1][2], S[1][3]));
      const float m2 = fmaxf(fmaxf(S[2][0], S[2][1]), fmaxf(S[2][2], S[2][3]));
      const float m3 = fmaxf(fmaxf(S[3][0], S[3][1]), fmaxf(S[3][2], S[3][3]));
      cm = fmaxf(fmaxf(m0, m1), fmaxf(m2, m3));
      cm = fmaxf(cm, __shfl_xor(cm, 16));
      cm = fmaxf(cm, __shfl_xor(cm, 32));   // chunk max for qrow l16
    }
    if (!__all(cm <= m_i + DEFER_THR)) {
      const float mn = fmaxf(m_i, cm);
      const float sc = exp2f((m_i - mn) * C2EXP);
      m_i = mn;
      l_i *= sc;
      float scR[4];
#pragma unroll
      for (int r = 0; r < 4; ++r) scR[r] = __shfl(sc, quad * 4 + r);
#pragma unroll
      for (int nt = 0; nt < 8; ++nt)
#pragma unroll
        for (int r = 0; r < 4; ++r) O[nt][r] *= scR[r];
    }
    {
      const float mC = m_i * C2EXP;
      float ps = 0.f;
#pragma unroll
      for (int nt = 0; nt < 4; ++nt) {
        const float p0 = exp2f(S[nt][0] * C2EXP - mC);
        const float p1 = exp2f(S[nt][1] * C2EXP - mC);
        const float p2 = exp2f(S[nt][2] * C2EXP - mC);
        const float p3 = exp2f(S[nt][3] * C2EXP - mC);
        ps += (p0 + p1) + (p2 + p3);
        uint2 pk2 = make_uint2(pack2bf(p0, p1), pack2bf(p2, p3));
        *reinterpret_cast<uint2*>(&Ps[wv][l16 * 72 + nt * 16 + quad * 4]) = pk2;
      }
      ps += __shfl_xor(ps, 16);
      ps += __shfl_xor(ps, 32);
      l_i += ps;
    }
    // Ps write->read is within-wave (lgkmcnt-ordered).

    __syncthreads();   // prev unit's PV readers of SBV done
    // ---- V stage: scalar-scatter transpose (round-8 verbatim, -> SBV) ----
#pragma unroll
    for (int i = 0; i < 4; ++i) {
      const int e = tid + 256 * i;
      const int key = e & 63, dc8 = (e >> 6) * 8;
      uint4 vv = *reinterpret_cast<const uint4*>(
          Vb + (size_t)pidx[c * 64 + key] * 512 + h * 128 + dc8);
      const ushort_t* u = reinterpret_cast<const ushort_t*>(&vv);
#pragma unroll
      for (int j = 0; j < 8; ++j) {
        const int d = dc8 + j;
        SBV[d * 64 + (((key >> 3) ^ j) << 3) + (key & 7)] = u[j];
      }
    }
    __syncthreads();   // V staged

    // ---- PV ----
#pragma unroll
    for (int ks = 0; ks < 2; ++ks) {
      bf16x8 a = *reinterpret_cast<const bf16x8*>(&Ps[wv][l16 * 72 + ks * 32 + quad * 8]);
#pragma unroll
      for (int nt = 0; nt < 8; ++nt) {
        const int d = nt * 16 + l16;
        const int q8 = ks * 4 + quad;
        bf16x8 b = *reinterpret_cast<const bf16x8*>(
            &SBV[d * 64 + ((q8 ^ (d & 7)) << 3)]);
        O[nt] = __builtin_amdgcn_mfma_f32_16x16x32_bf16(a, b, O[nt], 0, 0, 0);
      }
    }

    if (c == 3) {
      // End of head h: fold normalized O into accS.
      float invR[4];
#pragma unroll
      for (int r = 0; r < 4; ++r) invR[r] = 1.0f / __shfl(l_i, quad * 4 + r);
#pragma unroll
      for (int nt = 0; nt < 8; ++nt)
#pragma unroll
        for (int r = 0; r < 4; ++r) accS[nt][r] += O[nt][r] * invR[r];
    }

    __syncthreads();   // drains next-tile gl2lds; all waves done with cur/SBV
  }

#pragma unroll
  for (int r = 0; r < 4; ++r) {
    const int n = pidx[qg * 64 + wv * 16 + quad * 4 + r];
#pragma unroll
    for (int nt = 0; nt < 8; ++nt)
      locS[(size_t)n * 128 + nt * 16 + l16] = f2bf(accS[nt][r] * 0.25f);
  }
}

// ---------------------------------------------------------------------------
// K5: MFMA cross-attention (verified round 14).
// ---------------------------------------------------------------------------
__global__ __launch_bounds__(256, 2) void k_cross(
    const ushort_t* __restrict__ Qb, const ushort_t* __restrict__ rpk,
    const ushort_t* __restrict__ rvT, ushort_t* __restrict__ glb)
{
  const int h = blockIdx.y;
  const int n0 = blockIdx.x * 64;
  const int tid = threadIdx.x, lane = tid & 63, wv = tid >> 6;
  const int l16 = lane & 15, quad = lane >> 4;

  __shared__ __align__(16) ushort_t BsK[2][64 * 128];   // 2 x 16 KiB
  __shared__ __align__(16) ushort_t BsV[2][128 * 64];   // 2 x 16 KiB
  __shared__ __align__(16) ushort_t Ps[4][16 * 72];     // 9 KiB wave-private

  bf16x8 qf[4];
  {
    const ushort_t* qrow =
        Qb + (size_t)(n0 + wv * 16 + l16) * 512 + h * 128 + quad * 8;
#pragma unroll
    for (int ks = 0; ks < 4; ++ks)
      qf[ks] = *reinterpret_cast<const bf16x8*>(qrow + ks * 32);
  }

  const int kRL = lane >> 4;        // row-in-group 0..3 (K)
  const int kCH = lane & 15;        // 16B chunk 0..15  (K)
  const int vDL = lane >> 3;        // row-in-group 0..7 (V)
  const int vCH = lane & 7;         // 16B chunk 0..7   (V)

  floatx4 O[8] = {};
  float m_i = -3e38f, l_i = 0.f;    // for qrow = l16 (replicated over quads)

  {
#pragma unroll
    for (int j = 0; j < 4; ++j) {
      const int row = wv * 16 + j * 4 + kRL;     // 0..63
      gl2lds16(rpk + (size_t)row * 512 + h * 128 + ((kCH ^ (row & 7)) << 3),
               &BsK[0][(wv * 16 + j * 4) * 128]);
      const int d = wv * 32 + j * 8 + vDL;       // 0..127
      gl2lds16(rvT + (size_t)(h * 128 + d) * 512 + ((vCH ^ (d & 7)) << 3),
               &BsV[0][(wv * 32 + j * 8) * 64]);
    }
  }
  __syncthreads();   // implicit vmcnt(0): chunk 0 landed

  const int kswz = l16 & 7;

  for (int c = 0; c < 8; ++c) {
    const int cur = c & 1;

    if (c < 7) {
      const int nb = cur ^ 1;
      const int cn = c + 1;
#pragma unroll
      for (int j = 0; j < 4; ++j) {
        const int row = wv * 16 + j * 4 + kRL;
        gl2lds16(rpk + (size_t)(cn * 64 + row) * 512 + h * 128 +
                     ((kCH ^ (row & 7)) << 3),
                 &BsK[nb][(wv * 16 + j * 4) * 128]);
        const int d = wv * 32 + j * 8 + vDL;
        gl2lds16(rvT + (size_t)(h * 128 + d) * 512 + cn * 64 +
                     ((vCH ^ (d & 7)) << 3),
                 &BsV[nb][(wv * 32 + j * 8) * 64]);
      }
    }

    // ---- swapped QK^T: S[nt][r] = score[rep=nt*16+quad*4+r][qrow=l16] ----
    floatx4 S[4] = {};
#pragma unroll
    for (int ks = 0; ks < 4; ++ks) {
      const int ac = ks * 4 + quad;
#pragma unroll
      for (int nt = 0; nt < 4; ++nt) {
        bf16x8 b = *reinterpret_cast<const bf16x8*>(
            &BsK[cur][(nt * 16 + l16) * 128 + ((ac ^ kswz) << 3)]);
        S[nt] = __builtin_amdgcn_mfma_f32_16x16x32_bf16(b, qf[ks], S[nt], 0, 0, 0);
      }
    }

    // ---- softmax over lane-local reps (exp2 domain, defer-max) ----
    float cm;
    {
      const float m0 = fmaxf(fmaxf(S[0][0], S[0][1]), fmaxf(S[0][2], S[0][3]));
      const float m1 = fmaxf(fmaxf(S[1][0], S[1][1]), fmaxf(S[1][2], S[1][3]));
      const float m2 = fmaxf(fmaxf(S[2][0], S[2][1]), fmaxf(S[2][2], S[2][3]));
      const float m3 = fmaxf(fmaxf(S[3][0], S[3][1]), fmaxf(S[3][2], S[3][3]));
      cm = fmaxf(fmaxf(m0, m1), fmaxf(m2, m3));
      cm = fmaxf(cm, __shfl_xor(cm, 16));
      cm = fmaxf(cm, __shfl_xor(cm, 32));   // chunk max for qrow l16
    }
    if (!__all(cm <= m_i + DEFER_THR)) {
      const float mn = fmaxf(m_i, cm);
      const float sc = exp2f((m_i - mn) * C2EXP);
      m_i = mn;
      l_i *= sc;
      float scR[4];
#pragma unroll
      for (int r = 0; r < 4; ++r) scR[r] = __shfl(sc, quad * 4 + r);
#pragma unroll
      for (int nt = 0; nt < 8; ++nt)
#pragma unroll
        for (int r = 0; r < 4; ++r) O[nt][r] *= scR[r];
    }
    {
      const float mC = m_i * C2EXP;
      float ps = 0.f;
#pragma unroll
      for (int nt = 0; nt < 4; ++nt) {
        const float p0 = exp2f(S[nt][0] * C2EXP - mC);
        const float p1 = exp2f(S[nt][1] * C2EXP - mC);
        const float p2 = exp2f(S[nt][2] * C2EXP - mC);
        const float p3 = exp2f(S[nt][3] * C2EXP - mC);
        ps += (p0 + p1) + (p2 + p3);
        uint2 pk2 = make_uint2(pack2bf(p0, p1), pack2bf(p2, p3));
        *reinterpret_cast<uint2*>(&Ps[wv][l16 * 72 + nt * 16 + quad * 4]) = pk2;
      }
      ps += __shfl_xor(ps, 16);
      ps += __shfl_xor(ps, 32);             // chunk sum for qrow l16
      l_i += ps;
    }

    // ---- PV ----
#pragma unroll
    for (int ks = 0; ks < 2; ++ks) {
      bf16x8 a = *reinterpret_cast<const bf16x8*>(&Ps[wv][l16 * 72 + ks * 32 + quad * 8]);
#pragma unroll
      for (int nt = 0; nt < 8; ++nt) {
        const int q8 = ks * 4 + quad;
        bf16x8 b = *reinterpret_cast<const bf16x8*>(
            &BsV[cur][(nt * 16 + l16) * 64 + ((q8 ^ kswz) << 3)]);
        O[nt] = __builtin_amdgcn_mfma_f32_16x16x32_bf16(a, b, O[nt], 0, 0, 0);
      }
    }

    __syncthreads();   // drains next-chunk loads; all waves done with 'cur'
  }

  float invR[4];
#pragma unroll
  for (int r = 0; r < 4; ++r) invR[r] = 1.0f / __shfl(l_i, quad * 4 + r);
#pragma unroll
  for (int r = 0; r < 4; ++r) {
    const int n = n0 + wv * 16 + quad * 4 + r;
#pragma unroll
    for (int nt = 0; nt < 8; ++nt)
      glb[(size_t)n * 512 + h * 128 + nt * 16 + l16] = f2bf(O[nt][r] * invR[r]);
  }
}

// ---------------------------------------------------------------------------
// K6: combine -> f32 output.
// ---------------------------------------------------------------------------
__global__ __launch_bounds__(256) void k_combine(
    const ushort_t* __restrict__ locS, const ushort_t* __restrict__ glb,
    const ushort_t* __restrict__ Vb, const float* __restrict__ scal,
    float* __restrict__ out)
{
  const int t = blockIdx.x * 256 + threadIdx.x;
  const int n = t >> 6, dp = t & 63;
  const float alpha = 1.0f / (1.0f + __expf(-scal[0]));
  const float beta = scal[1];
  const uint32 lv = reinterpret_cast<const uint32*>(locS)[(size_t)n * 64 + dp];
  float g0 = 0.f, g1 = 0.f, v0 = 0.f, v1 = 0.f;
#pragma unroll
  for (int hh = 0; hh < 4; ++hh) {
    const uint32 gv = *reinterpret_cast<const uint32*>(glb + (size_t)n * 512 + hh * 128 + 2 * dp);
    const uint32 vv = *reinterpret_cast<const uint32*>(Vb + (size_t)n * 512 + hh * 128 + 2 * dp);
    g0 += bflo(gv); g1 += bfhi(gv);
    v0 += bflo(vv); v1 += bfhi(vv);
  }
  const float r0 = alpha * bflo(lv) + (1.0f - alpha) * g0 * 0.25f + beta * v0 * 0.25f;
  const float r1 = alpha * bfhi(lv) + (1.0f - alpha) * g1 * 0.25f + beta * v1 * 0.25f;
  reinterpret_cast<float2*>(out)[(size_t)n * 64 + dp] = make_float2(r0, r1);
}

extern "C" void kernel_launch(void* const* d_in, const int* in_sizes, int n_in,
                              void* d_out, int out_size, void* d_ws, size_t ws_size,
                              hipStream_t stream) {
  const void* x     = d_in[0];
  const int*  pidx  = (const int*)d_in[1];
  const void* Wq    = d_in[2];
  const void* bq    = d_in[3];
  const void* Wk    = d_in[4];
  const void* bk    = d_in[5];
  const void* Wv    = d_in[6];
  const void* bv    = d_in[7];
  const void* seeds = d_in[8];
  const void* al    = d_in[9];
  const void* be    = d_in[10];

  char* ws = (char*)d_ws;
  ushort_t* Qb   = (ushort_t*)(ws + OFF_Q);
  ushort_t* Kb   = (ushort_t*)(ws + OFF_K);
  ushort_t* Vb   = (ushort_t*)(ws + OFF_V);
  ushort_t* locS = (ushort_t*)(ws + OFF_LOC);
  ushort_t* rpk  = (ushort_t*)(ws + OFF_RPK);
  ushort_t* xc   = (ushort_t*)(ws + OFF_XC);
  ushort_t* wc   = (ushort_t*)(ws + OFF_WC);
  float*    scal = (float*)   (ws + OFF_SCAL);
  uint32*   flags= (uint32*)  (ws + OFF_FLAG);
  ushort_t* rvT  = (ushort_t*)(ws + OFF_RVT);
  ushort_t* glb  = (ushort_t*)(ws + OFF_GLB);

  k_detect<<<1, 64, 0, stream>>>((const uint32*)x, (const ushort_t*)be, flags);
  k_convert<<<dim3(4096, 2), 256, 0, stream>>>(x, Wq, bq, Wk, bk, Wv, bv, seeds, al, be,
                                               xc, wc, scal, flags);
  k_qkv<<<512, 256, 0, stream>>>(xc, wc, Qb, Kb, Vb);
  k_pool<<<dim3(128, 4), 256, 0, stream>>>(Kb, Vb, pidx, wc, rpk, rvT);
  k_fine<<<dim3(128, 4), 256, 0, stream>>>(Qb, Kb, Vb, pidx, locS);
  k_cross<<<dim3(512, 4), 256, 0, stream>>>(Qb, rpk, rvT, glb);
  k_combine<<<8192, 256, 0, stream>>>(locS, glb, Vb, scal, (float*)d_out);
}

// Round 7
// 320.174 us; speedup vs baseline: 1.6426x; 1.0371x over previous
//
#include <hip/hip_runtime.h>
#include <hip/hip_bf16.h>

// PCGTConvLayer round 16: k_cross widened to 128 Q-rows per block (grid
// 256x4). The staged K/V chunk (unchanged, double-buffered gl2lds) now feeds
// TWO sequential 64-row compute sets -> staging bytes, staging VALU and
// barriers per flop halve; Ps LDS reused by both sets (no growth, 73 KiB,
// 2 blocks/CU). Ps pack now uses hw v_cvt_pk_bf16_f32 (RNE, same as f2bf).
// All other kernels verbatim from round 15 (332.1 us).
// N=32768 IN=256 D=128 H=4 M=4 KP=128 S=256, SCALE=sqrt(128).

#define INV_SCALE 0.08838834764831845f
// INV_SCALE * log2(e)
#define C2EXP 0.12751744f
// 8 / INV_SCALE  (defer-max threshold in unscaled-score domain)
#define DEFER_THR 90.50966799f

typedef __attribute__((ext_vector_type(8))) short bf16x8;
typedef __attribute__((ext_vector_type(4))) float floatx4;
typedef unsigned short ushort_t;
typedef unsigned int uint32;

// ---- ws layout (bytes) ----
#define OFF_Q    0ull            // bf16 [32768][512]
#define OFF_K    33554432ull     // bf16 [32768][512]
#define OFF_V    67108864ull     // bf16 [32768][512]
#define OFF_LOC  100663296ull    // bf16 [32768][128]
#define OFF_RPK  109051904ull    // bf16 [512][4][128]
#define OFF_XC   110100480ull    // bf16 [32768][256]
#define OFF_WC   126877696ull    // bf16: WqT,WkT,WvT ([512][256] each), biases, seeds
#define OFF_SCAL 127671296ull    // f32 [2]
#define OFF_FLAG 127671304ull    // u32 [2]
#define OFF_RVT  127672320ull    // bf16 [4][128][512]
#define OFF_GLB  128196608ull    // bf16 [32768][512]

#define WC_WQ 0
#define WC_WK 131072
#define WC_WV 262144
#define WC_BQ 393216
#define WC_BK 393728
#define WC_BV 394240
#define WC_SEED 394752
#define WC_TOT 396800

static __device__ __forceinline__ float bflo(uint32 u) {
  return __uint_as_float(u << 16);
}
static __device__ __forceinline__ float bfhi(uint32 u) {
  return __uint_as_float(u & 0xffff0000u);
}
static __device__ __forceinline__ float bf2f(ushort_t u) {
  return __uint_as_float(((uint32)u) << 16);
}
static __device__ __forceinline__ ushort_t f2bf(float f) {
  uint32 x = __float_as_uint(f);
  uint32 r = x + 0x7fffu + ((x >> 16) & 1u);
  return (ushort_t)(r >> 16);
}
static __device__ __forceinline__ uint32 pack2bf(float a, float b) {
  return (uint32)f2bf(a) | ((uint32)f2bf(b) << 16);
}
// HW packed f32->bf16 (RNE; lo16 = a, hi16 = b). Same rounding as f2bf.
static __device__ __forceinline__ uint32 cvtpk(float a, float b) {
  uint32 r;
  asm("v_cvt_pk_bf16_f32 %0, %1, %2" : "=v"(r) : "v"(a), "v"(b));
  return r;
}

// async global -> LDS, 16 bytes per lane. LDS dest must be wave-uniform base;
// lane i lands at base + i*16 B. Global source is per-lane.
static __device__ __forceinline__ void gl2lds16(const ushort_t* g, ushort_t* l) {
  __builtin_amdgcn_global_load_lds(
      (const __attribute__((address_space(1))) void*)g,
      (__attribute__((address_space(3))) void*)l, 16, 0, 0);
}

// ---------------------------------------------------------------------------
__global__ __launch_bounds__(64) void k_detect(const uint32* __restrict__ xw,
                                               const ushort_t* __restrict__ betaRaw,
                                               uint32* __restrict__ flags) {
  const int lane = threadIdx.x;
  const uint32 w = xw[lane * 137 + 3];
  const int e = (w >> 7) & 0xff;
  const unsigned long long b = __ballot(e >= 100 && e <= 140);
  if (lane == 0) {
    flags[0] = (__popcll(b) >= 48) ? 1u : 0u;
    flags[1] = (betaRaw[0] != 0) ? 1u : 0u;
  }
}

// ---------------------------------------------------------------------------
// K1: canonicalize. x -> xc (identity layout). W matrices -> TRANSPOSED
// bf16 [512][256] at same wc offsets. biases/seeds identity.
// ---------------------------------------------------------------------------
static __device__ __forceinline__ void conv8(const void* src, long j, int isB,
                                             ushort_t* dst) {
  if (isB) {
    *reinterpret_cast<uint4*>(dst) =
        *reinterpret_cast<const uint4*>(reinterpret_cast<const ushort_t*>(src) + j);
  } else {
    const float* f = reinterpret_cast<const float*>(src) + j;
    const float4 a = *reinterpret_cast<const float4*>(f);
    const float4 b = *reinterpret_cast<const float4*>(f + 4);
    uint4 o;
    o.x = pack2bf(a.x, a.y); o.y = pack2bf(a.z, a.w);
    o.z = pack2bf(b.x, b.y); o.w = pack2bf(b.z, b.w);
    *reinterpret_cast<uint4*>(dst) = o;
  }
}

__global__ __launch_bounds__(256) void k_convert(
    const void* __restrict__ x,
    const void* __restrict__ Wq, const void* __restrict__ bq,
    const void* __restrict__ Wk, const void* __restrict__ bk,
    const void* __restrict__ Wv, const void* __restrict__ bv,
    const void* __restrict__ seeds, const void* __restrict__ alpha,
    const void* __restrict__ beta,
    ushort_t* __restrict__ xc, ushort_t* __restrict__ wc,
    float* __restrict__ scal, const uint32* __restrict__ flags)
{
  const int isB = (int)flags[0];
  const long i8 = ((long)blockIdx.x * 256 + threadIdx.x) * 8;
  if (blockIdx.y == 0) {
    conv8(x, i8, isB, xc + i8);
  } else {
    if (i8 < WC_BQ) {
      // W region: transpose. i8 = sel*131072 + k*512 + n (8 consecutive n).
      const int sel = (int)(i8 >> 17);
      const long local = i8 & 131071;
      const int kk = (int)(local >> 9);
      const int nn = (int)(local & 511);
      const void* src = sel == 0 ? Wq : (sel == 1 ? Wk : Wv);
      ushort_t* dstW = wc + sel * 131072;
#pragma unroll
      for (int j = 0; j < 8; ++j) {
        ushort_t v;
        if (isB) v = reinterpret_cast<const ushort_t*>(src)[local + j];
        else     v = f2bf(reinterpret_cast<const float*>(src)[local + j]);
        dstW[(size_t)(nn + j) * 256 + kk] = v;
      }
    } else if (i8 < WC_TOT) {
      const void* src; long j;
      if (i8 < WC_BK)        { src = bq;    j = i8 - WC_BQ; }
      else if (i8 < WC_BV)   { src = bk;    j = i8 - WC_BK; }
      else if (i8 < WC_SEED) { src = bv;    j = i8 - WC_BV; }
      else                   { src = seeds; j = i8 - WC_SEED; }
      conv8(src, j, isB, wc + i8);
    }
    if (blockIdx.x == 0 && threadIdx.x == 0) {
      const int isBS = (int)flags[1];
      scal[0] = isBS ? bf2f(reinterpret_cast<const ushort_t*>(alpha)[0])
                     : reinterpret_cast<const float*>(alpha)[0];
      scal[1] = isBS ? bf2f(reinterpret_cast<const ushort_t*>(beta)[0])
                     : reinterpret_cast<const float*>(beta)[0];
    }
  }
}

// ---------------------------------------------------------------------------
// K2: fused QKV GEMM. One block = 64 rows of x; loops sel(3) x 8 col-chunks.
// Xs staged ONCE (XOR-swizzled: chunk c of row at ((c^(row&7))<<3)); Ws from
// W^T with identical swizzle via coalesced uint4. MFMA 16x16x32, wave =
// 16 rows x 64 cols per chunk. LDS exactly 64 KiB.
// ---------------------------------------------------------------------------
__global__ __launch_bounds__(256) void k_qkv(
    const ushort_t* __restrict__ xc, const ushort_t* __restrict__ wc,
    ushort_t* __restrict__ Qb, ushort_t* __restrict__ Kb, ushort_t* __restrict__ Vb)
{
  const int m0 = blockIdx.x * 64;
  const int tid = threadIdx.x, lane = tid & 63, wv = tid >> 6;
  const int l16 = lane & 15, quad = lane >> 4;

  __shared__ __align__(16) ushort_t Xs[64 * 256];   // 32 KiB
  __shared__ __align__(16) ushort_t Ws[64 * 256];   // 32 KiB

#pragma unroll
  for (int i = 0; i < 8; ++i) {
    const int id = tid + 256 * i;          // 2048 chunks of 8
    const int row = id >> 5, c = id & 31;
    uint4 v = *reinterpret_cast<const uint4*>(xc + (size_t)(m0 + row) * 256 + c * 8);
    *reinterpret_cast<uint4*>(&Xs[row * 256 + ((c ^ (row & 7)) << 3)]) = v;
  }

  for (int sel = 0; sel < 3; ++sel) {
    const ushort_t* WT   = wc + sel * 131072;
    const ushort_t* bias = wc + WC_BQ + sel * 512;
    ushort_t* out        = sel == 0 ? Qb : (sel == 1 ? Kb : Vb);
    for (int nc = 0; nc < 8; ++nc) {
      const int n0 = nc * 64;
      __syncthreads();   // prev chunk's Ws readers done (also orders Xs staging)
#pragma unroll
      for (int i = 0; i < 8; ++i) {
        const int id = tid + 256 * i;
        const int row = id >> 5, c = id & 31;
        uint4 v = *reinterpret_cast<const uint4*>(WT + (size_t)(n0 + row) * 256 + c * 8);
        *reinterpret_cast<uint4*>(&Ws[row * 256 + ((c ^ (row & 7)) << 3)]) = v;
      }
      __syncthreads();

      floatx4 acc[4] = {};
      const int arow = wv * 16 + l16;
#pragma unroll
      for (int ks = 0; ks < 8; ++ks) {
        const int ac = ks * 4 + quad;
        bf16x8 a = *reinterpret_cast<const bf16x8*>(&Xs[arow * 256 + ((ac ^ (arow & 7)) << 3)]);
#pragma unroll
        for (int nt = 0; nt < 4; ++nt) {
          const int brow = nt * 16 + l16;
          bf16x8 b = *reinterpret_cast<const bf16x8*>(&Ws[brow * 256 + ((ac ^ (brow & 7)) << 3)]);
          acc[nt] = __builtin_amdgcn_mfma_f32_16x16x32_bf16(a, b, acc[nt], 0, 0, 0);
        }
      }

#pragma unroll
      for (int nt = 0; nt < 4; ++nt) {
        const int col = n0 + nt * 16 + l16;
        const float bf = bf2f(bias[col]);
#pragma unroll
        for (int r = 0; r < 4; ++r) {
          const int row = m0 + wv * 16 + quad * 4 + r;
          out[(size_t)row * 512 + col] = f2bf(acc[nt][r] + bf);
        }
      }
    }
  }
}

// ---------------------------------------------------------------------------
// K3: pooling (seeds -> rpk, rvT). Verified (CHK3).
// ---------------------------------------------------------------------------
__global__ __launch_bounds__(256) void k_pool(
    const ushort_t* __restrict__ Kb, const ushort_t* __restrict__ Vb,
    const int* __restrict__ pidx_all, const ushort_t* __restrict__ wc,
    ushort_t* __restrict__ rpk, ushort_t* __restrict__ rvT)
{
  const int k = blockIdx.x, h = blockIdx.y;
  const int tid = threadIdx.x, lane = tid & 63, wv = tid >> 6;
  const int* pidx = pidx_all + k * 256;

  __shared__ __align__(16) ushort_t SB[128 * 256];
  const uint32* SBU = reinterpret_cast<const uint32*>(SB);

#pragma unroll
  for (int i = 0; i < 16; ++i) {
    const int e8 = tid + 256 * i;
    const int q = e8 >> 4, dc = (e8 & 15) * 8;
    uint4 kv = *reinterpret_cast<const uint4*>(Kb + (size_t)pidx[q] * 512 + h * 128 + dc);
    const ushort_t* ku = reinterpret_cast<const ushort_t*>(&kv);
    const int qp = q >> 1, qb = q & 1;
#pragma unroll
    for (int j = 0; j < 8; ++j) {
      const int d = dc + j;
      SB[d * 256 + (((qp ^ (d & 31)) << 1) | qb)] = ku[j];
    }
  }
  __syncthreads();

  float q00, q01, q10, q11;
  {
    const uint32* ssrc = reinterpret_cast<const uint32*>(wc + WC_SEED + (size_t)(wv * 4 + h) * 128);
    float s00 = 0.f, s01 = 0.f, s10 = 0.f, s11 = 0.f;
#pragma unroll 8
    for (int dc = 0; dc < 64; ++dc) {
      const uint32 qv = ssrc[dc];
      const float a0 = bflo(qv), a1 = bfhi(qv);
      const int d0 = dc * 2, d1 = d0 + 1;
      const int c0 = lane ^ (d0 & 31);
      const int c1 = lane ^ (d1 & 31);
      const uint32 u00 = SBU[d0 * 128 + c0];
      const uint32 u01 = SBU[d0 * 128 + c0 + 64];
      const uint32 u10 = SBU[d1 * 128 + c1];
      const uint32 u11 = SBU[d1 * 128 + c1 + 64];
      s00 += a0 * bflo(u00) + a1 * bflo(u10);
      s01 += a0 * bfhi(u00) + a1 * bfhi(u10);
      s10 += a0 * bflo(u01) + a1 * bflo(u11);
      s11 += a0 * bfhi(u01) + a1 * bfhi(u11);
    }
    s00 *= INV_SCALE; s01 *= INV_SCALE; s10 *= INV_SCALE; s11 *= INV_SCALE;
    float mx = fmaxf(fmaxf(s00, s01), fmaxf(s10, s11));
#pragma unroll
    for (int off = 32; off >= 1; off >>= 1) mx = fmaxf(mx, __shfl_xor(mx, off));
    const float e00 = __expf(s00 - mx), e01 = __expf(s01 - mx);
    const float e10 = __expf(s10 - mx), e11 = __expf(s11 - mx);
    float sm = e00 + e01 + e10 + e11;
#pragma unroll
    for (int off = 32; off >= 1; off >>= 1) sm += __shfl_xor(sm, off);
    const float inv = 1.0f / sm;
    q00 = e00 * inv; q01 = e01 * inv; q10 = e10 * inv; q11 = e11 * inv;
  }

  {
    float rk0 = 0.f, rk1 = 0.f;
    const int d0 = 2 * lane, d1 = 2 * lane + 1;
#pragma unroll 4
    for (int qp = 0; qp < 64; ++qp) {
      const float pa = __shfl(q00, qp), pb = __shfl(q01, qp);
      const float pc = __shfl(q10, qp), pd = __shfl(q11, qp);
      const int c0 = qp ^ (d0 & 31);
      const int c1 = qp ^ (d1 & 31);
      const uint32 u0  = SBU[d0 * 128 + c0];
      const uint32 u0b = SBU[d0 * 128 + c0 + 64];
      const uint32 u1  = SBU[d1 * 128 + c1];
      const uint32 u1b = SBU[d1 * 128 + c1 + 64];
      rk0 += pa * bflo(u0) + pb * bfhi(u0) + pc * bflo(u0b) + pd * bfhi(u0b);
      rk1 += pa * bflo(u1) + pb * bfhi(u1) + pc * bflo(u1b) + pd * bfhi(u1b);
    }
    reinterpret_cast<uint32*>(rpk + ((size_t)((k * 4 + wv) * 4 + h)) * 128)[lane] = pack2bf(rk0, rk1);
  }
  __syncthreads();

#pragma unroll
  for (int i = 0; i < 16; ++i) {
    const int e8 = tid + 256 * i;
    const int q = e8 >> 4, dc = (e8 & 15) * 8;
    uint4 vv = *reinterpret_cast<const uint4*>(Vb + (size_t)pidx[q] * 512 + h * 128 + dc);
    *reinterpret_cast<uint4*>(&SB[q * 128 + dc]) = vv;
  }
  __syncthreads();

  {
    float rv0 = 0.f, rv1 = 0.f;
#pragma unroll 4
    for (int qp = 0; qp < 64; ++qp) {
      const float pa = __shfl(q00, qp), pb = __shfl(q01, qp);
      const float pc = __shfl(q10, qp), pd = __shfl(q11, qp);
      const uint32 v00 = SBU[(2 * qp) * 64 + lane];
      const uint32 v01 = SBU[(2 * qp + 1) * 64 + lane];
      const uint32 v10 = SBU[(128 + 2 * qp) * 64 + lane];
      const uint32 v11 = SBU[(129 + 2 * qp) * 64 + lane];
      rv0 += pa * bflo(v00) + pb * bflo(v01) + pc * bflo(v10) + pd * bflo(v11);
      rv1 += pa * bfhi(v00) + pb * bfhi(v01) + pc * bfhi(v10) + pd * bfhi(v11);
    }
    const int rrep = k * 4 + wv;
    rvT[(size_t)(h * 128 + 2 * lane) * 512 + rrep]     = f2bf(rv0);
    rvT[(size_t)(h * 128 + 2 * lane + 1) * 512 + rrep] = f2bf(rv1);
  }
}

// ---------------------------------------------------------------------------
// K4: MFMA fine attention (verified round 15).
// ---------------------------------------------------------------------------
__global__ __launch_bounds__(256) void k_fine(
    const ushort_t* __restrict__ Qb, const ushort_t* __restrict__ Kb,
    const ushort_t* __restrict__ Vb, const int* __restrict__ pidx_all,
    ushort_t* __restrict__ locS)
{
  const int k = blockIdx.x, qg = blockIdx.y;
  const int tid = threadIdx.x, lane = tid & 63, wv = tid >> 6;
  const int l16 = lane & 15, quad = lane >> 4;
  const int* pidx = pidx_all + k * 256;

  __shared__ __align__(16) ushort_t BsK[2][64 * 128];  // 2 x 16 KiB
  __shared__ __align__(16) ushort_t SBV[128 * 64];     // 16 KiB (V^T scatter)
  __shared__ __align__(16) ushort_t Ps[4][16 * 72];    // 9 KiB wave-private

  // This lane's q-row global index (q-row = l16 within the wave's 16 rows).
  const int qidx = pidx[qg * 64 + wv * 16 + l16];

  // K staging lane coordinates (round-13 pattern).
  const int kRL = lane >> 4;        // row-in-group 0..3
  const int kCH = lane & 15;        // 16B chunk 0..15
  const int kswz = l16 & 7;

  float accS[8][4];
#pragma unroll
  for (int nt = 0; nt < 8; ++nt)
#pragma unroll
    for (int r = 0; r < 4; ++r) accS[nt][r] = 0.f;

  // Prologue: stage K tile (h=0,c=0) into BsK[0].
#pragma unroll
  for (int j = 0; j < 4; ++j) {
    const int row = wv * 16 + j * 4 + kRL;   // 0..63
    gl2lds16(Kb + (size_t)pidx[row] * 512 + ((kCH ^ (row & 7)) << 3),
             &BsK[0][(wv * 16 + j * 4) * 128]);
  }
  __syncthreads();   // implicit vmcnt(0): tile 0 landed

  bf16x8 qf[4];
  floatx4 O[8];
  float m_i = -3e38f, l_i = 0.f;

  for (int idx = 0; idx < 16; ++idx) {
    const int h = idx >> 2, c = idx & 3;
    const int cur = idx & 1;

    if (c == 0) {
      // New head: load Q fragments, reset online-softmax state.
      const ushort_t* qrow = Qb + (size_t)qidx * 512 + h * 128 + quad * 8;
#pragma unroll
      for (int ks = 0; ks < 4; ++ks)
        qf[ks] = *reinterpret_cast<const bf16x8*>(qrow + ks * 32);
#pragma unroll
      for (int nt = 0; nt < 8; ++nt) O[nt] = (floatx4){0.f, 0.f, 0.f, 0.f};
      m_i = -3e38f;
      l_i = 0.f;
    }

    // Prefetch next (h,c) K tile into the other buffer (drained by the
    // end-of-iteration barrier's implicit vmcnt(0)).
    if (idx < 15) {
      const int hn = (idx + 1) >> 2, cn = (idx + 1) & 3;
      const int nb = cur ^ 1;
#pragma unroll
      for (int j = 0; j < 4; ++j) {
        const int row = wv * 16 + j * 4 + kRL;
        gl2lds16(Kb + (size_t)pidx[cn * 64 + row] * 512 + hn * 128 +
                     ((kCH ^ (row & 7)) << 3),
                 &BsK[nb][(wv * 16 + j * 4) * 128]);
      }
    }

    // ---- swapped QK^T: S[nt][r] = score[key = nt*16+quad*4+r][qrow = l16] ----
    floatx4 S[4] = {};
#pragma unroll
    for (int ks = 0; ks < 4; ++ks) {
      const int ac = ks * 4 + quad;
#pragma unroll
      for (int nt = 0; nt < 4; ++nt) {
        bf16x8 b = *reinterpret_cast<const bf16x8*>(
            &BsK[cur][(nt * 16 + l16) * 128 + ((ac ^ kswz) << 3)]);
        S[nt] = __builtin_amdgcn_mfma_f32_16x16x32_bf16(b, qf[ks], S[nt], 0, 0, 0);
      }
    }

    // ---- lane-local softmax (exp2 domain, defer-max) ----
    float cm;
    {
      const float m0 = fmaxf(fmaxf(S[0][0], S[0][1]), fmaxf(S[0][2], S[0][3]));
      const float m1 = fmaxf(fmaxf(S[1][0], S[1][1]), fmaxf(S[1][2], S[1][3]));
      const float m2 = fmaxf(fmaxf(S[2][0], S[2][1]), fmaxf(S[2][2], S[2][3]));
      const float m3 = fmaxf(fmaxf(S[3][0], S[3][1]), fmaxf(S[3][2], S[3][3]));
      cm = fmaxf(fmaxf(m0, m1), fmaxf(m2, m3));
      cm = fmaxf(cm, __shfl_xor(cm, 16));
      cm = fmaxf(cm, __shfl_xor(cm, 32));   // chunk max for qrow l16
    }
    if (!__all(cm <= m_i + DEFER_THR)) {
      const float mn = fmaxf(m_i, cm);
      const float sc = exp2f((m_i - mn) * C2EXP);
      m_i = mn;
      l_i *= sc;
      float scR[4];
#pragma unroll
      for (int r = 0; r < 4; ++r) scR[r] = __shfl(sc, quad * 4 + r);
#pragma unroll
      for (int nt = 0; nt < 8; ++nt)
#pragma unroll
        for (int r = 0; r < 4; ++r) O[nt][r] *= scR[r];
    }
    {
      const float mC = m_i * C2EXP;
      float ps = 0.f;
#pragma unroll
      for (int nt = 0; nt < 4; ++nt) {
        const float p0 = exp2f(S[nt][0] * C2EXP - mC);
        const float p1 = exp2f(S[nt][1] * C2EXP - mC);
        const float p2 = exp2f(S[nt][2] * C2EXP - mC);
        const float p3 = exp2f(S[nt][3] * C2EXP - mC);
        ps += (p0 + p1) + (p2 + p3);
        uint2 pk2 = make_uint2(pack2bf(p0, p1), pack2bf(p2, p3));
        *reinterpret_cast<uint2*>(&Ps[wv][l16 * 72 + nt * 16 + quad * 4]) = pk2;
      }
      ps += __shfl_xor(ps, 16);
      ps += __shfl_xor(ps, 32);
      l_i += ps;
    }
    // Ps write->read is within-wave (lgkmcnt-ordered).

    __syncthreads();   // prev unit's PV readers of SBV done
    // ---- V stage: scalar-scatter transpose (round-8 verbatim, -> SBV) ----
#pragma unroll
    for (int i = 0; i < 4; ++i) {
      const int e = tid + 256 * i;
      const int key = e & 63, dc8 = (e >> 6) * 8;
      uint4 vv = *reinterpret_cast<const uint4*>(
          Vb + (size_t)pidx[c * 64 + key] * 512 + h * 128 + dc8);
      const ushort_t* u = reinterpret_cast<const ushort_t*>(&vv);
#pragma unroll
      for (int j = 0; j < 8; ++j) {
        const int d = dc8 + j;
        SBV[d * 64 + (((key >> 3) ^ j) << 3) + (key & 7)] = u[j];
      }
    }
    __syncthreads();   // V staged

    // ---- PV ----
#pragma unroll
    for (int ks = 0; ks < 2; ++ks) {
      bf16x8 a = *reinterpret_cast<const bf16x8*>(&Ps[wv][l16 * 72 + ks * 32 + quad * 8]);
#pragma unroll
      for (int nt = 0; nt < 8; ++nt) {
        const int d = nt * 16 + l16;
        const int q8 = ks * 4 + quad;
        bf16x8 b = *reinterpret_cast<const bf16x8*>(
            &SBV[d * 64 + ((q8 ^ (d & 7)) << 3)]);
        O[nt] = __builtin_amdgcn_mfma_f32_16x16x32_bf16(a, b, O[nt], 0, 0, 0);
      }
    }

    if (c == 3) {
      // End of head h: fold normalized O into accS.
      float invR[4];
#pragma unroll
      for (int r = 0; r < 4; ++r) invR[r] = 1.0f / __shfl(l_i, quad * 4 + r);
#pragma unroll
      for (int nt = 0; nt < 8; ++nt)
#pragma unroll
        for (int r = 0; r < 4; ++r) accS[nt][r] += O[nt][r] * invR[r];
    }

    __syncthreads();   // drains next-tile gl2lds; all waves done with cur/SBV
  }

#pragma unroll
  for (int r = 0; r < 4; ++r) {
    const int n = pidx[qg * 64 + wv * 16 + quad * 4 + r];
#pragma unroll
    for (int nt = 0; nt < 8; ++nt)
      locS[(size_t)n * 128 + nt * 16 + l16] = f2bf(accS[nt][r] * 0.25f);
  }
}

// ---------------------------------------------------------------------------
// K5: MFMA cross-attention, round 16: 128 Q-rows per block (2 sequential
// 64-row sets share each staged chunk). Staging/barriers per flop halve;
// Ps reused by both sets (LDS unchanged, 73 KiB, 2 blocks/CU). cvt_pk
// hardware bf16 pack in the Ps store path.
// ---------------------------------------------------------------------------
__global__ __launch_bounds__(256, 2) void k_cross(
    const ushort_t* __restrict__ Qb, const ushort_t* __restrict__ rpk,
    const ushort_t* __restrict__ rvT, ushort_t* __restrict__ glb)
{
  const int h = blockIdx.y;
  const int n0 = blockIdx.x * 128;
  const int tid = threadIdx.x, lane = tid & 63, wv = tid >> 6;
  const int l16 = lane & 15, quad = lane >> 4;

  __shared__ __align__(16) ushort_t BsK[2][64 * 128];   // 2 x 16 KiB
  __shared__ __align__(16) ushort_t BsV[2][128 * 64];   // 2 x 16 KiB
  __shared__ __align__(16) ushort_t Ps[4][16 * 72];     // 9 KiB wave-private

  // Q fragments for both 64-row sets (set s: rows n0 + s*64 + wv*16 + l16).
  bf16x8 qf0[4], qf1[4];
  {
    const ushort_t* q0 =
        Qb + (size_t)(n0 + wv * 16 + l16) * 512 + h * 128 + quad * 8;
    const ushort_t* q1 = q0 + (size_t)64 * 512;
#pragma unroll
    for (int ks = 0; ks < 4; ++ks) {
      qf0[ks] = *reinterpret_cast<const bf16x8*>(q0 + ks * 32);
      qf1[ks] = *reinterpret_cast<const bf16x8*>(q1 + ks * 32);
    }
  }

  const int kRL = lane >> 4;        // row-in-group 0..3 (K)
  const int kCH = lane & 15;        // 16B chunk 0..15  (K)
  const int vDL = lane >> 3;        // row-in-group 0..7 (V)
  const int vCH = lane & 7;         // 16B chunk 0..7   (V)

  floatx4 O0[8] = {}, O1[8] = {};
  float m0_i = -3e38f, l0_i = 0.f;  // set 0, qrow = l16
  float m1_i = -3e38f, l1_i = 0.f;  // set 1, qrow = l16

  // Prologue: stage chunk 0 into buffer 0.
  {
#pragma unroll
    for (int j = 0; j < 4; ++j) {
      const int row = wv * 16 + j * 4 + kRL;     // 0..63
      gl2lds16(rpk + (size_t)row * 512 + h * 128 + ((kCH ^ (row & 7)) << 3),
               &BsK[0][(wv * 16 + j * 4) * 128]);
      const int d = wv * 32 + j * 8 + vDL;       // 0..127
      gl2lds16(rvT + (size_t)(h * 128 + d) * 512 + ((vCH ^ (d & 7)) << 3),
               &BsV[0][(wv * 32 + j * 8) * 64]);
    }
  }
  __syncthreads();   // implicit vmcnt(0): chunk 0 landed

  const int kswz = l16 & 7;

  for (int c = 0; c < 8; ++c) {
    const int cur = c & 1;

    if (c < 7) {
      const int nb = cur ^ 1;
      const int cn = c + 1;
#pragma unroll
      for (int j = 0; j < 4; ++j) {
        const int row = wv * 16 + j * 4 + kRL;
        gl2lds16(rpk + (size_t)(cn * 64 + row) * 512 + h * 128 +
                     ((kCH ^ (row & 7)) << 3),
                 &BsK[nb][(wv * 16 + j * 4) * 128]);
        const int d = wv * 32 + j * 8 + vDL;
        gl2lds16(rvT + (size_t)(h * 128 + d) * 512 + cn * 64 +
                     ((vCH ^ (d & 7)) << 3),
                 &BsV[nb][(wv * 32 + j * 8) * 64]);
      }
    }

    // ================= two sequential 64-row sets =================
#pragma unroll
    for (int s = 0; s < 2; ++s) {
      const bf16x8* qf = (s == 0) ? qf0 : qf1;
      floatx4* O      = (s == 0) ? O0 : O1;
      float& m_i      = (s == 0) ? m0_i : m1_i;
      float& l_i      = (s == 0) ? l0_i : l1_i;

      // ---- swapped QK^T: S[nt][r] = score[rep=nt*16+quad*4+r][qrow=l16] ----
      floatx4 S[4] = {};
#pragma unroll
      for (int ks = 0; ks < 4; ++ks) {
        const int ac = ks * 4 + quad;
#pragma unroll
        for (int nt = 0; nt < 4; ++nt) {
          bf16x8 b = *reinterpret_cast<const bf16x8*>(
              &BsK[cur][(nt * 16 + l16) * 128 + ((ac ^ kswz) << 3)]);
          S[nt] = __builtin_amdgcn_mfma_f32_16x16x32_bf16(b, qf[ks], S[nt], 0, 0, 0);
        }
      }

      // ---- softmax over lane-local reps (exp2 domain, defer-max) ----
      float cm;
      {
        const float a0 = fmaxf(fmaxf(S[0][0], S[0][1]), fmaxf(S[0][2], S[0][3]));
        const float a1 = fmaxf(fmaxf(S[1][0], S[1][1]), fmaxf(S[1][2], S[1][3]));
        const float a2 = fmaxf(fmaxf(S[2][0], S[2][1]), fmaxf(S[2][2], S[2][3]));
        const float a3 = fmaxf(fmaxf(S[3][0], S[3][1]), fmaxf(S[3][2], S[3][3]));
        cm = fmaxf(fmaxf(a0, a1), fmaxf(a2, a3));
        cm = fmaxf(cm, __shfl_xor(cm, 16));
        cm = fmaxf(cm, __shfl_xor(cm, 32));   // chunk max for qrow l16
      }
      if (!__all(cm <= m_i + DEFER_THR)) {
        const float mn = fmaxf(m_i, cm);
        const float sc = exp2f((m_i - mn) * C2EXP);
        m_i = mn;
        l_i *= sc;
        float scR[4];
#pragma unroll
        for (int r = 0; r < 4; ++r) scR[r] = __shfl(sc, quad * 4 + r);
#pragma unroll
        for (int nt = 0; nt < 8; ++nt)
#pragma unroll
          for (int r = 0; r < 4; ++r) O[nt][r] *= scR[r];
      }
      {
        const float mC = m_i * C2EXP;
        float ps = 0.f;
#pragma unroll
        for (int nt = 0; nt < 4; ++nt) {
          const float p0 = exp2f(S[nt][0] * C2EXP - mC);
          const float p1 = exp2f(S[nt][1] * C2EXP - mC);
          const float p2 = exp2f(S[nt][2] * C2EXP - mC);
          const float p3 = exp2f(S[nt][3] * C2EXP - mC);
          ps += (p0 + p1) + (p2 + p3);
          uint2 pk2 = make_uint2(cvtpk(p0, p1), cvtpk(p2, p3));
          *reinterpret_cast<uint2*>(&Ps[wv][l16 * 72 + nt * 16 + quad * 4]) = pk2;
        }
        ps += __shfl_xor(ps, 16);
        ps += __shfl_xor(ps, 32);             // chunk sum for qrow l16
        l_i += ps;
      }
      // Ps write->read within-wave (lgkmcnt-ordered); set1's writes are
      // WAR-ordered after set0's PV reads (in-order LDS per wave).

      // ---- PV ----
#pragma unroll
      for (int ks = 0; ks < 2; ++ks) {
        bf16x8 a = *reinterpret_cast<const bf16x8*>(&Ps[wv][l16 * 72 + ks * 32 + quad * 8]);
#pragma unroll
        for (int nt = 0; nt < 8; ++nt) {
          const int q8 = ks * 4 + quad;
          bf16x8 b = *reinterpret_cast<const bf16x8*>(
              &BsV[cur][(nt * 16 + l16) * 64 + ((q8 ^ kswz) << 3)]);
          O[nt] = __builtin_amdgcn_mfma_f32_16x16x32_bf16(a, b, O[nt], 0, 0, 0);
        }
      }
    }

    __syncthreads();   // drains next-chunk loads; all waves done with 'cur'
  }

  // Final normalize + store, per set.
#pragma unroll
  for (int s = 0; s < 2; ++s) {
    const floatx4* O = (s == 0) ? O0 : O1;
    const float l_i  = (s == 0) ? l0_i : l1_i;
    float invR[4];
#pragma unroll
    for (int r = 0; r < 4; ++r) invR[r] = 1.0f / __shfl(l_i, quad * 4 + r);
#pragma unroll
    for (int r = 0; r < 4; ++r) {
      const int n = n0 + s * 64 + wv * 16 + quad * 4 + r;
#pragma unroll
      for (int nt = 0; nt < 8; ++nt)
        glb[(size_t)n * 512 + h * 128 + nt * 16 + l16] = f2bf(O[nt][r] * invR[r]);
    }
  }
}

// ---------------------------------------------------------------------------
// K6: combine -> f32 output.
// ---------------------------------------------------------------------------
__global__ __launch_bounds__(256) void k_combine(
    const ushort_t* __restrict__ locS, const ushort_t* __restrict__ glb,
    const ushort_t* __restrict__ Vb, const float* __restrict__ scal,
    float* __restrict__ out)
{
  const int t = blockIdx.x * 256 + threadIdx.x;
  const int n = t >> 6, dp = t & 63;
  const float alpha = 1.0f / (1.0f + __expf(-scal[0]));
  const float beta = scal[1];
  const uint32 lv = reinterpret_cast<const uint32*>(locS)[(size_t)n * 64 + dp];
  float g0 = 0.f, g1 = 0.f, v0 = 0.f, v1 = 0.f;
#pragma unroll
  for (int hh = 0; hh < 4; ++hh) {
    const uint32 gv = *reinterpret_cast<const uint32*>(glb + (size_t)n * 512 + hh * 128 + 2 * dp);
    const uint32 vv = *reinterpret_cast<const uint32*>(Vb + (size_t)n * 512 + hh * 128 + 2 * dp);
    g0 += bflo(gv); g1 += bfhi(gv);
    v0 += bflo(vv); v1 += bfhi(vv);
  }
  const float r0 = alpha * bflo(lv) + (1.0f - alpha) * g0 * 0.25f + beta * v0 * 0.25f;
  const float r1 = alpha * bfhi(lv) + (1.0f - alpha) * g1 * 0.25f + beta * v1 * 0.25f;
  reinterpret_cast<float2*>(out)[(size_t)n * 64 + dp] = make_float2(r0, r1);
}

extern "C" void kernel_launch(void* const* d_in, const int* in_sizes, int n_in,
                              void* d_out, int out_size, void* d_ws, size_t ws_size,
                              hipStream_t stream) {
  const void* x     = d_in[0];
  const int*  pidx  = (const int*)d_in[1];
  const void* Wq    = d_in[2];
  const void* bq    = d_in[3];
  const void* Wk    = d_in[4];
  const void* bk    = d_in[5];
  const void* Wv    = d_in[6];
  const void* bv    = d_in[7];
  const void* seeds = d_in[8];
  const void* al    = d_in[9];
  const void* be    = d_in[10];

  char* ws = (char*)d_ws;
  ushort_t* Qb   = (ushort_t*)(ws + OFF_Q);
  ushort_t* Kb   = (ushort_t*)(ws + OFF_K);
  ushort_t* Vb   = (ushort_t*)(ws + OFF_V);
  ushort_t* locS = (ushort_t*)(ws + OFF_LOC);
  ushort_t* rpk  = (ushort_t*)(ws + OFF_RPK);
  ushort_t* xc   = (ushort_t*)(ws + OFF_XC);
  ushort_t* wc   = (ushort_t*)(ws + OFF_WC);
  float*    scal = (float*)   (ws + OFF_SCAL);
  uint32*   flags= (uint32*)  (ws + OFF_FLAG);
  ushort_t* rvT  = (ushort_t*)(ws + OFF_RVT);
  ushort_t* glb  = (ushort_t*)(ws + OFF_GLB);

  k_detect<<<1, 64, 0, stream>>>((const uint32*)x, (const ushort_t*)be, flags);
  k_convert<<<dim3(4096, 2), 256, 0, stream>>>(x, Wq, bq, Wk, bk, Wv, bv, seeds, al, be,
                                               xc, wc, scal, flags);
  k_qkv<<<512, 256, 0, stream>>>(xc, wc, Qb, Kb, Vb);
  k_pool<<<dim3(128, 4), 256, 0, stream>>>(Kb, Vb, pidx, wc, rpk, rvT);
  k_fine<<<dim3(128, 4), 256, 0, stream>>>(Qb, Kb, Vb, pidx, locS);
  k_cross<<<dim3(256, 4), 256, 0, stream>>>(Qb, rpk, rvT, glb);
  k_combine<<<8192, 256, 0, stream>>>(locS, glb, Vb, scal, (float*)d_out);
}

// Round 8
// 315.479 us; speedup vs baseline: 1.6670x; 1.0149x over previous
//
#include <hip/hip_runtime.h>
#include <hip/hip_bf16.h>

// PCGTConvLayer round 17: k_cross inner loops restructured to SHARE each
// staged B-fragment across both 64-row Q-sets (b loaded once -> 2 MFMAs).
// QK and PV LDS reads halve (the kernel was ~44% of LDS BW + 27% conflict
// overhead). Two Ps buffers enable shared PV; BsV goes single-buffered
// (staged post-PV, drained by next chunk's pre-PV barrier) to keep LDS at
// 66 KiB -> 2 blocks/CU. All other kernels verbatim from round 16 (320.2us).
// N=32768 IN=256 D=128 H=4 M=4 KP=128 S=256, SCALE=sqrt(128).

#define INV_SCALE 0.08838834764831845f
// INV_SCALE * log2(e)
#define C2EXP 0.12751744f
// 8 / INV_SCALE  (defer-max threshold in unscaled-score domain)
#define DEFER_THR 90.50966799f

typedef __attribute__((ext_vector_type(8))) short bf16x8;
typedef __attribute__((ext_vector_type(4))) float floatx4;
typedef unsigned short ushort_t;
typedef unsigned int uint32;

// ---- ws layout (bytes) ----
#define OFF_Q    0ull            // bf16 [32768][512]
#define OFF_K    33554432ull     // bf16 [32768][512]
#define OFF_V    67108864ull     // bf16 [32768][512]
#define OFF_LOC  100663296ull    // bf16 [32768][128]
#define OFF_RPK  109051904ull    // bf16 [512][4][128]
#define OFF_XC   110100480ull    // bf16 [32768][256]
#define OFF_WC   126877696ull    // bf16: WqT,WkT,WvT ([512][256] each), biases, seeds
#define OFF_SCAL 127671296ull    // f32 [2]
#define OFF_FLAG 127671304ull    // u32 [2]
#define OFF_RVT  127672320ull    // bf16 [4][128][512]
#define OFF_GLB  128196608ull    // bf16 [32768][512]

#define WC_WQ 0
#define WC_WK 131072
#define WC_WV 262144
#define WC_BQ 393216
#define WC_BK 393728
#define WC_BV 394240
#define WC_SEED 394752
#define WC_TOT 396800

static __device__ __forceinline__ float bflo(uint32 u) {
  return __uint_as_float(u << 16);
}
static __device__ __forceinline__ float bfhi(uint32 u) {
  return __uint_as_float(u & 0xffff0000u);
}
static __device__ __forceinline__ float bf2f(ushort_t u) {
  return __uint_as_float(((uint32)u) << 16);
}
static __device__ __forceinline__ ushort_t f2bf(float f) {
  uint32 x = __float_as_uint(f);
  uint32 r = x + 0x7fffu + ((x >> 16) & 1u);
  return (ushort_t)(r >> 16);
}
static __device__ __forceinline__ uint32 pack2bf(float a, float b) {
  return (uint32)f2bf(a) | ((uint32)f2bf(b) << 16);
}
// HW packed f32->bf16 (RNE; lo16 = a, hi16 = b). Same rounding as f2bf.
static __device__ __forceinline__ uint32 cvtpk(float a, float b) {
  uint32 r;
  asm("v_cvt_pk_bf16_f32 %0, %1, %2" : "=v"(r) : "v"(a), "v"(b));
  return r;
}

// async global -> LDS, 16 bytes per lane. LDS dest must be wave-uniform base;
// lane i lands at base + i*16 B. Global source is per-lane.
static __device__ __forceinline__ void gl2lds16(const ushort_t* g, ushort_t* l) {
  __builtin_amdgcn_global_load_lds(
      (const __attribute__((address_space(1))) void*)g,
      (__attribute__((address_space(3))) void*)l, 16, 0, 0);
}

// ---------------------------------------------------------------------------
__global__ __launch_bounds__(64) void k_detect(const uint32* __restrict__ xw,
                                               const ushort_t* __restrict__ betaRaw,
                                               uint32* __restrict__ flags) {
  const int lane = threadIdx.x;
  const uint32 w = xw[lane * 137 + 3];
  const int e = (w >> 7) & 0xff;
  const unsigned long long b = __ballot(e >= 100 && e <= 140);
  if (lane == 0) {
    flags[0] = (__popcll(b) >= 48) ? 1u : 0u;
    flags[1] = (betaRaw[0] != 0) ? 1u : 0u;
  }
}

// ---------------------------------------------------------------------------
// K1: canonicalize. x -> xc (identity layout). W matrices -> TRANSPOSED
// bf16 [512][256] at same wc offsets. biases/seeds identity.
// ---------------------------------------------------------------------------
static __device__ __forceinline__ void conv8(const void* src, long j, int isB,
                                             ushort_t* dst) {
  if (isB) {
    *reinterpret_cast<uint4*>(dst) =
        *reinterpret_cast<const uint4*>(reinterpret_cast<const ushort_t*>(src) + j);
  } else {
    const float* f = reinterpret_cast<const float*>(src) + j;
    const float4 a = *reinterpret_cast<const float4*>(f);
    const float4 b = *reinterpret_cast<const float4*>(f + 4);
    uint4 o;
    o.x = pack2bf(a.x, a.y); o.y = pack2bf(a.z, a.w);
    o.z = pack2bf(b.x, b.y); o.w = pack2bf(b.z, b.w);
    *reinterpret_cast<uint4*>(dst) = o;
  }
}

__global__ __launch_bounds__(256) void k_convert(
    const void* __restrict__ x,
    const void* __restrict__ Wq, const void* __restrict__ bq,
    const void* __restrict__ Wk, const void* __restrict__ bk,
    const void* __restrict__ Wv, const void* __restrict__ bv,
    const void* __restrict__ seeds, const void* __restrict__ alpha,
    const void* __restrict__ beta,
    ushort_t* __restrict__ xc, ushort_t* __restrict__ wc,
    float* __restrict__ scal, const uint32* __restrict__ flags)
{
  const int isB = (int)flags[0];
  const long i8 = ((long)blockIdx.x * 256 + threadIdx.x) * 8;
  if (blockIdx.y == 0) {
    conv8(x, i8, isB, xc + i8);
  } else {
    if (i8 < WC_BQ) {
      // W region: transpose. i8 = sel*131072 + k*512 + n (8 consecutive n).
      const int sel = (int)(i8 >> 17);
      const long local = i8 & 131071;
      const int kk = (int)(local >> 9);
      const int nn = (int)(local & 511);
      const void* src = sel == 0 ? Wq : (sel == 1 ? Wk : Wv);
      ushort_t* dstW = wc + sel * 131072;
#pragma unroll
      for (int j = 0; j < 8; ++j) {
        ushort_t v;
        if (isB) v = reinterpret_cast<const ushort_t*>(src)[local + j];
        else     v = f2bf(reinterpret_cast<const float*>(src)[local + j]);
        dstW[(size_t)(nn + j) * 256 + kk] = v;
      }
    } else if (i8 < WC_TOT) {
      const void* src; long j;
      if (i8 < WC_BK)        { src = bq;    j = i8 - WC_BQ; }
      else if (i8 < WC_BV)   { src = bk;    j = i8 - WC_BK; }
      else if (i8 < WC_SEED) { src = bv;    j = i8 - WC_BV; }
      else                   { src = seeds; j = i8 - WC_SEED; }
      conv8(src, j, isB, wc + i8);
    }
    if (blockIdx.x == 0 && threadIdx.x == 0) {
      const int isBS = (int)flags[1];
      scal[0] = isBS ? bf2f(reinterpret_cast<const ushort_t*>(alpha)[0])
                     : reinterpret_cast<const float*>(alpha)[0];
      scal[1] = isBS ? bf2f(reinterpret_cast<const ushort_t*>(beta)[0])
                     : reinterpret_cast<const float*>(beta)[0];
    }
  }
}

// ---------------------------------------------------------------------------
// K2: fused QKV GEMM. One block = 64 rows of x; loops sel(3) x 8 col-chunks.
// Xs staged ONCE (XOR-swizzled: chunk c of row at ((c^(row&7))<<3)); Ws from
// W^T with identical swizzle via coalesced uint4. MFMA 16x16x32, wave =
// 16 rows x 64 cols per chunk. LDS exactly 64 KiB.
// ---------------------------------------------------------------------------
__global__ __launch_bounds__(256) void k_qkv(
    const ushort_t* __restrict__ xc, const ushort_t* __restrict__ wc,
    ushort_t* __restrict__ Qb, ushort_t* __restrict__ Kb, ushort_t* __restrict__ Vb)
{
  const int m0 = blockIdx.x * 64;
  const int tid = threadIdx.x, lane = tid & 63, wv = tid >> 6;
  const int l16 = lane & 15, quad = lane >> 4;

  __shared__ __align__(16) ushort_t Xs[64 * 256];   // 32 KiB
  __shared__ __align__(16) ushort_t Ws[64 * 256];   // 32 KiB

#pragma unroll
  for (int i = 0; i < 8; ++i) {
    const int id = tid + 256 * i;          // 2048 chunks of 8
    const int row = id >> 5, c = id & 31;
    uint4 v = *reinterpret_cast<const uint4*>(xc + (size_t)(m0 + row) * 256 + c * 8);
    *reinterpret_cast<uint4*>(&Xs[row * 256 + ((c ^ (row & 7)) << 3)]) = v;
  }

  for (int sel = 0; sel < 3; ++sel) {
    const ushort_t* WT   = wc + sel * 131072;
    const ushort_t* bias = wc + WC_BQ + sel * 512;
    ushort_t* out        = sel == 0 ? Qb : (sel == 1 ? Kb : Vb);
    for (int nc = 0; nc < 8; ++nc) {
      const int n0 = nc * 64;
      __syncthreads();   // prev chunk's Ws readers done (also orders Xs staging)
#pragma unroll
      for (int i = 0; i < 8; ++i) {
        const int id = tid + 256 * i;
        const int row = id >> 5, c = id & 31;
        uint4 v = *reinterpret_cast<const uint4*>(WT + (size_t)(n0 + row) * 256 + c * 8);
        *reinterpret_cast<uint4*>(&Ws[row * 256 + ((c ^ (row & 7)) << 3)]) = v;
      }
      __syncthreads();

      floatx4 acc[4] = {};
      const int arow = wv * 16 + l16;
#pragma unroll
      for (int ks = 0; ks < 8; ++ks) {
        const int ac = ks * 4 + quad;
        bf16x8 a = *reinterpret_cast<const bf16x8*>(&Xs[arow * 256 + ((ac ^ (arow & 7)) << 3)]);
#pragma unroll
        for (int nt = 0; nt < 4; ++nt) {
          const int brow = nt * 16 + l16;
          bf16x8 b = *reinterpret_cast<const bf16x8*>(&Ws[brow * 256 + ((ac ^ (brow & 7)) << 3)]);
          acc[nt] = __builtin_amdgcn_mfma_f32_16x16x32_bf16(a, b, acc[nt], 0, 0, 0);
        }
      }

#pragma unroll
      for (int nt = 0; nt < 4; ++nt) {
        const int col = n0 + nt * 16 + l16;
        const float bf = bf2f(bias[col]);
#pragma unroll
        for (int r = 0; r < 4; ++r) {
          const int row = m0 + wv * 16 + quad * 4 + r;
          out[(size_t)row * 512 + col] = f2bf(acc[nt][r] + bf);
        }
      }
    }
  }
}

// ---------------------------------------------------------------------------
// K3: pooling (seeds -> rpk, rvT). Verified (CHK3).
// ---------------------------------------------------------------------------
__global__ __launch_bounds__(256) void k_pool(
    const ushort_t* __restrict__ Kb, const ushort_t* __restrict__ Vb,
    const int* __restrict__ pidx_all, const ushort_t* __restrict__ wc,
    ushort_t* __restrict__ rpk, ushort_t* __restrict__ rvT)
{
  const int k = blockIdx.x, h = blockIdx.y;
  const int tid = threadIdx.x, lane = tid & 63, wv = tid >> 6;
  const int* pidx = pidx_all + k * 256;

  __shared__ __align__(16) ushort_t SB[128 * 256];
  const uint32* SBU = reinterpret_cast<const uint32*>(SB);

#pragma unroll
  for (int i = 0; i < 16; ++i) {
    const int e8 = tid + 256 * i;
    const int q = e8 >> 4, dc = (e8 & 15) * 8;
    uint4 kv = *reinterpret_cast<const uint4*>(Kb + (size_t)pidx[q] * 512 + h * 128 + dc);
    const ushort_t* ku = reinterpret_cast<const ushort_t*>(&kv);
    const int qp = q >> 1, qb = q & 1;
#pragma unroll
    for (int j = 0; j < 8; ++j) {
      const int d = dc + j;
      SB[d * 256 + (((qp ^ (d & 31)) << 1) | qb)] = ku[j];
    }
  }
  __syncthreads();

  float q00, q01, q10, q11;
  {
    const uint32* ssrc = reinterpret_cast<const uint32*>(wc + WC_SEED + (size_t)(wv * 4 + h) * 128);
    float s00 = 0.f, s01 = 0.f, s10 = 0.f, s11 = 0.f;
#pragma unroll 8
    for (int dc = 0; dc < 64; ++dc) {
      const uint32 qv = ssrc[dc];
      const float a0 = bflo(qv), a1 = bfhi(qv);
      const int d0 = dc * 2, d1 = d0 + 1;
      const int c0 = lane ^ (d0 & 31);
      const int c1 = lane ^ (d1 & 31);
      const uint32 u00 = SBU[d0 * 128 + c0];
      const uint32 u01 = SBU[d0 * 128 + c0 + 64];
      const uint32 u10 = SBU[d1 * 128 + c1];
      const uint32 u11 = SBU[d1 * 128 + c1 + 64];
      s00 += a0 * bflo(u00) + a1 * bflo(u10);
      s01 += a0 * bfhi(u00) + a1 * bfhi(u10);
      s10 += a0 * bflo(u01) + a1 * bflo(u11);
      s11 += a0 * bfhi(u01) + a1 * bfhi(u11);
    }
    s00 *= INV_SCALE; s01 *= INV_SCALE; s10 *= INV_SCALE; s11 *= INV_SCALE;
    float mx = fmaxf(fmaxf(s00, s01), fmaxf(s10, s11));
#pragma unroll
    for (int off = 32; off >= 1; off >>= 1) mx = fmaxf(mx, __shfl_xor(mx, off));
    const float e00 = __expf(s00 - mx), e01 = __expf(s01 - mx);
    const float e10 = __expf(s10 - mx), e11 = __expf(s11 - mx);
    float sm = e00 + e01 + e10 + e11;
#pragma unroll
    for (int off = 32; off >= 1; off >>= 1) sm += __shfl_xor(sm, off);
    const float inv = 1.0f / sm;
    q00 = e00 * inv; q01 = e01 * inv; q10 = e10 * inv; q11 = e11 * inv;
  }

  {
    float rk0 = 0.f, rk1 = 0.f;
    const int d0 = 2 * lane, d1 = 2 * lane + 1;
#pragma unroll 4
    for (int qp = 0; qp < 64; ++qp) {
      const float pa = __shfl(q00, qp), pb = __shfl(q01, qp);
      const float pc = __shfl(q10, qp), pd = __shfl(q11, qp);
      const int c0 = qp ^ (d0 & 31);
      const int c1 = qp ^ (d1 & 31);
      const uint32 u0  = SBU[d0 * 128 + c0];
      const uint32 u0b = SBU[d0 * 128 + c0 + 64];
      const uint32 u1  = SBU[d1 * 128 + c1];
      const uint32 u1b = SBU[d1 * 128 + c1 + 64];
      rk0 += pa * bflo(u0) + pb * bfhi(u0) + pc * bflo(u0b) + pd * bfhi(u0b);
      rk1 += pa * bflo(u1) + pb * bfhi(u1) + pc * bflo(u1b) + pd * bfhi(u1b);
    }
    reinterpret_cast<uint32*>(rpk + ((size_t)((k * 4 + wv) * 4 + h)) * 128)[lane] = pack2bf(rk0, rk1);
  }
  __syncthreads();

#pragma unroll
  for (int i = 0; i < 16; ++i) {
    const int e8 = tid + 256 * i;
    const int q = e8 >> 4, dc = (e8 & 15) * 8;
    uint4 vv = *reinterpret_cast<const uint4*>(Vb + (size_t)pidx[q] * 512 + h * 128 + dc);
    *reinterpret_cast<uint4*>(&SB[q * 128 + dc]) = vv;
  }
  __syncthreads();

  {
    float rv0 = 0.f, rv1 = 0.f;
#pragma unroll 4
    for (int qp = 0; qp < 64; ++qp) {
      const float pa = __shfl(q00, qp), pb = __shfl(q01, qp);
      const float pc = __shfl(q10, qp), pd = __shfl(q11, qp);
      const uint32 v00 = SBU[(2 * qp) * 64 + lane];
      const uint32 v01 = SBU[(2 * qp + 1) * 64 + lane];
      const uint32 v10 = SBU[(128 + 2 * qp) * 64 + lane];
      const uint32 v11 = SBU[(129 + 2 * qp) * 64 + lane];
      rv0 += pa * bflo(v00) + pb * bflo(v01) + pc * bflo(v10) + pd * bflo(v11);
      rv1 += pa * bfhi(v00) + pb * bfhi(v01) + pc * bfhi(v10) + pd * bfhi(v11);
    }
    const int rrep = k * 4 + wv;
    rvT[(size_t)(h * 128 + 2 * lane) * 512 + rrep]     = f2bf(rv0);
    rvT[(size_t)(h * 128 + 2 * lane + 1) * 512 + rrep] = f2bf(rv1);
  }
}

// ---------------------------------------------------------------------------
// K4: MFMA fine attention (verified round 15).
// ---------------------------------------------------------------------------
__global__ __launch_bounds__(256) void k_fine(
    const ushort_t* __restrict__ Qb, const ushort_t* __restrict__ Kb,
    const ushort_t* __restrict__ Vb, const int* __restrict__ pidx_all,
    ushort_t* __restrict__ locS)
{
  const int k = blockIdx.x, qg = blockIdx.y;
  const int tid = threadIdx.x, lane = tid & 63, wv = tid >> 6;
  const int l16 = lane & 15, quad = lane >> 4;
  const int* pidx = pidx_all + k * 256;

  __shared__ __align__(16) ushort_t BsK[2][64 * 128];  // 2 x 16 KiB
  __shared__ __align__(16) ushort_t SBV[128 * 64];     // 16 KiB (V^T scatter)
  __shared__ __align__(16) ushort_t Ps[4][16 * 72];    // 9 KiB wave-private

  // This lane's q-row global index (q-row = l16 within the wave's 16 rows).
  const int qidx = pidx[qg * 64 + wv * 16 + l16];

  // K staging lane coordinates (round-13 pattern).
  const int kRL = lane >> 4;        // row-in-group 0..3
  const int kCH = lane & 15;        // 16B chunk 0..15
  const int kswz = l16 & 7;

  float accS[8][4];
#pragma unroll
  for (int nt = 0; nt < 8; ++nt)
#pragma unroll
    for (int r = 0; r < 4; ++r) accS[nt][r] = 0.f;

  // Prologue: stage K tile (h=0,c=0) into BsK[0].
#pragma unroll
  for (int j = 0; j < 4; ++j) {
    const int row = wv * 16 + j * 4 + kRL;   // 0..63
    gl2lds16(Kb + (size_t)pidx[row] * 512 + ((kCH ^ (row & 7)) << 3),
             &BsK[0][(wv * 16 + j * 4) * 128]);
  }
  __syncthreads();   // implicit vmcnt(0): tile 0 landed

  bf16x8 qf[4];
  floatx4 O[8];
  float m_i = -3e38f, l_i = 0.f;

  for (int idx = 0; idx < 16; ++idx) {
    const int h = idx >> 2, c = idx & 3;
    const int cur = idx & 1;

    if (c == 0) {
      // New head: load Q fragments, reset online-softmax state.
      const ushort_t* qrow = Qb + (size_t)qidx * 512 + h * 128 + quad * 8;
#pragma unroll
      for (int ks = 0; ks < 4; ++ks)
        qf[ks] = *reinterpret_cast<const bf16x8*>(qrow + ks * 32);
#pragma unroll
      for (int nt = 0; nt < 8; ++nt) O[nt] = (floatx4){0.f, 0.f, 0.f, 0.f};
      m_i = -3e38f;
      l_i = 0.f;
    }

    // Prefetch next (h,c) K tile into the other buffer (drained by the
    // end-of-iteration barrier's implicit vmcnt(0)).
    if (idx < 15) {
      const int hn = (idx + 1) >> 2, cn = (idx + 1) & 3;
      const int nb = cur ^ 1;
#pragma unroll
      for (int j = 0; j < 4; ++j) {
        const int row = wv * 16 + j * 4 + kRL;
        gl2lds16(Kb + (size_t)pidx[cn * 64 + row] * 512 + hn * 128 +
                     ((kCH ^ (row & 7)) << 3),
                 &BsK[nb][(wv * 16 + j * 4) * 128]);
      }
    }

    // ---- swapped QK^T: S[nt][r] = score[key = nt*16+quad*4+r][qrow = l16] ----
    floatx4 S[4] = {};
#pragma unroll
    for (int ks = 0; ks < 4; ++ks) {
      const int ac = ks * 4 + quad;
#pragma unroll
      for (int nt = 0; nt < 4; ++nt) {
        bf16x8 b = *reinterpret_cast<const bf16x8*>(
            &BsK[cur][(nt * 16 + l16) * 128 + ((ac ^ kswz) << 3)]);
        S[nt] = __builtin_amdgcn_mfma_f32_16x16x32_bf16(b, qf[ks], S[nt], 0, 0, 0);
      }
    }

    // ---- lane-local softmax (exp2 domain, defer-max) ----
    float cm;
    {
      const float m0 = fmaxf(fmaxf(S[0][0], S[0][1]), fmaxf(S[0][2], S[0][3]));
      const float m1 = fmaxf(fmaxf(S[1][0], S[1][1]), fmaxf(S[1][2], S[1][3]));
      const float m2 = fmaxf(fmaxf(S[2][0], S[2][1]), fmaxf(S[2][2], S[2][3]));
      const float m3 = fmaxf(fmaxf(S[3][0], S[3][1]), fmaxf(S[3][2], S[3][3]));
      cm = fmaxf(fmaxf(m0, m1), fmaxf(m2, m3));
      cm = fmaxf(cm, __shfl_xor(cm, 16));
      cm = fmaxf(cm, __shfl_xor(cm, 32));   // chunk max for qrow l16
    }
    if (!__all(cm <= m_i + DEFER_THR)) {
      const float mn = fmaxf(m_i, cm);
      const float sc = exp2f((m_i - mn) * C2EXP);
      m_i = mn;
      l_i *= sc;
      float scR[4];
#pragma unroll
      for (int r = 0; r < 4; ++r) scR[r] = __shfl(sc, quad * 4 + r);
#pragma unroll
      for (int nt = 0; nt < 8; ++nt)
#pragma unroll
        for (int r = 0; r < 4; ++r) O[nt][r] *= scR[r];
    }
    {
      const float mC = m_i * C2EXP;
      float ps = 0.f;
#pragma unroll
      for (int nt = 0; nt < 4; ++nt) {
        const float p0 = exp2f(S[nt][0] * C2EXP - mC);
        const float p1 = exp2f(S[nt][1] * C2EXP - mC);
        const float p2 = exp2f(S[nt][2] * C2EXP - mC);
        const float p3 = exp2f(S[nt][3] * C2EXP - mC);
        ps += (p0 + p1) + (p2 + p3);
        uint2 pk2 = make_uint2(pack2bf(p0, p1), pack2bf(p2, p3));
        *reinterpret_cast<uint2*>(&Ps[wv][l16 * 72 + nt * 16 + quad * 4]) = pk2;
      }
      ps += __shfl_xor(ps, 16);
      ps += __shfl_xor(ps, 32);
      l_i += ps;
    }
    // Ps write->read is within-wave (lgkmcnt-ordered).

    __syncthreads();   // prev unit's PV readers of SBV done
    // ---- V stage: scalar-scatter transpose (round-8 verbatim, -> SBV) ----
#pragma unroll
    for (int i = 0; i < 4; ++i) {
      const int e = tid + 256 * i;
      const int key = e & 63, dc8 = (e >> 6) * 8;
      uint4 vv = *reinterpret_cast<const uint4*>(
          Vb + (size_t)pidx[c * 64 + key] * 512 + h * 128 + dc8);
      const ushort_t* u = reinterpret_cast<const ushort_t*>(&vv);
#pragma unroll
      for (int j = 0; j < 8; ++j) {
        const int d = dc8 + j;
        SBV[d * 64 + (((key >> 3) ^ j) << 3) + (key & 7)] = u[j];
      }
    }
    __syncthreads();   // V staged

    // ---- PV ----
#pragma unroll
    for (int ks = 0; ks < 2; ++ks) {
      bf16x8 a = *reinterpret_cast<const bf16x8*>(&Ps[wv][l16 * 72 + ks * 32 + quad * 8]);
#pragma unroll
      for (int nt = 0; nt < 8; ++nt) {
        const int d = nt * 16 + l16;
        const int q8 = ks * 4 + quad;
        bf16x8 b = *reinterpret_cast<const bf16x8*>(
            &SBV[d * 64 + ((q8 ^ (d & 7)) << 3)]);
        O[nt] = __builtin_amdgcn_mfma_f32_16x16x32_bf16(a, b, O[nt], 0, 0, 0);
      }
    }

    if (c == 3) {
      // End of head h: fold normalized O into accS.
      float invR[4];
#pragma unroll
      for (int r = 0; r < 4; ++r) invR[r] = 1.0f / __shfl(l_i, quad * 4 + r);
#pragma unroll
      for (int nt = 0; nt < 8; ++nt)
#pragma unroll
        for (int r = 0; r < 4; ++r) accS[nt][r] += O[nt][r] * invR[r];
    }

    __syncthreads();   // drains next-tile gl2lds; all waves done with cur/SBV
  }

#pragma unroll
  for (int r = 0; r < 4; ++r) {
    const int n = pidx[qg * 64 + wv * 16 + quad * 4 + r];
#pragma unroll
    for (int nt = 0; nt < 8; ++nt)
      locS[(size_t)n * 128 + nt * 16 + l16] = f2bf(accS[nt][r] * 0.25f);
  }
}

// ---------------------------------------------------------------------------
// K5: MFMA cross-attention, round 17.
// 128 Q-rows/block; each staged B-fragment loaded ONCE and fed to BOTH
// sets' MFMAs (QK and PV LDS reads halve). Two Ps buffers (one per set)
// enable the shared PV; BsV single-buffered: staged after the post-PV
// barrier, drained by the next chunk's pre-PV barrier (QK+softmax cover
// the L2 latency). LDS: 32K (K dbuf) + 16K (V) + 18K (Ps x2) = 66 KiB.
// ---------------------------------------------------------------------------
__global__ __launch_bounds__(256, 2) void k_cross(
    const ushort_t* __restrict__ Qb, const ushort_t* __restrict__ rpk,
    const ushort_t* __restrict__ rvT, ushort_t* __restrict__ glb)
{
  const int h = blockIdx.y;
  const int n0 = blockIdx.x * 128;
  const int tid = threadIdx.x, lane = tid & 63, wv = tid >> 6;
  const int l16 = lane & 15, quad = lane >> 4;

  __shared__ __align__(16) ushort_t BsK[2][64 * 128];   // 2 x 16 KiB
  __shared__ __align__(16) ushort_t BsV[128 * 64];      // 16 KiB (single)
  __shared__ __align__(16) ushort_t Ps[2][4][16 * 72];  // 18 KiB (per set)

  // Q fragments for both 64-row sets (set s: rows n0 + s*64 + wv*16 + l16).
  bf16x8 qf0[4], qf1[4];
  {
    const ushort_t* q0 =
        Qb + (size_t)(n0 + wv * 16 + l16) * 512 + h * 128 + quad * 8;
    const ushort_t* q1 = q0 + (size_t)64 * 512;
#pragma unroll
    for (int ks = 0; ks < 4; ++ks) {
      qf0[ks] = *reinterpret_cast<const bf16x8*>(q0 + ks * 32);
      qf1[ks] = *reinterpret_cast<const bf16x8*>(q1 + ks * 32);
    }
  }

  const int kRL = lane >> 4;        // row-in-group 0..3 (K)
  const int kCH = lane & 15;        // 16B chunk 0..15  (K)
  const int vDL = lane >> 3;        // row-in-group 0..7 (V)
  const int vCH = lane & 7;         // 16B chunk 0..7   (V)

  floatx4 O0[8] = {}, O1[8] = {};
  float m0_i = -3e38f, l0_i = 0.f;  // set 0, qrow = l16
  float m1_i = -3e38f, l1_i = 0.f;  // set 1, qrow = l16

  // Prologue: stage K[0] into BsK[0] and V[0] into BsV.
  {
#pragma unroll
    for (int j = 0; j < 4; ++j) {
      const int row = wv * 16 + j * 4 + kRL;     // 0..63
      gl2lds16(rpk + (size_t)row * 512 + h * 128 + ((kCH ^ (row & 7)) << 3),
               &BsK[0][(wv * 16 + j * 4) * 128]);
      const int d = wv * 32 + j * 8 + vDL;       // 0..127
      gl2lds16(rvT + (size_t)(h * 128 + d) * 512 + ((vCH ^ (d & 7)) << 3),
               &BsV[(wv * 32 + j * 8) * 64]);
    }
  }
  __syncthreads();   // implicit vmcnt(0): K[0], V[0] landed

  const int kswz = l16 & 7;

  for (int c = 0; c < 8; ++c) {
    const int cur = c & 1;

    // Stage next K tile (double-buffered).
    if (c < 7) {
      const int nb = cur ^ 1;
      const int cn = c + 1;
#pragma unroll
      for (int j = 0; j < 4; ++j) {
        const int row = wv * 16 + j * 4 + kRL;
        gl2lds16(rpk + (size_t)(cn * 64 + row) * 512 + h * 128 +
                     ((kCH ^ (row & 7)) << 3),
                 &BsK[nb][(wv * 16 + j * 4) * 128]);
      }
    }

    // ---- shared-B QK^T: b loaded once, MFMA'd into both sets ----
    floatx4 S0[4] = {}, S1[4] = {};
#pragma unroll
    for (int ks = 0; ks < 4; ++ks) {
      const int ac = ks * 4 + quad;
#pragma unroll
      for (int nt = 0; nt < 4; ++nt) {
        bf16x8 b = *reinterpret_cast<const bf16x8*>(
            &BsK[cur][(nt * 16 + l16) * 128 + ((ac ^ kswz) << 3)]);
        S0[nt] = __builtin_amdgcn_mfma_f32_16x16x32_bf16(b, qf0[ks], S0[nt], 0, 0, 0);
        S1[nt] = __builtin_amdgcn_mfma_f32_16x16x32_bf16(b, qf1[ks], S1[nt], 0, 0, 0);
      }
    }

    // ---- softmax per set (exp2 domain, defer-max) -> Ps[s] ----
#pragma unroll
    for (int s = 0; s < 2; ++s) {
      floatx4* S      = (s == 0) ? S0 : S1;
      floatx4* O      = (s == 0) ? O0 : O1;
      float& m_i      = (s == 0) ? m0_i : m1_i;
      float& l_i      = (s == 0) ? l0_i : l1_i;

      float cm;
      {
        const float a0 = fmaxf(fmaxf(S[0][0], S[0][1]), fmaxf(S[0][2], S[0][3]));
        const float a1 = fmaxf(fmaxf(S[1][0], S[1][1]), fmaxf(S[1][2], S[1][3]));
        const float a2 = fmaxf(fmaxf(S[2][0], S[2][1]), fmaxf(S[2][2], S[2][3]));
        const float a3 = fmaxf(fmaxf(S[3][0], S[3][1]), fmaxf(S[3][2], S[3][3]));
        cm = fmaxf(fmaxf(a0, a1), fmaxf(a2, a3));
        cm = fmaxf(cm, __shfl_xor(cm, 16));
        cm = fmaxf(cm, __shfl_xor(cm, 32));   // chunk max for qrow l16
      }
      if (!__all(cm <= m_i + DEFER_THR)) {
        const float mn = fmaxf(m_i, cm);
        const float sc = exp2f((m_i - mn) * C2EXP);
        m_i = mn;
        l_i *= sc;
        float scR[4];
#pragma unroll
        for (int r = 0; r < 4; ++r) scR[r] = __shfl(sc, quad * 4 + r);
#pragma unroll
        for (int nt = 0; nt < 8; ++nt)
#pragma unroll
          for (int r = 0; r < 4; ++r) O[nt][r] *= scR[r];
      }
      {
        const float mC = m_i * C2EXP;
        float ps = 0.f;
#pragma unroll
        for (int nt = 0; nt < 4; ++nt) {
          const float p0 = exp2f(S[nt][0] * C2EXP - mC);
          const float p1 = exp2f(S[nt][1] * C2EXP - mC);
          const float p2 = exp2f(S[nt][2] * C2EXP - mC);
          const float p3 = exp2f(S[nt][3] * C2EXP - mC);
          ps += (p0 + p1) + (p2 + p3);
          uint2 pk2 = make_uint2(cvtpk(p0, p1), cvtpk(p2, p3));
          *reinterpret_cast<uint2*>(&Ps[s][wv][l16 * 72 + nt * 16 + quad * 4]) = pk2;
        }
        ps += __shfl_xor(ps, 16);
        ps += __shfl_xor(ps, 32);             // chunk sum for qrow l16
        l_i += ps;
      }
    }

    __syncthreads();   // drains V[c] staging (issued end of prev chunk);
                       // also orders all waves before shared PV.

    // ---- shared-B PV: b loaded once, MFMA'd into both sets ----
#pragma unroll
    for (int ks = 0; ks < 2; ++ks) {
      bf16x8 a0 = *reinterpret_cast<const bf16x8*>(&Ps[0][wv][l16 * 72 + ks * 32 + quad * 8]);
      bf16x8 a1 = *reinterpret_cast<const bf16x8*>(&Ps[1][wv][l16 * 72 + ks * 32 + quad * 8]);
#pragma unroll
      for (int nt = 0; nt < 8; ++nt) {
        const int q8 = ks * 4 + quad;
        bf16x8 b = *reinterpret_cast<const bf16x8*>(
            &BsV[(nt * 16 + l16) * 64 + ((q8 ^ kswz) << 3)]);
        O0[nt] = __builtin_amdgcn_mfma_f32_16x16x32_bf16(a0, b, O0[nt], 0, 0, 0);
        O1[nt] = __builtin_amdgcn_mfma_f32_16x16x32_bf16(a1, b, O1[nt], 0, 0, 0);
      }
    }

    __syncthreads();   // all waves done reading BsV -> free to restage

    // Stage next V tile into the (single) BsV buffer; drains at the next
    // chunk's pre-PV barrier (QK+softmax cover the latency).
    if (c < 7) {
      const int cn = c + 1;
#pragma unroll
      for (int j = 0; j < 4; ++j) {
        const int d = wv * 32 + j * 8 + vDL;
        gl2lds16(rvT + (size_t)(h * 128 + d) * 512 + cn * 64 +
                     ((vCH ^ (d & 7)) << 3),
                 &BsV[(wv * 32 + j * 8) * 64]);
      }
    }
  }

  // Final normalize + store, per set.
#pragma unroll
  for (int s = 0; s < 2; ++s) {
    const floatx4* O = (s == 0) ? O0 : O1;
    const float l_i  = (s == 0) ? l0_i : l1_i;
    float invR[4];
#pragma unroll
    for (int r = 0; r < 4; ++r) invR[r] = 1.0f / __shfl(l_i, quad * 4 + r);
#pragma unroll
    for (int r = 0; r < 4; ++r) {
      const int n = n0 + s * 64 + wv * 16 + quad * 4 + r;
#pragma unroll
      for (int nt = 0; nt < 8; ++nt)
        glb[(size_t)n * 512 + h * 128 + nt * 16 + l16] = f2bf(O[nt][r] * invR[r]);
    }
  }
}

// ---------------------------------------------------------------------------
// K6: combine -> f32 output.
// ---------------------------------------------------------------------------
__global__ __launch_bounds__(256) void k_combine(
    const ushort_t* __restrict__ locS, const ushort_t* __restrict__ glb,
    const ushort_t* __restrict__ Vb, const float* __restrict__ scal,
    float* __restrict__ out)
{
  const int t = blockIdx.x * 256 + threadIdx.x;
  const int n = t >> 6, dp = t & 63;
  const float alpha = 1.0f / (1.0f + __expf(-scal[0]));
  const float beta = scal[1];
  const uint32 lv = reinterpret_cast<const uint32*>(locS)[(size_t)n * 64 + dp];
  float g0 = 0.f, g1 = 0.f, v0 = 0.f, v1 = 0.f;
#pragma unroll
  for (int hh = 0; hh < 4; ++hh) {
    const uint32 gv = *reinterpret_cast<const uint32*>(glb + (size_t)n * 512 + hh * 128 + 2 * dp);
    const uint32 vv = *reinterpret_cast<const uint32*>(Vb + (size_t)n * 512 + hh * 128 + 2 * dp);
    g0 += bflo(gv); g1 += bfhi(gv);
    v0 += bflo(vv); v1 += bfhi(vv);
  }
  const float r0 = alpha * bflo(lv) + (1.0f - alpha) * g0 * 0.25f + beta * v0 * 0.25f;
  const float r1 = alpha * bfhi(lv) + (1.0f - alpha) * g1 * 0.25f + beta * v1 * 0.25f;
  reinterpret_cast<float2*>(out)[(size_t)n * 64 + dp] = make_float2(r0, r1);
}

extern "C" void kernel_launch(void* const* d_in, const int* in_sizes, int n_in,
                              void* d_out, int out_size, void* d_ws, size_t ws_size,
                              hipStream_t stream) {
  const void* x     = d_in[0];
  const int*  pidx  = (const int*)d_in[1];
  const void* Wq    = d_in[2];
  const void* bq    = d_in[3];
  const void* Wk    = d_in[4];
  const void* bk    = d_in[5];
  const void* Wv    = d_in[6];
  const void* bv    = d_in[7];
  const void* seeds = d_in[8];
  const void* al    = d_in[9];
  const void* be    = d_in[10];

  char* ws = (char*)d_ws;
  ushort_t* Qb   = (ushort_t*)(ws + OFF_Q);
  ushort_t* Kb   = (ushort_t*)(ws + OFF_K);
  ushort_t* Vb   = (ushort_t*)(ws + OFF_V);
  ushort_t* locS = (ushort_t*)(ws + OFF_LOC);
  ushort_t* rpk  = (ushort_t*)(ws + OFF_RPK);
  ushort_t* xc   = (ushort_t*)(ws + OFF_XC);
  ushort_t* wc   = (ushort_t*)(ws + OFF_WC);
  float*    scal = (float*)   (ws + OFF_SCAL);
  uint32*   flags= (uint32*)  (ws + OFF_FLAG);
  ushort_t* rvT  = (ushort_t*)(ws + OFF_RVT);
  ushort_t* glb  = (ushort_t*)(ws + OFF_GLB);

  k_detect<<<1, 64, 0, stream>>>((const uint32*)x, (const ushort_t*)be, flags);
  k_convert<<<dim3(4096, 2), 256, 0, stream>>>(x, Wq, bq, Wk, bk, Wv, bv, seeds, al, be,
                                               xc, wc, scal, flags);
  k_qkv<<<512, 256, 0, stream>>>(xc, wc, Qb, Kb, Vb);
  k_pool<<<dim3(128, 4), 256, 0, stream>>>(Kb, Vb, pidx, wc, rpk, rvT);
  k_fine<<<dim3(128, 4), 256, 0, stream>>>(Qb, Kb, Vb, pidx, locS);
  k_cross<<<dim3(256, 4), 256, 0, stream>>>(Qb, rpk, rvT, glb);
  k_combine<<<8192, 256, 0, stream>>>(locS, glb, Vb, scal, (float*)d_out);
}

// Round 9
// 305.690 us; speedup vs baseline: 1.7204x; 1.0320x over previous
//
#include <hip/hip_runtime.h>
#include <hip/hip_bf16.h>

// PCGTConvLayer round 18: k_qkv rebuilt on the verified k_cross chassis:
// X fragments in registers (32 VGPR, loaded once), Ws double-buffered via
// global_load_lds + XOR swizzle (pre-swizzled source / swizzled ds_read),
// 1 barrier per chunk with next-tile loads flying under current MFMA.
// LDS 2x32K = 64 KiB (unchanged footprint, 2 blocks/CU). W^T addressing
// flattened: tile t = rows t*64.. of the (1536x256) W^T block.
// All other kernels verbatim from round 17 (315.5 us).
// N=32768 IN=256 D=128 H=4 M=4 KP=128 S=256, SCALE=sqrt(128).

#define INV_SCALE 0.08838834764831845f
// INV_SCALE * log2(e)
#define C2EXP 0.12751744f
// 8 / INV_SCALE  (defer-max threshold in unscaled-score domain)
#define DEFER_THR 90.50966799f

typedef __attribute__((ext_vector_type(8))) short bf16x8;
typedef __attribute__((ext_vector_type(4))) float floatx4;
typedef unsigned short ushort_t;
typedef unsigned int uint32;

// ---- ws layout (bytes) ----
#define OFF_Q    0ull            // bf16 [32768][512]
#define OFF_K    33554432ull     // bf16 [32768][512]
#define OFF_V    67108864ull     // bf16 [32768][512]
#define OFF_LOC  100663296ull    // bf16 [32768][128]
#define OFF_RPK  109051904ull    // bf16 [512][4][128]
#define OFF_XC   110100480ull    // bf16 [32768][256]
#define OFF_WC   126877696ull    // bf16: WqT,WkT,WvT ([512][256] each), biases, seeds
#define OFF_SCAL 127671296ull    // f32 [2]
#define OFF_FLAG 127671304ull    // u32 [2]
#define OFF_RVT  127672320ull    // bf16 [4][128][512]
#define OFF_GLB  128196608ull    // bf16 [32768][512]

#define WC_WQ 0
#define WC_WK 131072
#define WC_WV 262144
#define WC_BQ 393216
#define WC_BK 393728
#define WC_BV 394240
#define WC_SEED 394752
#define WC_TOT 396800

static __device__ __forceinline__ float bflo(uint32 u) {
  return __uint_as_float(u << 16);
}
static __device__ __forceinline__ float bfhi(uint32 u) {
  return __uint_as_float(u & 0xffff0000u);
}
static __device__ __forceinline__ float bf2f(ushort_t u) {
  return __uint_as_float(((uint32)u) << 16);
}
static __device__ __forceinline__ ushort_t f2bf(float f) {
  uint32 x = __float_as_uint(f);
  uint32 r = x + 0x7fffu + ((x >> 16) & 1u);
  return (ushort_t)(r >> 16);
}
static __device__ __forceinline__ uint32 pack2bf(float a, float b) {
  return (uint32)f2bf(a) | ((uint32)f2bf(b) << 16);
}
// HW packed f32->bf16 (RNE; lo16 = a, hi16 = b). Same rounding as f2bf.
static __device__ __forceinline__ uint32 cvtpk(float a, float b) {
  uint32 r;
  asm("v_cvt_pk_bf16_f32 %0, %1, %2" : "=v"(r) : "v"(a), "v"(b));
  return r;
}

// async global -> LDS, 16 bytes per lane. LDS dest must be wave-uniform base;
// lane i lands at base + i*16 B. Global source is per-lane.
static __device__ __forceinline__ void gl2lds16(const ushort_t* g, ushort_t* l) {
  __builtin_amdgcn_global_load_lds(
      (const __attribute__((address_space(1))) void*)g,
      (__attribute__((address_space(3))) void*)l, 16, 0, 0);
}

// ---------------------------------------------------------------------------
__global__ __launch_bounds__(64) void k_detect(const uint32* __restrict__ xw,
                                               const ushort_t* __restrict__ betaRaw,
                                               uint32* __restrict__ flags) {
  const int lane = threadIdx.x;
  const uint32 w = xw[lane * 137 + 3];
  const int e = (w >> 7) & 0xff;
  const unsigned long long b = __ballot(e >= 100 && e <= 140);
  if (lane == 0) {
    flags[0] = (__popcll(b) >= 48) ? 1u : 0u;
    flags[1] = (betaRaw[0] != 0) ? 1u : 0u;
  }
}

// ---------------------------------------------------------------------------
// K1: canonicalize. x -> xc (identity layout). W matrices -> TRANSPOSED
// bf16 [512][256] at same wc offsets. biases/seeds identity.
// ---------------------------------------------------------------------------
static __device__ __forceinline__ void conv8(const void* src, long j, int isB,
                                             ushort_t* dst) {
  if (isB) {
    *reinterpret_cast<uint4*>(dst) =
        *reinterpret_cast<const uint4*>(reinterpret_cast<const ushort_t*>(src) + j);
  } else {
    const float* f = reinterpret_cast<const float*>(src) + j;
    const float4 a = *reinterpret_cast<const float4*>(f);
    const float4 b = *reinterpret_cast<const float4*>(f + 4);
    uint4 o;
    o.x = pack2bf(a.x, a.y); o.y = pack2bf(a.z, a.w);
    o.z = pack2bf(b.x, b.y); o.w = pack2bf(b.z, b.w);
    *reinterpret_cast<uint4*>(dst) = o;
  }
}

__global__ __launch_bounds__(256) void k_convert(
    const void* __restrict__ x,
    const void* __restrict__ Wq, const void* __restrict__ bq,
    const void* __restrict__ Wk, const void* __restrict__ bk,
    const void* __restrict__ Wv, const void* __restrict__ bv,
    const void* __restrict__ seeds, const void* __restrict__ alpha,
    const void* __restrict__ beta,
    ushort_t* __restrict__ xc, ushort_t* __restrict__ wc,
    float* __restrict__ scal, const uint32* __restrict__ flags)
{
  const int isB = (int)flags[0];
  const long i8 = ((long)blockIdx.x * 256 + threadIdx.x) * 8;
  if (blockIdx.y == 0) {
    conv8(x, i8, isB, xc + i8);
  } else {
    if (i8 < WC_BQ) {
      // W region: transpose. i8 = sel*131072 + k*512 + n (8 consecutive n).
      const int sel = (int)(i8 >> 17);
      const long local = i8 & 131071;
      const int kk = (int)(local >> 9);
      const int nn = (int)(local & 511);
      const void* src = sel == 0 ? Wq : (sel == 1 ? Wk : Wv);
      ushort_t* dstW = wc + sel * 131072;
#pragma unroll
      for (int j = 0; j < 8; ++j) {
        ushort_t v;
        if (isB) v = reinterpret_cast<const ushort_t*>(src)[local + j];
        else     v = f2bf(reinterpret_cast<const float*>(src)[local + j]);
        dstW[(size_t)(nn + j) * 256 + kk] = v;
      }
    } else if (i8 < WC_TOT) {
      const void* src; long j;
      if (i8 < WC_BK)        { src = bq;    j = i8 - WC_BQ; }
      else if (i8 < WC_BV)   { src = bk;    j = i8 - WC_BK; }
      else if (i8 < WC_SEED) { src = bv;    j = i8 - WC_BV; }
      else                   { src = seeds; j = i8 - WC_SEED; }
      conv8(src, j, isB, wc + i8);
    }
    if (blockIdx.x == 0 && threadIdx.x == 0) {
      const int isBS = (int)flags[1];
      scal[0] = isBS ? bf2f(reinterpret_cast<const ushort_t*>(alpha)[0])
                     : reinterpret_cast<const float*>(alpha)[0];
      scal[1] = isBS ? bf2f(reinterpret_cast<const ushort_t*>(beta)[0])
                     : reinterpret_cast<const float*>(beta)[0];
    }
  }
}

// ---------------------------------------------------------------------------
// K2: fused QKV GEMM, round 18. X frags in registers (loaded once); Ws
// double-buffered via gl2lds + XOR swizzle; 1 barrier/chunk; next tile's
// loads fly under current chunk's MFMA. Tile t (0..23) = flat W^T rows
// t*64..t*64+63 (sel = t>>3, nc = t&7). LDS 2x32 KiB.
// ---------------------------------------------------------------------------
__global__ __launch_bounds__(256) void k_qkv(
    const ushort_t* __restrict__ xc, const ushort_t* __restrict__ wc,
    ushort_t* __restrict__ Qb, ushort_t* __restrict__ Kb, ushort_t* __restrict__ Vb)
{
  const int m0 = blockIdx.x * 64;
  const int tid = threadIdx.x, lane = tid & 63, wv = tid >> 6;
  const int l16 = lane & 15, quad = lane >> 4;
  const int kswz = l16 & 7;

  __shared__ __align__(16) ushort_t Ws[2][64 * 256];   // 2 x 32 KiB

  // A-fragments in registers: row = m0 + wv*16 + l16, chunk (ks*4+quad)*8.
  bf16x8 af[8];
  {
    const ushort_t* xrow = xc + (size_t)(m0 + wv * 16 + l16) * 256 + quad * 8;
#pragma unroll
    for (int ks = 0; ks < 8; ++ks)
      af[ks] = *reinterpret_cast<const bf16x8*>(xrow + ks * 32);
  }

  // Staging lane coords: each gl2lds covers 2 rows (512 B each).
  const int wRL = lane >> 5;        // row-in-pair 0..1
  const int wCH = lane & 31;        // 16B chunk 0..31

  // Prologue: stage W tile 0 into Ws[0].
#pragma unroll
  for (int j = 0; j < 8; ++j) {
    const int row = wv * 16 + j * 2 + wRL;      // 0..63
    gl2lds16(wc + (size_t)row * 256 + ((wCH ^ (row & 7)) << 3),
             &Ws[0][(wv * 16 + j * 2) * 256]);
  }
  __syncthreads();   // implicit vmcnt(0): tile 0 landed

  for (int t = 0; t < 24; ++t) {
    const int cur = t & 1;

    // Stage next tile into the other buffer; drained by end-of-chunk barrier.
    if (t < 23) {
      const int nb = cur ^ 1;
      const int tn = t + 1;
#pragma unroll
      for (int j = 0; j < 8; ++j) {
        const int row = wv * 16 + j * 2 + wRL;
        gl2lds16(wc + (size_t)(tn * 64 + row) * 256 + ((wCH ^ (row & 7)) << 3),
                 &Ws[nb][(wv * 16 + j * 2) * 256]);
      }
    }

    floatx4 acc[4] = {};
#pragma unroll
    for (int ks = 0; ks < 8; ++ks) {
      const int ac = ks * 4 + quad;
#pragma unroll
      for (int nt = 0; nt < 4; ++nt) {
        bf16x8 b = *reinterpret_cast<const bf16x8*>(
            &Ws[cur][(nt * 16 + l16) * 256 + ((ac ^ kswz) << 3)]);
        acc[nt] = __builtin_amdgcn_mfma_f32_16x16x32_bf16(af[ks], b, acc[nt], 0, 0, 0);
      }
    }

    const int sel = t >> 3, nc = t & 7;
    const ushort_t* bias = wc + WC_BQ + sel * 512;
    ushort_t* out = sel == 0 ? Qb : (sel == 1 ? Kb : Vb);
    const int n0 = nc * 64;
#pragma unroll
    for (int nt = 0; nt < 4; ++nt) {
      const int col = n0 + nt * 16 + l16;
      const float bf = bf2f(bias[col]);
#pragma unroll
      for (int r = 0; r < 4; ++r) {
        const int row = m0 + wv * 16 + quad * 4 + r;
        out[(size_t)row * 512 + col] = f2bf(acc[nt][r] + bf);
      }
    }

    __syncthreads();   // drains next-tile gl2lds; all waves done with 'cur'
  }
}

// ---------------------------------------------------------------------------
// K3: pooling (seeds -> rpk, rvT). Verified (CHK3).
// ---------------------------------------------------------------------------
__global__ __launch_bounds__(256) void k_pool(
    const ushort_t* __restrict__ Kb, const ushort_t* __restrict__ Vb,
    const int* __restrict__ pidx_all, const ushort_t* __restrict__ wc,
    ushort_t* __restrict__ rpk, ushort_t* __restrict__ rvT)
{
  const int k = blockIdx.x, h = blockIdx.y;
  const int tid = threadIdx.x, lane = tid & 63, wv = tid >> 6;
  const int* pidx = pidx_all + k * 256;

  __shared__ __align__(16) ushort_t SB[128 * 256];
  const uint32* SBU = reinterpret_cast<const uint32*>(SB);

#pragma unroll
  for (int i = 0; i < 16; ++i) {
    const int e8 = tid + 256 * i;
    const int q = e8 >> 4, dc = (e8 & 15) * 8;
    uint4 kv = *reinterpret_cast<const uint4*>(Kb + (size_t)pidx[q] * 512 + h * 128 + dc);
    const ushort_t* ku = reinterpret_cast<const ushort_t*>(&kv);
    const int qp = q >> 1, qb = q & 1;
#pragma unroll
    for (int j = 0; j < 8; ++j) {
      const int d = dc + j;
      SB[d * 256 + (((qp ^ (d & 31)) << 1) | qb)] = ku[j];
    }
  }
  __syncthreads();

  float q00, q01, q10, q11;
  {
    const uint32* ssrc = reinterpret_cast<const uint32*>(wc + WC_SEED + (size_t)(wv * 4 + h) * 128);
    float s00 = 0.f, s01 = 0.f, s10 = 0.f, s11 = 0.f;
#pragma unroll 8
    for (int dc = 0; dc < 64; ++dc) {
      const uint32 qv = ssrc[dc];
      const float a0 = bflo(qv), a1 = bfhi(qv);
      const int d0 = dc * 2, d1 = d0 + 1;
      const int c0 = lane ^ (d0 & 31);
      const int c1 = lane ^ (d1 & 31);
      const uint32 u00 = SBU[d0 * 128 + c0];
      const uint32 u01 = SBU[d0 * 128 + c0 + 64];
      const uint32 u10 = SBU[d1 * 128 + c1];
      const uint32 u11 = SBU[d1 * 128 + c1 + 64];
      s00 += a0 * bflo(u00) + a1 * bflo(u10);
      s01 += a0 * bfhi(u00) + a1 * bfhi(u10);
      s10 += a0 * bflo(u01) + a1 * bflo(u11);
      s11 += a0 * bfhi(u01) + a1 * bfhi(u11);
    }
    s00 *= INV_SCALE; s01 *= INV_SCALE; s10 *= INV_SCALE; s11 *= INV_SCALE;
    float mx = fmaxf(fmaxf(s00, s01), fmaxf(s10, s11));
#pragma unroll
    for (int off = 32; off >= 1; off >>= 1) mx = fmaxf(mx, __shfl_xor(mx, off));
    const float e00 = __expf(s00 - mx), e01 = __expf(s01 - mx);
    const float e10 = __expf(s10 - mx), e11 = __expf(s11 - mx);
    float sm = e00 + e01 + e10 + e11;
#pragma unroll
    for (int off = 32; off >= 1; off >>= 1) sm += __shfl_xor(sm, off);
    const float inv = 1.0f / sm;
    q00 = e00 * inv; q01 = e01 * inv; q10 = e10 * inv; q11 = e11 * inv;
  }

  {
    float rk0 = 0.f, rk1 = 0.f;
    const int d0 = 2 * lane, d1 = 2 * lane + 1;
#pragma unroll 4
    for (int qp = 0; qp < 64; ++qp) {
      const float pa = __shfl(q00, qp), pb = __shfl(q01, qp);
      const float pc = __shfl(q10, qp), pd = __shfl(q11, qp);
      const int c0 = qp ^ (d0 & 31);
      const int c1 = qp ^ (d1 & 31);
      const uint32 u0  = SBU[d0 * 128 + c0];
      const uint32 u0b = SBU[d0 * 128 + c0 + 64];
      const uint32 u1  = SBU[d1 * 128 + c1];
      const uint32 u1b = SBU[d1 * 128 + c1 + 64];
      rk0 += pa * bflo(u0) + pb * bfhi(u0) + pc * bflo(u0b) + pd * bfhi(u0b);
      rk1 += pa * bflo(u1) + pb * bfhi(u1) + pc * bflo(u1b) + pd * bfhi(u1b);
    }
    reinterpret_cast<uint32*>(rpk + ((size_t)((k * 4 + wv) * 4 + h)) * 128)[lane] = pack2bf(rk0, rk1);
  }
  __syncthreads();

#pragma unroll
  for (int i = 0; i < 16; ++i) {
    const int e8 = tid + 256 * i;
    const int q = e8 >> 4, dc = (e8 & 15) * 8;
    uint4 vv = *reinterpret_cast<const uint4*>(Vb + (size_t)pidx[q] * 512 + h * 128 + dc);
    *reinterpret_cast<uint4*>(&SB[q * 128 + dc]) = vv;
  }
  __syncthreads();

  {
    float rv0 = 0.f, rv1 = 0.f;
#pragma unroll 4
    for (int qp = 0; qp < 64; ++qp) {
      const float pa = __shfl(q00, qp), pb = __shfl(q01, qp);
      const float pc = __shfl(q10, qp), pd = __shfl(q11, qp);
      const uint32 v00 = SBU[(2 * qp) * 64 + lane];
      const uint32 v01 = SBU[(2 * qp + 1) * 64 + lane];
      const uint32 v10 = SBU[(128 + 2 * qp) * 64 + lane];
      const uint32 v11 = SBU[(129 + 2 * qp) * 64 + lane];
      rv0 += pa * bflo(v00) + pb * bflo(v01) + pc * bflo(v10) + pd * bflo(v11);
      rv1 += pa * bfhi(v00) + pb * bfhi(v01) + pc * bfhi(v10) + pd * bfhi(v11);
    }
    const int rrep = k * 4 + wv;
    rvT[(size_t)(h * 128 + 2 * lane) * 512 + rrep]     = f2bf(rv0);
    rvT[(size_t)(h * 128 + 2 * lane + 1) * 512 + rrep] = f2bf(rv1);
  }
}

// ---------------------------------------------------------------------------
// K4: MFMA fine attention (verified round 15).
// ---------------------------------------------------------------------------
__global__ __launch_bounds__(256) void k_fine(
    const ushort_t* __restrict__ Qb, const ushort_t* __restrict__ Kb,
    const ushort_t* __restrict__ Vb, const int* __restrict__ pidx_all,
    ushort_t* __restrict__ locS)
{
  const int k = blockIdx.x, qg = blockIdx.y;
  const int tid = threadIdx.x, lane = tid & 63, wv = tid >> 6;
  const int l16 = lane & 15, quad = lane >> 4;
  const int* pidx = pidx_all + k * 256;

  __shared__ __align__(16) ushort_t BsK[2][64 * 128];  // 2 x 16 KiB
  __shared__ __align__(16) ushort_t SBV[128 * 64];     // 16 KiB (V^T scatter)
  __shared__ __align__(16) ushort_t Ps[4][16 * 72];    // 9 KiB wave-private

  // This lane's q-row global index (q-row = l16 within the wave's 16 rows).
  const int qidx = pidx[qg * 64 + wv * 16 + l16];

  // K staging lane coordinates (round-13 pattern).
  const int kRL = lane >> 4;        // row-in-group 0..3
  const int kCH = lane & 15;        // 16B chunk 0..15
  const int kswz = l16 & 7;

  float accS[8][4];
#pragma unroll
  for (int nt = 0; nt < 8; ++nt)
#pragma unroll
    for (int r = 0; r < 4; ++r) accS[nt][r] = 0.f;

  // Prologue: stage K tile (h=0,c=0) into BsK[0].
#pragma unroll
  for (int j = 0; j < 4; ++j) {
    const int row = wv * 16 + j * 4 + kRL;   // 0..63
    gl2lds16(Kb + (size_t)pidx[row] * 512 + ((kCH ^ (row & 7)) << 3),
             &BsK[0][(wv * 16 + j * 4) * 128]);
  }
  __syncthreads();   // implicit vmcnt(0): tile 0 landed

  bf16x8 qf[4];
  floatx4 O[8];
  float m_i = -3e38f, l_i = 0.f;

  for (int idx = 0; idx < 16; ++idx) {
    const int h = idx >> 2, c = idx & 3;
    const int cur = idx & 1;

    if (c == 0) {
      // New head: load Q fragments, reset online-softmax state.
      const ushort_t* qrow = Qb + (size_t)qidx * 512 + h * 128 + quad * 8;
#pragma unroll
      for (int ks = 0; ks < 4; ++ks)
        qf[ks] = *reinterpret_cast<const bf16x8*>(qrow + ks * 32);
#pragma unroll
      for (int nt = 0; nt < 8; ++nt) O[nt] = (floatx4){0.f, 0.f, 0.f, 0.f};
      m_i = -3e38f;
      l_i = 0.f;
    }

    // Prefetch next (h,c) K tile into the other buffer (drained by the
    // end-of-iteration barrier's implicit vmcnt(0)).
    if (idx < 15) {
      const int hn = (idx + 1) >> 2, cn = (idx + 1) & 3;
      const int nb = cur ^ 1;
#pragma unroll
      for (int j = 0; j < 4; ++j) {
        const int row = wv * 16 + j * 4 + kRL;
        gl2lds16(Kb + (size_t)pidx[cn * 64 + row] * 512 + hn * 128 +
                     ((kCH ^ (row & 7)) << 3),
                 &BsK[nb][(wv * 16 + j * 4) * 128]);
      }
    }

    // ---- swapped QK^T: S[nt][r] = score[key = nt*16+quad*4+r][qrow = l16] ----
    floatx4 S[4] = {};
#pragma unroll
    for (int ks = 0; ks < 4; ++ks) {
      const int ac = ks * 4 + quad;
#pragma unroll
      for (int nt = 0; nt < 4; ++nt) {
        bf16x8 b = *reinterpret_cast<const bf16x8*>(
            &BsK[cur][(nt * 16 + l16) * 128 + ((ac ^ kswz) << 3)]);
        S[nt] = __builtin_amdgcn_mfma_f32_16x16x32_bf16(b, qf[ks], S[nt], 0, 0, 0);
      }
    }

    // ---- lane-local softmax (exp2 domain, defer-max) ----
    float cm;
    {
      const float m0 = fmaxf(fmaxf(S[0][0], S[0][1]), fmaxf(S[0][2], S[0][3]));
      const float m1 = fmaxf(fmaxf(S[1][0], S[1][1]), fmaxf(S[1][2], S[1][3]));
      const float m2 = fmaxf(fmaxf(S[2][0], S[2][1]), fmaxf(S[2][2], S[2][3]));
      const float m3 = fmaxf(fmaxf(S[3][0], S[3][1]), fmaxf(S[3][2], S[3][3]));
      cm = fmaxf(fmaxf(m0, m1), fmaxf(m2, m3));
      cm = fmaxf(cm, __shfl_xor(cm, 16));
      cm = fmaxf(cm, __shfl_xor(cm, 32));   // chunk max for qrow l16
    }
    if (!__all(cm <= m_i + DEFER_THR)) {
      const float mn = fmaxf(m_i, cm);
      const float sc = exp2f((m_i - mn) * C2EXP);
      m_i = mn;
      l_i *= sc;
      float scR[4];
#pragma unroll
      for (int r = 0; r < 4; ++r) scR[r] = __shfl(sc, quad * 4 + r);
#pragma unroll
      for (int nt = 0; nt < 8; ++nt)
#pragma unroll
        for (int r = 0; r < 4; ++r) O[nt][r] *= scR[r];
    }
    {
      const float mC = m_i * C2EXP;
      float ps = 0.f;
#pragma unroll
      for (int nt = 0; nt < 4; ++nt) {
        const float p0 = exp2f(S[nt][0] * C2EXP - mC);
        const float p1 = exp2f(S[nt][1] * C2EXP - mC);
        const float p2 = exp2f(S[nt][2] * C2EXP - mC);
        const float p3 = exp2f(S[nt][3] * C2EXP - mC);
        ps += (p0 + p1) + (p2 + p3);
        uint2 pk2 = make_uint2(pack2bf(p0, p1), pack2bf(p2, p3));
        *reinterpret_cast<uint2*>(&Ps[wv][l16 * 72 + nt * 16 + quad * 4]) = pk2;
      }
      ps += __shfl_xor(ps, 16);
      ps += __shfl_xor(ps, 32);
      l_i += ps;
    }
    // Ps write->read is within-wave (lgkmcnt-ordered).

    __syncthreads();   // prev unit's PV readers of SBV done
    // ---- V stage: scalar-scatter transpose (round-8 verbatim, -> SBV) ----
#pragma unroll
    for (int i = 0; i < 4; ++i) {
      const int e = tid + 256 * i;
      const int key = e & 63, dc8 = (e >> 6) * 8;
      uint4 vv = *reinterpret_cast<const uint4*>(
          Vb + (size_t)pidx[c * 64 + key] * 512 + h * 128 + dc8);
      const ushort_t* u = reinterpret_cast<const ushort_t*>(&vv);
#pragma unroll
      for (int j = 0; j < 8; ++j) {
        const int d = dc8 + j;
        SBV[d * 64 + (((key >> 3) ^ j) << 3) + (key & 7)] = u[j];
      }
    }
    __syncthreads();   // V staged

    // ---- PV ----
#pragma unroll
    for (int ks = 0; ks < 2; ++ks) {
      bf16x8 a = *reinterpret_cast<const bf16x8*>(&Ps[wv][l16 * 72 + ks * 32 + quad * 8]);
#pragma unroll
      for (int nt = 0; nt < 8; ++nt) {
        const int d = nt * 16 + l16;
        const int q8 = ks * 4 + quad;
        bf16x8 b = *reinterpret_cast<const bf16x8*>(
            &SBV[d * 64 + ((q8 ^ (d & 7)) << 3)]);
        O[nt] = __builtin_amdgcn_mfma_f32_16x16x32_bf16(a, b, O[nt], 0, 0, 0);
      }
    }

    if (c == 3) {
      // End of head h: fold normalized O into accS.
      float invR[4];
#pragma unroll
      for (int r = 0; r < 4; ++r) invR[r] = 1.0f / __shfl(l_i, quad * 4 + r);
#pragma unroll
      for (int nt = 0; nt < 8; ++nt)
#pragma unroll
        for (int r = 0; r < 4; ++r) accS[nt][r] += O[nt][r] * invR[r];
    }

    __syncthreads();   // drains next-tile gl2lds; all waves done with cur/SBV
  }

#pragma unroll
  for (int r = 0; r < 4; ++r) {
    const int n = pidx[qg * 64 + wv * 16 + quad * 4 + r];
#pragma unroll
    for (int nt = 0; nt < 8; ++nt)
      locS[(size_t)n * 128 + nt * 16 + l16] = f2bf(accS[nt][r] * 0.25f);
  }
}

// ---------------------------------------------------------------------------
// K5: MFMA cross-attention (verified round 17).
// ---------------------------------------------------------------------------
__global__ __launch_bounds__(256, 2) void k_cross(
    const ushort_t* __restrict__ Qb, const ushort_t* __restrict__ rpk,
    const ushort_t* __restrict__ rvT, ushort_t* __restrict__ glb)
{
  const int h = blockIdx.y;
  const int n0 = blockIdx.x * 128;
  const int tid = threadIdx.x, lane = tid & 63, wv = tid >> 6;
  const int l16 = lane & 15, quad = lane >> 4;

  __shared__ __align__(16) ushort_t BsK[2][64 * 128];   // 2 x 16 KiB
  __shared__ __align__(16) ushort_t BsV[128 * 64];      // 16 KiB (single)
  __shared__ __align__(16) ushort_t Ps[2][4][16 * 72];  // 18 KiB (per set)

  // Q fragments for both 64-row sets (set s: rows n0 + s*64 + wv*16 + l16).
  bf16x8 qf0[4], qf1[4];
  {
    const ushort_t* q0 =
        Qb + (size_t)(n0 + wv * 16 + l16) * 512 + h * 128 + quad * 8;
    const ushort_t* q1 = q0 + (size_t)64 * 512;
#pragma unroll
    for (int ks = 0; ks < 4; ++ks) {
      qf0[ks] = *reinterpret_cast<const bf16x8*>(q0 + ks * 32);
      qf1[ks] = *reinterpret_cast<const bf16x8*>(q1 + ks * 32);
    }
  }

  const int kRL = lane >> 4;        // row-in-group 0..3 (K)
  const int kCH = lane & 15;        // 16B chunk 0..15  (K)
  const int vDL = lane >> 3;        // row-in-group 0..7 (V)
  const int vCH = lane & 7;         // 16B chunk 0..7   (V)

  floatx4 O0[8] = {}, O1[8] = {};
  float m0_i = -3e38f, l0_i = 0.f;  // set 0, qrow = l16
  float m1_i = -3e38f, l1_i = 0.f;  // set 1, qrow = l16

  // Prologue: stage K[0] into BsK[0] and V[0] into BsV.
  {
#pragma unroll
    for (int j = 0; j < 4; ++j) {
      const int row = wv * 16 + j * 4 + kRL;     // 0..63
      gl2lds16(rpk + (size_t)row * 512 + h * 128 + ((kCH ^ (row & 7)) << 3),
               &BsK[0][(wv * 16 + j * 4) * 128]);
      const int d = wv * 32 + j * 8 + vDL;       // 0..127
      gl2lds16(rvT + (size_t)(h * 128 + d) * 512 + ((vCH ^ (d & 7)) << 3),
               &BsV[(wv * 32 + j * 8) * 64]);
    }
  }
  __syncthreads();   // implicit vmcnt(0): K[0], V[0] landed

  const int kswz = l16 & 7;

  for (int c = 0; c < 8; ++c) {
    const int cur = c & 1;

    // Stage next K tile (double-buffered).
    if (c < 7) {
      const int nb = cur ^ 1;
      const int cn = c + 1;
#pragma unroll
      for (int j = 0; j < 4; ++j) {
        const int row = wv * 16 + j * 4 + kRL;
        gl2lds16(rpk + (size_t)(cn * 64 + row) * 512 + h * 128 +
                     ((kCH ^ (row & 7)) << 3),
                 &BsK[nb][(wv * 16 + j * 4) * 128]);
      }
    }

    // ---- shared-B QK^T: b loaded once, MFMA'd into both sets ----
    floatx4 S0[4] = {}, S1[4] = {};
#pragma unroll
    for (int ks = 0; ks < 4; ++ks) {
      const int ac = ks * 4 + quad;
#pragma unroll
      for (int nt = 0; nt < 4; ++nt) {
        bf16x8 b = *reinterpret_cast<const bf16x8*>(
            &BsK[cur][(nt * 16 + l16) * 128 + ((ac ^ kswz) << 3)]);
        S0[nt] = __builtin_amdgcn_mfma_f32_16x16x32_bf16(b, qf0[ks], S0[nt], 0, 0, 0);
        S1[nt] = __builtin_amdgcn_mfma_f32_16x16x32_bf16(b, qf1[ks], S1[nt], 0, 0, 0);
      }
    }

    // ---- softmax per set (exp2 domain, defer-max) -> Ps[s] ----
#pragma unroll
    for (int s = 0; s < 2; ++s) {
      floatx4* S      = (s == 0) ? S0 : S1;
      floatx4* O      = (s == 0) ? O0 : O1;
      float& m_i      = (s == 0) ? m0_i : m1_i;
      float& l_i      = (s == 0) ? l0_i : l1_i;

      float cm;
      {
        const float a0 = fmaxf(fmaxf(S[0][0], S[0][1]), fmaxf(S[0][2], S[0][3]));
        const float a1 = fmaxf(fmaxf(S[1][0], S[1][1]), fmaxf(S[1][2], S[1][3]));
        const float a2 = fmaxf(fmaxf(S[2][0], S[2][1]), fmaxf(S[2][2], S[2][3]));
        const float a3 = fmaxf(fmaxf(S[3][0], S[3][1]), fmaxf(S[3][2], S[3][3]));
        cm = fmaxf(fmaxf(a0, a1), fmaxf(a2, a3));
        cm = fmaxf(cm, __shfl_xor(cm, 16));
        cm = fmaxf(cm, __shfl_xor(cm, 32));   // chunk max for qrow l16
      }
      if (!__all(cm <= m_i + DEFER_THR)) {
        const float mn = fmaxf(m_i, cm);
        const float sc = exp2f((m_i - mn) * C2EXP);
        m_i = mn;
        l_i *= sc;
        float scR[4];
#pragma unroll
        for (int r = 0; r < 4; ++r) scR[r] = __shfl(sc, quad * 4 + r);
#pragma unroll
        for (int nt = 0; nt < 8; ++nt)
#pragma unroll
          for (int r = 0; r < 4; ++r) O[nt][r] *= scR[r];
      }
      {
        const float mC = m_i * C2EXP;
        float ps = 0.f;
#pragma unroll
        for (int nt = 0; nt < 4; ++nt) {
          const float p0 = exp2f(S[nt][0] * C2EXP - mC);
          const float p1 = exp2f(S[nt][1] * C2EXP - mC);
          const float p2 = exp2f(S[nt][2] * C2EXP - mC);
          const float p3 = exp2f(S[nt][3] * C2EXP - mC);
          ps += (p0 + p1) + (p2 + p3);
          uint2 pk2 = make_uint2(cvtpk(p0, p1), cvtpk(p2, p3));
          *reinterpret_cast<uint2*>(&Ps[s][wv][l16 * 72 + nt * 16 + quad * 4]) = pk2;
        }
        ps += __shfl_xor(ps, 16);
        ps += __shfl_xor(ps, 32);             // chunk sum for qrow l16
        l_i += ps;
      }
    }

    __syncthreads();   // drains V[c] staging (issued end of prev chunk);
                       // also orders all waves before shared PV.

    // ---- shared-B PV: b loaded once, MFMA'd into both sets ----
#pragma unroll
    for (int ks = 0; ks < 2; ++ks) {
      bf16x8 a0 = *reinterpret_cast<const bf16x8*>(&Ps[0][wv][l16 * 72 + ks * 32 + quad * 8]);
      bf16x8 a1 = *reinterpret_cast<const bf16x8*>(&Ps[1][wv][l16 * 72 + ks * 32 + quad * 8]);
#pragma unroll
      for (int nt = 0; nt < 8; ++nt) {
        const int q8 = ks * 4 + quad;
        bf16x8 b = *reinterpret_cast<const bf16x8*>(
            &BsV[(nt * 16 + l16) * 64 + ((q8 ^ kswz) << 3)]);
        O0[nt] = __builtin_amdgcn_mfma_f32_16x16x32_bf16(a0, b, O0[nt], 0, 0, 0);
        O1[nt] = __builtin_amdgcn_mfma_f32_16x16x32_bf16(a1, b, O1[nt], 0, 0, 0);
      }
    }

    __syncthreads();   // all waves done reading BsV -> free to restage

    // Stage next V tile into the (single) BsV buffer; drains at the next
    // chunk's pre-PV barrier (QK+softmax cover the latency).
    if (c < 7) {
      const int cn = c + 1;
#pragma unroll
      for (int j = 0; j < 4; ++j) {
        const int d = wv * 32 + j * 8 + vDL;
        gl2lds16(rvT + (size_t)(h * 128 + d) * 512 + cn * 64 +
                     ((vCH ^ (d & 7)) << 3),
                 &BsV[(wv * 32 + j * 8) * 64]);
      }
    }
  }

  // Final normalize + store, per set.
#pragma unroll
  for (int s = 0; s < 2; ++s) {
    const floatx4* O = (s == 0) ? O0 : O1;
    const float l_i  = (s == 0) ? l0_i : l1_i;
    float invR[4];
#pragma unroll
    for (int r = 0; r < 4; ++r) invR[r] = 1.0f / __shfl(l_i, quad * 4 + r);
#pragma unroll
    for (int r = 0; r < 4; ++r) {
      const int n = n0 + s * 64 + wv * 16 + quad * 4 + r;
#pragma unroll
      for (int nt = 0; nt < 8; ++nt)
        glb[(size_t)n * 512 + h * 128 + nt * 16 + l16] = f2bf(O[nt][r] * invR[r]);
    }
  }
}

// ---------------------------------------------------------------------------
// K6: combine -> f32 output.
// ---------------------------------------------------------------------------
__global__ __launch_bounds__(256) void k_combine(
    const ushort_t* __restrict__ locS, const ushort_t* __restrict__ glb,
    const ushort_t* __restrict__ Vb, const float* __restrict__ scal,
    float* __restrict__ out)
{
  const int t = blockIdx.x * 256 + threadIdx.x;
  const int n = t >> 6, dp = t & 63;
  const float alpha = 1.0f / (1.0f + __expf(-scal[0]));
  const float beta = scal[1];
  const uint32 lv = reinterpret_cast<const uint32*>(locS)[(size_t)n * 64 + dp];
  float g0 = 0.f, g1 = 0.f, v0 = 0.f, v1 = 0.f;
#pragma unroll
  for (int hh = 0; hh < 4; ++hh) {
    const uint32 gv = *reinterpret_cast<const uint32*>(glb + (size_t)n * 512 + hh * 128 + 2 * dp);
    const uint32 vv = *reinterpret_cast<const uint32*>(Vb + (size_t)n * 512 + hh * 128 + 2 * dp);
    g0 += bflo(gv); g1 += bfhi(gv);
    v0 += bflo(vv); v1 += bfhi(vv);
  }
  const float r0 = alpha * bflo(lv) + (1.0f - alpha) * g0 * 0.25f + beta * v0 * 0.25f;
  const float r1 = alpha * bfhi(lv) + (1.0f - alpha) * g1 * 0.25f + beta * v1 * 0.25f;
  reinterpret_cast<float2*>(out)[(size_t)n * 64 + dp] = make_float2(r0, r1);
}

extern "C" void kernel_launch(void* const* d_in, const int* in_sizes, int n_in,
                              void* d_out, int out_size, void* d_ws, size_t ws_size,
                              hipStream_t stream) {
  const void* x     = d_in[0];
  const int*  pidx  = (const int*)d_in[1];
  const void* Wq    = d_in[2];
  const void* bq    = d_in[3];
  const void* Wk    = d_in[4];
  const void* bk    = d_in[5];
  const void* Wv    = d_in[6];
  const void* bv    = d_in[7];
  const void* seeds = d_in[8];
  const void* al    = d_in[9];
  const void* be    = d_in[10];

  char* ws = (char*)d_ws;
  ushort_t* Qb   = (ushort_t*)(ws + OFF_Q);
  ushort_t* Kb   = (ushort_t*)(ws + OFF_K);
  ushort_t* Vb   = (ushort_t*)(ws + OFF_V);
  ushort_t* locS = (ushort_t*)(ws + OFF_LOC);
  ushort_t* rpk  = (ushort_t*)(ws + OFF_RPK);
  ushort_t* xc   = (ushort_t*)(ws + OFF_XC);
  ushort_t* wc   = (ushort_t*)(ws + OFF_WC);
  float*    scal = (float*)   (ws + OFF_SCAL);
  uint32*   flags= (uint32*)  (ws + OFF_FLAG);
  ushort_t* rvT  = (ushort_t*)(ws + OFF_RVT);
  ushort_t* glb  = (ushort_t*)(ws + OFF_GLB);

  k_detect<<<1, 64, 0, stream>>>((const uint32*)x, (const ushort_t*)be, flags);
  k_convert<<<dim3(4096, 2), 256, 0, stream>>>(x, Wq, bq, Wk, bk, Wv, bv, seeds, al, be,
                                               xc, wc, scal, flags);
  k_qkv<<<512, 256, 0, stream>>>(xc, wc, Qb, Kb, Vb);
  k_pool<<<dim3(128, 4), 256, 0, stream>>>(Kb, Vb, pidx, wc, rpk, rvT);
  k_fine<<<dim3(128, 4), 256, 0, stream>>>(Qb, Kb, Vb, pidx, locS);
  k_cross<<<dim3(256, 4), 256, 0, stream>>>(Qb, rpk, rvT, glb);
  k_combine<<<8192, 256, 0, stream>>>(locS, glb, Vb, scal, (float*)d_out);
}